// Round 5
// baseline (328.299 us; speedup 1.0000x reference)
//
#include <hip/hip_runtime.h>
#include <stdint.h>

#define N_IN  128
#define N_H   256
#define N_OUT 64

typedef __attribute__((ext_vector_type(8))) __bf16 bf16x8;
typedef __attribute__((ext_vector_type(4))) float f32x4;

// ---------------- Threefry-2x32 (JAX-compatible) ----------------
__device__ __forceinline__ void tf4(uint32_t& x0, uint32_t& x1,
                                    const int r0, const int r1, const int r2, const int r3) {
  x0 += x1; x1 = (x1 << r0) | (x1 >> (32 - r0)); x1 ^= x0;
  x0 += x1; x1 = (x1 << r1) | (x1 >> (32 - r1)); x1 ^= x0;
  x0 += x1; x1 = (x1 << r2) | (x1 >> (32 - r2)); x1 ^= x0;
  x0 += x1; x1 = (x1 << r3) | (x1 >> (32 - r3)); x1 ^= x0;
}

__device__ __forceinline__ uint2 threefry2x32(uint32_t k0, uint32_t k1, uint32_t x0, uint32_t x1) {
  const uint32_t k2 = k0 ^ k1 ^ 0x1BD11BDAu;
  x0 += k0; x1 += k1;
  tf4(x0, x1, 13, 15, 26, 6);   x0 += k1; x1 += k2 + 1u;
  tf4(x0, x1, 17, 29, 16, 24);  x0 += k2; x1 += k0 + 2u;
  tf4(x0, x1, 13, 15, 26, 6);   x0 += k0; x1 += k1 + 3u;
  tf4(x0, x1, 17, 29, 16, 24);  x0 += k1; x1 += k2 + 4u;
  tf4(x0, x1, 13, 15, 26, 6);   x0 += k2; x1 += k0 + 5u;
  return make_uint2(x0, x1);
}

// ---------------- dropout mask precompute ----------------
// mask[row*16 + colb] bit ct = keep(row, ct*16 + colb); one thread per word.
__global__ __launch_bounds__(256) void k_mask(uint16_t* __restrict__ mask, int N) {
  int g = blockIdx.x * 256 + threadIdx.x;
  if (g >= N * 16) return;
  uint32_t row = (uint32_t)(g >> 4), colb = (uint32_t)(g & 15);
  uint32_t base = row * 256u + colb;
  uint32_t m = 0;
#pragma unroll
  for (int ct = 0; ct < 16; ct++) {
    uint2 o = threefry2x32(0u, 42u, 0u, base + (uint32_t)ct * 16u);
    uint32_t bits = o.x ^ o.y;
    m |= ((~bits) >> 31) << ct;   // keep <=> top bit clear
  }
  mask[g] = (uint16_t)m;
}

// split f32 -> (hi,lo) bf16 bit patterns packed in one u32: (hi<<16)|lo
__device__ __forceinline__ uint32_t pack_hilo(float v) {
  uint32_t bits = __builtin_bit_cast(uint32_t, v);
  uint32_t hi = bits & 0xffff0000u;
  float lo = v - __builtin_bit_cast(float, hi);
  uint32_t lob = __builtin_bit_cast(uint32_t, lo) >> 16;
  return hi | lob;
}

// ---------------- edge-index layout detection (int64 vs int32) ----------------
__global__ void k_detect(const int* __restrict__ e, int E, int* __restrict__ flag) {
  __shared__ int s_nz;
  if (threadIdx.x == 0) s_nz = 0;
  __syncthreads();
  int n = E < 2048 ? E : 2048;
  for (int i = threadIdx.x; i < n; i += 256)
    if (e[2 * i + 1] != 0) atomicAdd(&s_nz, 1);
  __syncthreads();
  if (threadIdx.x == 0) *flag = (s_nz == 0) ? 2 : 1;
}

// ---------------- CSR build ----------------
__global__ void k_deg(const int* __restrict__ eidx, int* __restrict__ deg, int E,
                      const int* __restrict__ flag) {
  int e = blockIdx.x * 256 + threadIdx.x;
  if (e >= E) return;
  int stride = *flag;
  int d = eidx[(size_t)(E + e) * stride];
  atomicAdd(deg + d, 1);
}

// hierarchical scan, phase A: per-block (1024 elems) sum
__global__ __launch_bounds__(256) void k_scanA(const int* __restrict__ deg,
                                               int* __restrict__ bsum, int N) {
  const int b = blockIdx.x, t = threadIdx.x;
  const int base = b * 1024 + t * 4;
  int s = 0;
  if (base + 3 < N) {
    int4 v = *reinterpret_cast<const int4*>(deg + base);
    s = v.x + v.y + v.z + v.w;
  } else {
    for (int i = 0; i < 4; i++) if (base + i < N) s += deg[base + i];
  }
  __shared__ int ws[4];
#pragma unroll
  for (int off = 32; off; off >>= 1) s += __shfl_down(s, off);
  if ((t & 63) == 0) ws[t >> 6] = s;
  __syncthreads();
  if (t == 0) bsum[b] = ws[0] + ws[1] + ws[2] + ws[3];
}

// phase B: single-wave exclusive scan of block sums (NB <= 64); writes rowptr[N]
__global__ void k_scanB(const int* __restrict__ bsum, int* __restrict__ boff,
                        int* __restrict__ rowptrN, int NB) {
  int t = threadIdx.x;   // 64 threads
  int x = (t < NB) ? bsum[t] : 0;
  int v = x;
#pragma unroll
  for (int off = 1; off < 64; off <<= 1) {
    int u = __shfl_up(v, off);
    if (t >= off) v += u;
  }
  if (t < NB) boff[t] = v - x;
  if (t == 63) *rowptrN = v;
}

// phase C: per-block local scan + boff, fused norm + cursor
__global__ __launch_bounds__(256) void k_scanC(const int* __restrict__ deg,
                                               const int* __restrict__ boff,
                                               int* __restrict__ rowptr,
                                               float* __restrict__ norm,
                                               int* __restrict__ cursor, int N) {
  __shared__ int sums[256];
  const int b = blockIdx.x, t = threadIdx.x;
  const int base = b * 1024 + t * 4;
  int d[4]; int s = 0;
#pragma unroll
  for (int i = 0; i < 4; i++) { d[i] = (base + i < N) ? deg[base + i] : 0; s += d[i]; }
  sums[t] = s;
  __syncthreads();
  for (int off = 1; off < 256; off <<= 1) {
    int u = (t >= off) ? sums[t - off] : 0;
    __syncthreads();
    sums[t] += u;
    __syncthreads();
  }
  int run = boff[b] + ((t == 0) ? 0 : sums[t - 1]);
#pragma unroll
  for (int i = 0; i < 4; i++) {
    if (base + i < N) {
      rowptr[base + i] = run;
      cursor[base + i] = run;
      norm[base + i] = d[i] > 0 ? rsqrtf((float)d[i]) : 1.0f;
      run += d[i];
    }
  }
}

__global__ void k_fill(const int* __restrict__ eidx, int* __restrict__ cursor,
                       int* __restrict__ esrc, int E, const int* __restrict__ flag) {
  int e = blockIdx.x * 256 + threadIdx.x;
  if (e >= E) return;
  int stride = *flag;
  int s = eidx[(size_t)e * stride];
  int d = eidx[(size_t)(E + e) * stride];
  int pos = atomicAdd(cursor + d, 1);
  esrc[pos] = s;
}

// per-row insertion sort in LDS (canonical deterministic order)
__global__ __launch_bounds__(256) void k_sortlds(int* __restrict__ esrc,
                                                 const int* __restrict__ rowptr, int N) {
  __shared__ int buf[64 * 256];   // 64 KB: 64 slots per thread, column-major (stride 256)
  int n = blockIdx.x * 256 + threadIdx.x;
  if (n >= N) return;
  const int t = threadIdx.x;
  int lo = rowptr[n], hi = rowptr[n + 1], d = hi - lo;
  if (d <= 64) {
    for (int i = 0; i < d; i++) buf[i * 256 + t] = esrc[lo + i];
    for (int i = 1; i < d; i++) {
      int v = buf[i * 256 + t];
      int j = i - 1;
      while (j >= 0 && buf[j * 256 + t] > v) { buf[(j + 1) * 256 + t] = buf[j * 256 + t]; j--; }
      buf[(j + 1) * 256 + t] = v;
    }
    for (int i = 0; i < d; i++) esrc[lo + i] = buf[i * 256 + t];
  } else {
    for (int i = lo + 1; i < hi; i++) {
      int v = esrc[i];
      int j = i - 1;
      while (j >= lo && esrc[j] > v) { esrc[j + 1] = esrc[j]; j--; }
      esrc[j + 1] = v;
    }
  }
}

// ---------------- layer-1 pull: aggP[n] = pack(sum h[s]*norm[s]) ----------------
__global__ __launch_bounds__(256) void k_pull1(
    const float* __restrict__ h, const float* __restrict__ norm,
    const int* __restrict__ rowptr, const int* __restrict__ esrc,
    uint32_t* __restrict__ aggP, int N) {
  int node = blockIdx.x * 4 + (threadIdx.x >> 6);
  if (node >= N) return;
  int lane = threadIdx.x & 63;
  int lo = rowptr[node], hi = rowptr[node + 1];
  float2 a0 = {0.f, 0.f}, a1 = {0.f, 0.f}, a2 = {0.f, 0.f}, a3 = {0.f, 0.f};
  int e = lo;
  for (; e + 3 < hi; e += 4) {
    int s0 = esrc[e], s1 = esrc[e + 1], s2 = esrc[e + 2], s3 = esrc[e + 3];
    float n0 = norm[s0], n1 = norm[s1], n2 = norm[s2], n3 = norm[s3];
    float2 v0 = *reinterpret_cast<const float2*>(h + (size_t)s0 * N_IN + lane * 2);
    float2 v1 = *reinterpret_cast<const float2*>(h + (size_t)s1 * N_IN + lane * 2);
    float2 v2 = *reinterpret_cast<const float2*>(h + (size_t)s2 * N_IN + lane * 2);
    float2 v3 = *reinterpret_cast<const float2*>(h + (size_t)s3 * N_IN + lane * 2);
    a0.x = fmaf(v0.x, n0, a0.x); a0.y = fmaf(v0.y, n0, a0.y);
    a1.x = fmaf(v1.x, n1, a1.x); a1.y = fmaf(v1.y, n1, a1.y);
    a2.x = fmaf(v2.x, n2, a2.x); a2.y = fmaf(v2.y, n2, a2.y);
    a3.x = fmaf(v3.x, n3, a3.x); a3.y = fmaf(v3.y, n3, a3.y);
  }
  for (; e < hi; e++) {
    int s0 = esrc[e];
    float n0 = norm[s0];
    float2 v0 = *reinterpret_cast<const float2*>(h + (size_t)s0 * N_IN + lane * 2);
    a0.x = fmaf(v0.x, n0, a0.x); a0.y = fmaf(v0.y, n0, a0.y);
  }
  float rx = (a0.x + a1.x) + (a2.x + a3.x);
  float ry = (a0.y + a1.y) + (a2.y + a3.y);
  uint2 p = make_uint2(pack_hilo(rx), pack_hilo(ry));
  *reinterpret_cast<uint2*>(aggP + (size_t)node * N_IN + lane * 2) = p;
}

// ---------------- W pack: fragment-order (hi,lo) bf16 planes ----------------
__global__ void k_packW(const float* __restrict__ W, uint4* __restrict__ WH,
                        uint4* __restrict__ WL, int Ncols, int nct, int nks) {
  int g = blockIdx.x * 256 + threadIdx.x;
  if (g >= nct * nks * 64) return;
  int lane = g & 63;
  int grp = g >> 6;
  int ks = grp % nks, ct = grp / nks;
  int k0 = ks * 32 + (lane >> 4) * 8;
  int col = ct * 16 + (lane & 15);
  uint32_t hb[8], lb[8];
#pragma unroll
  for (int j = 0; j < 8; j++) {
    float w = W[(size_t)(k0 + j) * Ncols + col];
    uint32_t bits = __builtin_bit_cast(uint32_t, w);
    uint32_t hi = bits & 0xffff0000u;
    float lo = w - __builtin_bit_cast(float, hi);
    hb[j] = hi >> 16;
    lb[j] = __builtin_bit_cast(uint32_t, lo) >> 16;
  }
  WH[g] = make_uint4(hb[0] | (hb[1] << 16), hb[2] | (hb[3] << 16),
                     hb[4] | (hb[5] << 16), hb[6] | (hb[7] << 16));
  WL[g] = make_uint4(lb[0] | (lb[1] << 16), lb[2] | (lb[3] << 16),
                     lb[4] | (lb[5] << 16), lb[6] | (lb[7] << 16));
}

// ---------------- GEMM1 (split-bf16 MFMA, no LDS, col-split by blockIdx.y) ----------------
// blockIdx.y = cy in {0,1}: this block computes col-tiles ct in [cy*8, cy*8+8)
__global__ __launch_bounds__(256) void k_gemm1_mfma(
    const uint32_t* __restrict__ aggP, const uint4* __restrict__ WH,
    const uint4* __restrict__ WL, const float* __restrict__ b1,
    const float* __restrict__ norm, const uint16_t* __restrict__ mask,
    uint32_t* __restrict__ h1sP, int Nn) {
  const int tid = threadIdx.x;
  const int wave = tid >> 6, lane = tid & 63;
  const int row0 = blockIdx.x * 64 + wave * 16;
  const int cy = blockIdx.y;
  const int lrow = lane & 15, lk = lane >> 4;
  int arow = row0 + lrow; if (arow >= Nn) arow = Nn - 1;

  f32x4 acc[8];
#pragma unroll
  for (int c = 0; c < 8; c++) acc[c] = f32x4{0.f, 0.f, 0.f, 0.f};

#pragma unroll
  for (int ks = 0; ks < 4; ks++) {
    const uint4* ap = reinterpret_cast<const uint4*>(aggP + (size_t)arow * N_IN + ks * 32 + lk * 8);
    uint4 p0 = ap[0], p1 = ap[1];
    uint32_t pw[8] = {p0.x, p0.y, p0.z, p0.w, p1.x, p1.y, p1.z, p1.w};
    union { ushort u[8]; bf16x8 v; } ah, al;
#pragma unroll
    for (int j = 0; j < 8; j++) { ah.u[j] = (ushort)(pw[j] >> 16); al.u[j] = (ushort)(pw[j] & 0xffffu); }
#pragma unroll
    for (int c = 0; c < 8; c++) {
      int ct = cy * 8 + c;
      union { uint4 q; bf16x8 v; } bh, bl;
      bh.q = WH[(ct * 4 + ks) * 64 + lane];
      bl.q = WL[(ct * 4 + ks) * 64 + lane];
      acc[c] = __builtin_amdgcn_mfma_f32_16x16x32_bf16(ah.v, bh.v, acc[c], 0, 0, 0);
      acc[c] = __builtin_amdgcn_mfma_f32_16x16x32_bf16(ah.v, bl.v, acc[c], 0, 0, 0);
      acc[c] = __builtin_amdgcn_mfma_f32_16x16x32_bf16(al.v, bh.v, acc[c], 0, 0, 0);
    }
  }

  const int colb = lane & 15, rgrp = lane >> 4;
#pragma unroll
  for (int r = 0; r < 4; r++) {
    int row = row0 + rgrp * 4 + r;
    if (row >= Nn) continue;
    float nr = norm[row];
    uint32_t m = mask[row * 16 + colb];
#pragma unroll
    for (int c = 0; c < 8; c++) {
      int ct = cy * 8 + c;
      int col = ct * 16 + colb;
      float v = fmaf(acc[c][r], nr, b1[col]);
      v = fmaxf(v, 0.f);
      v = ((m >> ct) & 1u) ? v * (2.0f * nr) : 0.f;   // dropout + pre-apply src norm
      h1sP[(size_t)row * N_H + col] = pack_hilo(v);
    }
  }
}

// ---------------- GEMM2 (split-bf16 MFMA): z = h1s @ W2 ----------------
__global__ __launch_bounds__(256) void k_gemm2_mfma(
    const uint32_t* __restrict__ h1sP, const uint4* __restrict__ WH,
    const uint4* __restrict__ WL, float* __restrict__ z, int Nn) {
  const int tid = threadIdx.x;
  const int wave = tid >> 6, lane = tid & 63;
  const int row0 = blockIdx.x * 64 + wave * 16;
  const int lrow = lane & 15, lk = lane >> 4;
  int arow = row0 + lrow; if (arow >= Nn) arow = Nn - 1;

  f32x4 acc[4];
#pragma unroll
  for (int ct = 0; ct < 4; ct++) acc[ct] = f32x4{0.f, 0.f, 0.f, 0.f};

#pragma unroll
  for (int ks = 0; ks < 8; ks++) {
    const uint4* ap = reinterpret_cast<const uint4*>(h1sP + (size_t)arow * N_H + ks * 32 + lk * 8);
    uint4 p0 = ap[0], p1 = ap[1];
    uint32_t pw[8] = {p0.x, p0.y, p0.z, p0.w, p1.x, p1.y, p1.z, p1.w};
    union { ushort u[8]; bf16x8 v; } ah, al;
#pragma unroll
    for (int j = 0; j < 8; j++) { ah.u[j] = (ushort)(pw[j] >> 16); al.u[j] = (ushort)(pw[j] & 0xffffu); }
#pragma unroll
    for (int ct = 0; ct < 4; ct++) {
      union { uint4 q; bf16x8 v; } bh, bl;
      bh.q = WH[(ct * 8 + ks) * 64 + lane];
      bl.q = WL[(ct * 8 + ks) * 64 + lane];
      acc[ct] = __builtin_amdgcn_mfma_f32_16x16x32_bf16(ah.v, bh.v, acc[ct], 0, 0, 0);
      acc[ct] = __builtin_amdgcn_mfma_f32_16x16x32_bf16(ah.v, bl.v, acc[ct], 0, 0, 0);
      acc[ct] = __builtin_amdgcn_mfma_f32_16x16x32_bf16(al.v, bh.v, acc[ct], 0, 0, 0);
    }
  }

  const int colb = lane & 15, rgrp = lane >> 4;
#pragma unroll
  for (int r = 0; r < 4; r++) {
    int row = row0 + rgrp * 4 + r;
    if (row >= Nn) continue;
#pragma unroll
    for (int ct = 0; ct < 4; ct++)
      z[(size_t)row * N_OUT + ct * 16 + colb] = acc[ct][r];
  }
}

// ---------------- layer-2 pull fused epilogue ----------------
__global__ __launch_bounds__(256) void k_pull2(
    const float* __restrict__ z, const float* __restrict__ norm,
    const float* __restrict__ b2, const int* __restrict__ rowptr,
    const int* __restrict__ esrc, float* __restrict__ out, int N) {
  int node = blockIdx.x * 4 + (threadIdx.x >> 6);
  if (node >= N) return;
  int lane = threadIdx.x & 63;
  int lo = rowptr[node], hi = rowptr[node + 1];
  float a0 = 0.f, a1 = 0.f, a2 = 0.f, a3 = 0.f;
  int e = lo;
  for (; e + 3 < hi; e += 4) {
    int s0 = esrc[e], s1 = esrc[e + 1], s2 = esrc[e + 2], s3 = esrc[e + 3];
    a0 += z[(size_t)s0 * N_OUT + lane];
    a1 += z[(size_t)s1 * N_OUT + lane];
    a2 += z[(size_t)s2 * N_OUT + lane];
    a3 += z[(size_t)s3 * N_OUT + lane];
  }
  for (; e < hi; e++) a0 += z[(size_t)esrc[e] * N_OUT + lane];
  out[(size_t)node * N_OUT + lane] = ((a0 + a1) + (a2 + a3)) * norm[node] + b2[lane];
}

extern "C" void kernel_launch(void* const* d_in, const int* in_sizes, int n_in,
                              void* d_out, int out_size, void* d_ws, size_t ws_size,
                              hipStream_t stream) {
  const float* h  = (const float*)d_in[0];
  const float* W1 = (const float*)d_in[1];
  const float* b1 = (const float*)d_in[2];
  const float* W2 = (const float*)d_in[3];
  const float* b2 = (const float*)d_in[4];
  const int* eidx = (const int*)d_in[5];
  const int N = in_sizes[0] / N_IN;
  const int E = in_sizes[5] / 2;
  const int NB = (N + 1023) / 1024;   // scan blocks (<= 64)

  char* ws = (char*)d_ws;
  size_t off = 0;
  auto alloc = [&](size_t bytes) { void* p = ws + off; off += (bytes + 511) & ~(size_t)511; return p; };
  int*      eflag  = (int*)alloc(sizeof(int));
  int*      deg    = (int*)alloc((size_t)N * 4);
  int*      rowptr = (int*)alloc((size_t)(N + 1) * 4);
  int*      cursor = (int*)alloc((size_t)N * 4);
  float*    norm   = (float*)alloc((size_t)N * 4);
  int*      esrc   = (int*)alloc((size_t)E * 4);
  int*      bsum   = (int*)alloc((size_t)64 * 4);
  int*      boff   = (int*)alloc((size_t)64 * 4);
  uint16_t* mask   = (uint16_t*)alloc((size_t)N * 16 * 2);
  uint4*    W1H    = (uint4*)alloc((size_t)16 * 4 * 64 * 16);
  uint4*    W1L    = (uint4*)alloc((size_t)16 * 4 * 64 * 16);
  uint4*    W2H    = (uint4*)alloc((size_t)4 * 8 * 64 * 16);
  uint4*    W2L    = (uint4*)alloc((size_t)4 * 8 * 64 * 16);
  uint32_t* aggP   = (uint32_t*)alloc((size_t)N * N_IN * 4);
  uint32_t* h1sP   = (uint32_t*)alloc((size_t)N * N_H * 4);
  float*    z      = (float*)aggP;   // aggP dead after gemm1; z is 12.8 MB < 25.6 MB
  float*    out    = (float*)d_out;

  hipMemsetAsync(deg, 0, (size_t)N * 4, stream);

  // graph-independent prep
  k_packW<<<(16 * 4 * 64 + 255) / 256, 256, 0, stream>>>(W1, W1H, W1L, N_H, 16, 4);
  k_packW<<<(4 * 8 * 64 + 255) / 256, 256, 0, stream>>>(W2, W2H, W2L, N_OUT, 4, 8);
  k_mask<<<(N * 16 + 255) / 256, 256, 0, stream>>>(mask, N);

  k_detect<<<1, 256, 0, stream>>>(eidx, E, eflag);
  k_deg<<<(E + 255) / 256, 256, 0, stream>>>(eidx, deg, E, eflag);
  k_scanA<<<NB, 256, 0, stream>>>(deg, bsum, N);
  k_scanB<<<1, 64, 0, stream>>>(bsum, boff, rowptr + N, NB);
  k_scanC<<<NB, 256, 0, stream>>>(deg, boff, rowptr, norm, cursor, N);
  k_fill<<<(E + 255) / 256, 256, 0, stream>>>(eidx, cursor, esrc, E, eflag);
  k_sortlds<<<(N + 255) / 256, 256, 0, stream>>>(esrc, rowptr, N);

  k_pull1<<<(N + 3) / 4, 256, 0, stream>>>(h, norm, rowptr, esrc, aggP, N);

  dim3 g1((N + 63) / 64, 2);
  k_gemm1_mfma<<<g1, 256, 0, stream>>>(aggP, W1H, W1L, b1, norm, mask, h1sP, N);
  k_gemm2_mfma<<<(N + 63) / 64, 256, 0, stream>>>(h1sP, W2H, W2L, z, N);

  k_pull2<<<(N + 3) / 4, 256, 0, stream>>>(z, norm, b2, rowptr, esrc, out, N);
}

// Round 6
// 317.718 us; speedup vs baseline: 1.0333x; 1.0333x over previous
//
#include <hip/hip_runtime.h>
#include <stdint.h>

#define N_IN  128
#define N_H   256
#define N_OUT 64
#define CHK   2048   // edges per bucketing block

typedef __attribute__((ext_vector_type(8))) __bf16 bf16x8;
typedef __attribute__((ext_vector_type(4))) float f32x4;

// ---------------- Threefry-2x32 (JAX-compatible) ----------------
__device__ __forceinline__ void tf4(uint32_t& x0, uint32_t& x1,
                                    const int r0, const int r1, const int r2, const int r3) {
  x0 += x1; x1 = (x1 << r0) | (x1 >> (32 - r0)); x1 ^= x0;
  x0 += x1; x1 = (x1 << r1) | (x1 >> (32 - r1)); x1 ^= x0;
  x0 += x1; x1 = (x1 << r2) | (x1 >> (32 - r2)); x1 ^= x0;
  x0 += x1; x1 = (x1 << r3) | (x1 >> (32 - r3)); x1 ^= x0;
}

__device__ __forceinline__ uint2 threefry2x32(uint32_t k0, uint32_t k1, uint32_t x0, uint32_t x1) {
  const uint32_t k2 = k0 ^ k1 ^ 0x1BD11BDAu;
  x0 += k0; x1 += k1;
  tf4(x0, x1, 13, 15, 26, 6);   x0 += k1; x1 += k2 + 1u;
  tf4(x0, x1, 17, 29, 16, 24);  x0 += k2; x1 += k0 + 2u;
  tf4(x0, x1, 13, 15, 26, 6);   x0 += k0; x1 += k1 + 3u;
  tf4(x0, x1, 17, 29, 16, 24);  x0 += k1; x1 += k2 + 4u;
  tf4(x0, x1, 13, 15, 26, 6);   x0 += k2; x1 += k0 + 5u;
  return make_uint2(x0, x1);
}

// ---------------- dropout mask precompute ----------------
__global__ __launch_bounds__(256) void k_mask(uint16_t* __restrict__ mask, int N) {
  int g = blockIdx.x * 256 + threadIdx.x;
  if (g >= N * 16) return;
  uint32_t row = (uint32_t)(g >> 4), colb = (uint32_t)(g & 15);
  uint32_t base = row * 256u + colb;
  uint32_t m = 0;
#pragma unroll
  for (int ct = 0; ct < 16; ct++) {
    uint2 o = threefry2x32(0u, 42u, 0u, base + (uint32_t)ct * 16u);
    uint32_t bits = o.x ^ o.y;
    m |= ((~bits) >> 31) << ct;   // keep <=> top bit clear
  }
  mask[g] = (uint16_t)m;
}

// split f32 -> (hi,lo) bf16 bit patterns packed in one u32: (hi<<16)|lo
__device__ __forceinline__ uint32_t pack_hilo(float v) {
  uint32_t bits = __builtin_bit_cast(uint32_t, v);
  uint32_t hi = bits & 0xffff0000u;
  float lo = v - __builtin_bit_cast(float, hi);
  uint32_t lob = __builtin_bit_cast(uint32_t, lo) >> 16;
  return hi | lob;
}

// ---------------- edge-index layout detection (int64 vs int32) ----------------
__global__ void k_detect(const int* __restrict__ e, int E, int* __restrict__ flag) {
  __shared__ int s_nz;
  if (threadIdx.x == 0) s_nz = 0;
  __syncthreads();
  int n = E < 2048 ? E : 2048;
  for (int i = threadIdx.x; i < n; i += 256)
    if (e[2 * i + 1] != 0) atomicAdd(&s_nz, 1);
  __syncthreads();
  if (threadIdx.x == 0) *flag = (s_nz == 0) ? 2 : 1;
}

// ---------------- CSR build ----------------
__global__ void k_deg(const int* __restrict__ eidx, int* __restrict__ deg, int E,
                      const int* __restrict__ flag) {
  int e = blockIdx.x * 256 + threadIdx.x;
  if (e >= E) return;
  int stride = *flag;
  int d = eidx[(size_t)(E + e) * stride];
  atomicAdd(deg + d, 1);
}

// hierarchical scan, phase A: per-block (1024 elems) sum
__global__ __launch_bounds__(256) void k_scanA(const int* __restrict__ deg,
                                               int* __restrict__ bsum, int N) {
  const int b = blockIdx.x, t = threadIdx.x;
  const int base = b * 1024 + t * 4;
  int s = 0;
  if (base + 3 < N) {
    int4 v = *reinterpret_cast<const int4*>(deg + base);
    s = v.x + v.y + v.z + v.w;
  } else {
    for (int i = 0; i < 4; i++) if (base + i < N) s += deg[base + i];
  }
  __shared__ int ws[4];
#pragma unroll
  for (int off = 32; off; off >>= 1) s += __shfl_down(s, off);
  if ((t & 63) == 0) ws[t >> 6] = s;
  __syncthreads();
  if (t == 0) bsum[b] = ws[0] + ws[1] + ws[2] + ws[3];
}

// phase B: single-wave exclusive scan of block sums (NB <= 64); writes rowptr[N]
__global__ void k_scanB(const int* __restrict__ bsum, int* __restrict__ boff,
                        int* __restrict__ rowptrN, int NB) {
  int t = threadIdx.x;   // 64 threads
  int x = (t < NB) ? bsum[t] : 0;
  int v = x;
#pragma unroll
  for (int off = 1; off < 64; off <<= 1) {
    int u = __shfl_up(v, off);
    if (t >= off) v += u;
  }
  if (t < NB) boff[t] = v - x;
  if (t == 63) *rowptrN = v;
}

// phase C: per-block local scan + boff, fused norm + cursor
__global__ __launch_bounds__(256) void k_scanC(const int* __restrict__ deg,
                                               const int* __restrict__ boff,
                                               int* __restrict__ rowptr,
                                               float* __restrict__ norm,
                                               int* __restrict__ cursor, int N) {
  __shared__ int sums[256];
  const int b = blockIdx.x, t = threadIdx.x;
  const int base = b * 1024 + t * 4;
  int d[4]; int s = 0;
#pragma unroll
  for (int i = 0; i < 4; i++) { d[i] = (base + i < N) ? deg[base + i] : 0; s += d[i]; }
  sums[t] = s;
  __syncthreads();
  for (int off = 1; off < 256; off <<= 1) {
    int u = (t >= off) ? sums[t - off] : 0;
    __syncthreads();
    sums[t] += u;
    __syncthreads();
  }
  int run = boff[b] + ((t == 0) ? 0 : sums[t - 1]);
#pragma unroll
  for (int i = 0; i < 4; i++) {
    if (base + i < N) {
      rowptr[base + i] = run;
      cursor[base + i] = run;
      norm[base + i] = d[i] > 0 ? rsqrtf((float)d[i]) : 1.0f;
      run += d[i];
    }
  }
}

// ---------------- edge bucketing (by dst>>8; valid for N <= 65536) ----------------
__global__ __launch_bounds__(256) void k_bhist(const int* __restrict__ eidx, int E,
                                               const int* __restrict__ flag,
                                               int* __restrict__ bktCnt) {
  __shared__ int hist[256];
  hist[threadIdx.x] = 0;
  __syncthreads();
  int stride = *flag;
  int base = blockIdx.x * CHK;
#pragma unroll
  for (int i = 0; i < 8; i++) {
    int e = base + i * 256 + threadIdx.x;
    if (e < E) {
      int d = eidx[(size_t)(E + e) * stride];
      atomicAdd(&hist[d >> 8], 1);
    }
  }
  __syncthreads();
  int hv = hist[threadIdx.x];
  if (hv) atomicAdd(&bktCnt[threadIdx.x], hv);
}

// 256-bin exclusive scan -> bucket cursors
__global__ __launch_bounds__(256) void k_bscan(const int* __restrict__ bktCnt,
                                               int* __restrict__ bktCur) {
  __shared__ int s[256];
  const int t = threadIdx.x;
  int x = bktCnt[t];
  s[t] = x;
  __syncthreads();
  for (int off = 1; off < 256; off <<= 1) {
    int u = (t >= off) ? s[t - off] : 0;
    __syncthreads();
    s[t] += u;
    __syncthreads();
  }
  bktCur[t] = s[t] - x;   // exclusive
}

__global__ __launch_bounds__(256) void k_bscatter(const int* __restrict__ eidx, int E,
                                                  const int* __restrict__ flag,
                                                  int* __restrict__ bktCur,
                                                  uint2* __restrict__ eb) {
  __shared__ int hist[256];
  __shared__ int base[256];
  const int t = threadIdx.x;
  hist[t] = 0;
  __syncthreads();
  int stride = *flag;
  int cb = blockIdx.x * CHK;
  int dc[8], sc[8];
#pragma unroll
  for (int i = 0; i < 8; i++) {
    int e = cb + i * 256 + t;
    if (e < E) {
      dc[i] = eidx[(size_t)(E + e) * stride];
      sc[i] = eidx[(size_t)e * stride];
      atomicAdd(&hist[dc[i] >> 8], 1);
    } else dc[i] = -1;
  }
  __syncthreads();
  int h = hist[t];
  if (h) base[t] = atomicAdd(&bktCur[t], h);
  __syncthreads();
  hist[t] = 0;   // reuse as intra-block cursor
  __syncthreads();
#pragma unroll
  for (int i = 0; i < 8; i++) {
    if (dc[i] >= 0) {
      int b = dc[i] >> 8;
      int r = atomicAdd(&hist[b], 1);
      eb[base[b] + r] = make_uint2((unsigned)sc[i], (unsigned)dc[i]);
    }
  }
}

// final fill: bucketed edges -> esrc via per-dst cursor (all L2-local per bucket)
__global__ void k_fill2(const uint2* __restrict__ eb, int* __restrict__ cursor,
                        int* __restrict__ esrc, int E) {
  int e = blockIdx.x * 256 + threadIdx.x;
  if (e >= E) return;
  uint2 r = eb[e];
  int pos = atomicAdd(cursor + r.y, 1);
  esrc[pos] = (int)r.x;
}

// per-row insertion sort in LDS (canonical deterministic order)
__global__ __launch_bounds__(256) void k_sortlds(int* __restrict__ esrc,
                                                 const int* __restrict__ rowptr, int N) {
  __shared__ int buf[64 * 256];
  int n = blockIdx.x * 256 + threadIdx.x;
  if (n >= N) return;
  const int t = threadIdx.x;
  int lo = rowptr[n], hi = rowptr[n + 1], d = hi - lo;
  if (d <= 64) {
    for (int i = 0; i < d; i++) buf[i * 256 + t] = esrc[lo + i];
    for (int i = 1; i < d; i++) {
      int v = buf[i * 256 + t];
      int j = i - 1;
      while (j >= 0 && buf[j * 256 + t] > v) { buf[(j + 1) * 256 + t] = buf[j * 256 + t]; j--; }
      buf[(j + 1) * 256 + t] = v;
    }
    for (int i = 0; i < d; i++) esrc[lo + i] = buf[i * 256 + t];
  } else {
    for (int i = lo + 1; i < hi; i++) {
      int v = esrc[i];
      int j = i - 1;
      while (j >= lo && esrc[j] > v) { esrc[j + 1] = esrc[j]; j--; }
      esrc[j + 1] = v;
    }
  }
}

// ---------------- layer-1 pull: 2 nodes/wave, 32 lanes x float4, 4-edge unroll ----------------
__global__ __launch_bounds__(256) void k_pull1(
    const float* __restrict__ h, const float* __restrict__ norm,
    const int* __restrict__ rowptr, const int* __restrict__ esrc,
    uint32_t* __restrict__ aggP, int N) {
  int node = blockIdx.x * 8 + (threadIdx.x >> 5);
  if (node >= N) return;
  int lane = threadIdx.x & 31;
  int lo = rowptr[node], hi = rowptr[node + 1];
  float4 a0 = {0,0,0,0}, a1 = {0,0,0,0}, a2 = {0,0,0,0}, a3 = {0,0,0,0};
  int e = lo;
  for (; e + 3 < hi; e += 4) {
    int s0 = esrc[e], s1 = esrc[e + 1], s2 = esrc[e + 2], s3 = esrc[e + 3];
    float n0 = norm[s0], n1 = norm[s1], n2 = norm[s2], n3 = norm[s3];
    float4 v0 = *reinterpret_cast<const float4*>(h + (size_t)s0 * N_IN + lane * 4);
    float4 v1 = *reinterpret_cast<const float4*>(h + (size_t)s1 * N_IN + lane * 4);
    float4 v2 = *reinterpret_cast<const float4*>(h + (size_t)s2 * N_IN + lane * 4);
    float4 v3 = *reinterpret_cast<const float4*>(h + (size_t)s3 * N_IN + lane * 4);
    a0.x = fmaf(v0.x, n0, a0.x); a0.y = fmaf(v0.y, n0, a0.y);
    a0.z = fmaf(v0.z, n0, a0.z); a0.w = fmaf(v0.w, n0, a0.w);
    a1.x = fmaf(v1.x, n1, a1.x); a1.y = fmaf(v1.y, n1, a1.y);
    a1.z = fmaf(v1.z, n1, a1.z); a1.w = fmaf(v1.w, n1, a1.w);
    a2.x = fmaf(v2.x, n2, a2.x); a2.y = fmaf(v2.y, n2, a2.y);
    a2.z = fmaf(v2.z, n2, a2.z); a2.w = fmaf(v2.w, n2, a2.w);
    a3.x = fmaf(v3.x, n3, a3.x); a3.y = fmaf(v3.y, n3, a3.y);
    a3.z = fmaf(v3.z, n3, a3.z); a3.w = fmaf(v3.w, n3, a3.w);
  }
  for (; e < hi; e++) {
    int s0 = esrc[e];
    float n0 = norm[s0];
    float4 v0 = *reinterpret_cast<const float4*>(h + (size_t)s0 * N_IN + lane * 4);
    a0.x = fmaf(v0.x, n0, a0.x); a0.y = fmaf(v0.y, n0, a0.y);
    a0.z = fmaf(v0.z, n0, a0.z); a0.w = fmaf(v0.w, n0, a0.w);
  }
  float4 r;
  r.x = (a0.x + a1.x) + (a2.x + a3.x);
  r.y = (a0.y + a1.y) + (a2.y + a3.y);
  r.z = (a0.z + a1.z) + (a2.z + a3.z);
  r.w = (a0.w + a1.w) + (a2.w + a3.w);
  uint4 p = make_uint4(pack_hilo(r.x), pack_hilo(r.y), pack_hilo(r.z), pack_hilo(r.w));
  *reinterpret_cast<uint4*>(aggP + (size_t)node * N_IN + lane * 4) = p;
}

// ---------------- W pack: fragment-order (hi,lo) bf16 planes ----------------
__global__ void k_packW(const float* __restrict__ W, uint4* __restrict__ WH,
                        uint4* __restrict__ WL, int Ncols, int nct, int nks) {
  int g = blockIdx.x * 256 + threadIdx.x;
  if (g >= nct * nks * 64) return;
  int lane = g & 63;
  int grp = g >> 6;
  int ks = grp % nks, ct = grp / nks;
  int k0 = ks * 32 + (lane >> 4) * 8;
  int col = ct * 16 + (lane & 15);
  uint32_t hb[8], lb[8];
#pragma unroll
  for (int j = 0; j < 8; j++) {
    float w = W[(size_t)(k0 + j) * Ncols + col];
    uint32_t bits = __builtin_bit_cast(uint32_t, w);
    uint32_t hi = bits & 0xffff0000u;
    float lo = w - __builtin_bit_cast(float, hi);
    hb[j] = hi >> 16;
    lb[j] = __builtin_bit_cast(uint32_t, lo) >> 16;
  }
  WH[g] = make_uint4(hb[0] | (hb[1] << 16), hb[2] | (hb[3] << 16),
                     hb[4] | (hb[5] << 16), hb[6] | (hb[7] << 16));
  WL[g] = make_uint4(lb[0] | (lb[1] << 16), lb[2] | (lb[3] << 16),
                     lb[4] | (lb[5] << 16), lb[6] | (lb[7] << 16));
}

// ---------------- GEMM1 (split-bf16 MFMA, no LDS, col-split by blockIdx.y) ----------------
__global__ __launch_bounds__(256) void k_gemm1_mfma(
    const uint32_t* __restrict__ aggP, const uint4* __restrict__ WH,
    const uint4* __restrict__ WL, const float* __restrict__ b1,
    const float* __restrict__ norm, const uint16_t* __restrict__ mask,
    uint32_t* __restrict__ h1sP, int Nn) {
  const int tid = threadIdx.x;
  const int wave = tid >> 6, lane = tid & 63;
  const int row0 = blockIdx.x * 64 + wave * 16;
  const int cy = blockIdx.y;
  const int lrow = lane & 15, lk = lane >> 4;
  int arow = row0 + lrow; if (arow >= Nn) arow = Nn - 1;

  f32x4 acc[8];
#pragma unroll
  for (int c = 0; c < 8; c++) acc[c] = f32x4{0.f, 0.f, 0.f, 0.f};

#pragma unroll
  for (int ks = 0; ks < 4; ks++) {
    const uint4* ap = reinterpret_cast<const uint4*>(aggP + (size_t)arow * N_IN + ks * 32 + lk * 8);
    uint4 p0 = ap[0], p1 = ap[1];
    uint32_t pw[8] = {p0.x, p0.y, p0.z, p0.w, p1.x, p1.y, p1.z, p1.w};
    union { ushort u[8]; bf16x8 v; } ah, al;
#pragma unroll
    for (int j = 0; j < 8; j++) { ah.u[j] = (ushort)(pw[j] >> 16); al.u[j] = (ushort)(pw[j] & 0xffffu); }
#pragma unroll
    for (int c = 0; c < 8; c++) {
      int ct = cy * 8 + c;
      union { uint4 q; bf16x8 v; } bh, bl;
      bh.q = WH[(ct * 4 + ks) * 64 + lane];
      bl.q = WL[(ct * 4 + ks) * 64 + lane];
      acc[c] = __builtin_amdgcn_mfma_f32_16x16x32_bf16(ah.v, bh.v, acc[c], 0, 0, 0);
      acc[c] = __builtin_amdgcn_mfma_f32_16x16x32_bf16(ah.v, bl.v, acc[c], 0, 0, 0);
      acc[c] = __builtin_amdgcn_mfma_f32_16x16x32_bf16(al.v, bh.v, acc[c], 0, 0, 0);
    }
  }

  const int colb = lane & 15, rgrp = lane >> 4;
#pragma unroll
  for (int r = 0; r < 4; r++) {
    int row = row0 + rgrp * 4 + r;
    if (row >= Nn) continue;
    float nr = norm[row];
    uint32_t m = mask[row * 16 + colb];
#pragma unroll
    for (int c = 0; c < 8; c++) {
      int ct = cy * 8 + c;
      int col = ct * 16 + colb;
      float v = fmaf(acc[c][r], nr, b1[col]);
      v = fmaxf(v, 0.f);
      v = ((m >> ct) & 1u) ? v * (2.0f * nr) : 0.f;   // dropout + pre-apply src norm
      h1sP[(size_t)row * N_H + col] = pack_hilo(v);
    }
  }
}

// ---------------- GEMM2 (split-bf16 MFMA): z = h1s @ W2 ----------------
__global__ __launch_bounds__(256) void k_gemm2_mfma(
    const uint32_t* __restrict__ h1sP, const uint4* __restrict__ WH,
    const uint4* __restrict__ WL, float* __restrict__ z, int Nn) {
  const int tid = threadIdx.x;
  const int wave = tid >> 6, lane = tid & 63;
  const int row0 = blockIdx.x * 64 + wave * 16;
  const int lrow = lane & 15, lk = lane >> 4;
  int arow = row0 + lrow; if (arow >= Nn) arow = Nn - 1;

  f32x4 acc[4];
#pragma unroll
  for (int ct = 0; ct < 4; ct++) acc[ct] = f32x4{0.f, 0.f, 0.f, 0.f};

#pragma unroll
  for (int ks = 0; ks < 8; ks++) {
    const uint4* ap = reinterpret_cast<const uint4*>(h1sP + (size_t)arow * N_H + ks * 32 + lk * 8);
    uint4 p0 = ap[0], p1 = ap[1];
    uint32_t pw[8] = {p0.x, p0.y, p0.z, p0.w, p1.x, p1.y, p1.z, p1.w};
    union { ushort u[8]; bf16x8 v; } ah, al;
#pragma unroll
    for (int j = 0; j < 8; j++) { ah.u[j] = (ushort)(pw[j] >> 16); al.u[j] = (ushort)(pw[j] & 0xffffu); }
#pragma unroll
    for (int ct = 0; ct < 4; ct++) {
      union { uint4 q; bf16x8 v; } bh, bl;
      bh.q = WH[(ct * 8 + ks) * 64 + lane];
      bl.q = WL[(ct * 8 + ks) * 64 + lane];
      acc[ct] = __builtin_amdgcn_mfma_f32_16x16x32_bf16(ah.v, bh.v, acc[ct], 0, 0, 0);
      acc[ct] = __builtin_amdgcn_mfma_f32_16x16x32_bf16(ah.v, bl.v, acc[ct], 0, 0, 0);
      acc[ct] = __builtin_amdgcn_mfma_f32_16x16x32_bf16(al.v, bh.v, acc[ct], 0, 0, 0);
    }
  }

  const int colb = lane & 15, rgrp = lane >> 4;
#pragma unroll
  for (int r = 0; r < 4; r++) {
    int row = row0 + rgrp * 4 + r;
    if (row >= Nn) continue;
#pragma unroll
    for (int ct = 0; ct < 4; ct++)
      z[(size_t)row * N_OUT + ct * 16 + colb] = acc[ct][r];
  }
}

// ---------------- layer-2 pull fused epilogue ----------------
__global__ __launch_bounds__(256) void k_pull2(
    const float* __restrict__ z, const float* __restrict__ norm,
    const float* __restrict__ b2, const int* __restrict__ rowptr,
    const int* __restrict__ esrc, float* __restrict__ out, int N) {
  int node = blockIdx.x * 4 + (threadIdx.x >> 6);
  if (node >= N) return;
  int lane = threadIdx.x & 63;
  int lo = rowptr[node], hi = rowptr[node + 1];
  float a0 = 0.f, a1 = 0.f, a2 = 0.f, a3 = 0.f;
  int e = lo;
  for (; e + 3 < hi; e += 4) {
    int s0 = esrc[e], s1 = esrc[e + 1], s2 = esrc[e + 2], s3 = esrc[e + 3];
    a0 += z[(size_t)s0 * N_OUT + lane];
    a1 += z[(size_t)s1 * N_OUT + lane];
    a2 += z[(size_t)s2 * N_OUT + lane];
    a3 += z[(size_t)s3 * N_OUT + lane];
  }
  for (; e < hi; e++) a0 += z[(size_t)esrc[e] * N_OUT + lane];
  out[(size_t)node * N_OUT + lane] = ((a0 + a1) + (a2 + a3)) * norm[node] + b2[lane];
}

extern "C" void kernel_launch(void* const* d_in, const int* in_sizes, int n_in,
                              void* d_out, int out_size, void* d_ws, size_t ws_size,
                              hipStream_t stream) {
  const float* h  = (const float*)d_in[0];
  const float* W1 = (const float*)d_in[1];
  const float* b1 = (const float*)d_in[2];
  const float* W2 = (const float*)d_in[3];
  const float* b2 = (const float*)d_in[4];
  const int* eidx = (const int*)d_in[5];
  const int N = in_sizes[0] / N_IN;
  const int E = in_sizes[5] / 2;
  const int NB = (N + 1023) / 1024;        // scan blocks (<= 64)
  const int NBE = (E + CHK - 1) / CHK;     // bucketing blocks

  char* ws = (char*)d_ws;
  size_t off = 0;
  auto alloc = [&](size_t bytes) { void* p = ws + off; off += (bytes + 511) & ~(size_t)511; return p; };
  int*      eflag  = (int*)alloc(sizeof(int));
  int*      deg    = (int*)alloc((size_t)N * 4);
  int*      rowptr = (int*)alloc((size_t)(N + 1) * 4);
  int*      cursor = (int*)alloc((size_t)N * 4);
  float*    norm   = (float*)alloc((size_t)N * 4);
  int*      esrc   = (int*)alloc((size_t)E * 4);
  int*      bsum   = (int*)alloc((size_t)64 * 4);
  int*      boff   = (int*)alloc((size_t)64 * 4);
  int*      bktCnt = (int*)alloc((size_t)256 * 4);
  int*      bktCur = (int*)alloc((size_t)256 * 4);
  uint16_t* mask   = (uint16_t*)alloc((size_t)N * 16 * 2);
  uint4*    W1H    = (uint4*)alloc((size_t)16 * 4 * 64 * 16);
  uint4*    W1L    = (uint4*)alloc((size_t)16 * 4 * 64 * 16);
  uint4*    W2H    = (uint4*)alloc((size_t)4 * 8 * 64 * 16);
  uint4*    W2L    = (uint4*)alloc((size_t)4 * 8 * 64 * 16);
  uint32_t* aggP   = (uint32_t*)alloc((size_t)N * N_IN * 4);
  uint32_t* h1sP   = (uint32_t*)alloc((size_t)N * N_H * 4);
  uint2*    eb     = (uint2*)aggP;   // 6.4 MB <= 25.6 MB; dead before pull1 writes aggP
  float*    z      = (float*)aggP;   // aggP dead after gemm1
  float*    out    = (float*)d_out;

  hipMemsetAsync(deg, 0, (size_t)N * 4, stream);
  hipMemsetAsync(bktCnt, 0, 256 * 4, stream);

  // graph-independent prep
  k_packW<<<(16 * 4 * 64 + 255) / 256, 256, 0, stream>>>(W1, W1H, W1L, N_H, 16, 4);
  k_packW<<<(4 * 8 * 64 + 255) / 256, 256, 0, stream>>>(W2, W2H, W2L, N_OUT, 4, 8);
  k_mask<<<(N * 16 + 255) / 256, 256, 0, stream>>>(mask, N);

  k_detect<<<1, 256, 0, stream>>>(eidx, E, eflag);
  k_deg<<<(E + 255) / 256, 256, 0, stream>>>(eidx, deg, E, eflag);
  k_scanA<<<NB, 256, 0, stream>>>(deg, bsum, N);
  k_scanB<<<1, 64, 0, stream>>>(bsum, boff, rowptr + N, NB);
  k_scanC<<<NB, 256, 0, stream>>>(deg, boff, rowptr, norm, cursor, N);

  // bucketed edge fill (replaces single scattered k_fill)
  k_bhist<<<NBE, 256, 0, stream>>>(eidx, E, eflag, bktCnt);
  k_bscan<<<1, 256, 0, stream>>>(bktCnt, bktCur);
  k_bscatter<<<NBE, 256, 0, stream>>>(eidx, E, eflag, bktCur, eb);
  k_fill2<<<(E + 255) / 256, 256, 0, stream>>>(eb, cursor, esrc, E);
  k_sortlds<<<(N + 255) / 256, 256, 0, stream>>>(esrc, rowptr, N);

  k_pull1<<<(N + 7) / 8, 256, 0, stream>>>(h, norm, rowptr, esrc, aggP, N);

  dim3 g1((N + 63) / 64, 2);
  k_gemm1_mfma<<<g1, 256, 0, stream>>>(aggP, W1H, W1L, b1, norm, mask, h1sP, N);
  k_gemm2_mfma<<<(N + 63) / 64, 256, 0, stream>>>(h1sP, W2H, W2L, z, N);

  k_pull2<<<(N + 3) / 4, 256, 0, stream>>>(z, norm, b2, rowptr, esrc, out, N);
}

// Round 7
// 258.444 us; speedup vs baseline: 1.2703x; 1.2293x over previous
//
#include <hip/hip_runtime.h>
#include <stdint.h>

#define N_IN  128
#define N_H   256
#define N_OUT 64
#define CHK   2048   // edges per bucketing block

typedef __attribute__((ext_vector_type(8))) __bf16 bf16x8;
typedef __attribute__((ext_vector_type(4))) float f32x4;

// ---------------- Threefry-2x32 (JAX-compatible) ----------------
__device__ __forceinline__ void tf4(uint32_t& x0, uint32_t& x1,
                                    const int r0, const int r1, const int r2, const int r3) {
  x0 += x1; x1 = (x1 << r0) | (x1 >> (32 - r0)); x1 ^= x0;
  x0 += x1; x1 = (x1 << r1) | (x1 >> (32 - r1)); x1 ^= x0;
  x0 += x1; x1 = (x1 << r2) | (x1 >> (32 - r2)); x1 ^= x0;
  x0 += x1; x1 = (x1 << r3) | (x1 >> (32 - r3)); x1 ^= x0;
}

__device__ __forceinline__ uint2 threefry2x32(uint32_t k0, uint32_t k1, uint32_t x0, uint32_t x1) {
  const uint32_t k2 = k0 ^ k1 ^ 0x1BD11BDAu;
  x0 += k0; x1 += k1;
  tf4(x0, x1, 13, 15, 26, 6);   x0 += k1; x1 += k2 + 1u;
  tf4(x0, x1, 17, 29, 16, 24);  x0 += k2; x1 += k0 + 2u;
  tf4(x0, x1, 13, 15, 26, 6);   x0 += k0; x1 += k1 + 3u;
  tf4(x0, x1, 17, 29, 16, 24);  x0 += k1; x1 += k2 + 4u;
  tf4(x0, x1, 13, 15, 26, 6);   x0 += k2; x1 += k0 + 5u;
  return make_uint2(x0, x1);
}

// ---------------- dropout mask precompute ----------------
__global__ __launch_bounds__(256) void k_mask(uint16_t* __restrict__ mask, int N) {
  int g = blockIdx.x * 256 + threadIdx.x;
  if (g >= N * 16) return;
  uint32_t row = (uint32_t)(g >> 4), colb = (uint32_t)(g & 15);
  uint32_t base = row * 256u + colb;
  uint32_t m = 0;
#pragma unroll
  for (int ct = 0; ct < 16; ct++) {
    uint2 o = threefry2x32(0u, 42u, 0u, base + (uint32_t)ct * 16u);
    uint32_t bits = o.x ^ o.y;
    m |= ((~bits) >> 31) << ct;   // keep <=> top bit clear
  }
  mask[g] = (uint16_t)m;
}

// split f32 -> (hi,lo) bf16 bit patterns packed in one u32: (hi<<16)|lo
__device__ __forceinline__ uint32_t pack_hilo(float v) {
  uint32_t bits = __builtin_bit_cast(uint32_t, v);
  uint32_t hi = bits & 0xffff0000u;
  float lo = v - __builtin_bit_cast(float, hi);
  uint32_t lob = __builtin_bit_cast(uint32_t, lo) >> 16;
  return hi | lob;
}

// ---------------- edge-index layout detection (int64 vs int32) ----------------
__global__ void k_detect(const int* __restrict__ e, int E, int* __restrict__ flag) {
  __shared__ int s_nz;
  if (threadIdx.x == 0) s_nz = 0;
  __syncthreads();
  int n = E < 2048 ? E : 2048;
  for (int i = threadIdx.x; i < n; i += 256)
    if (e[2 * i + 1] != 0) atomicAdd(&s_nz, 1);
  __syncthreads();
  if (threadIdx.x == 0) *flag = (s_nz == 0) ? 2 : 1;
}

// ---------------- edge bucketing (by dst>>8; valid for N <= 65536) ----------------
__global__ __launch_bounds__(256) void k_bhist(const int* __restrict__ eidx, int E,
                                               const int* __restrict__ flag,
                                               int* __restrict__ bktCnt) {
  __shared__ int hist[256];
  hist[threadIdx.x] = 0;
  __syncthreads();
  int stride = *flag;
  int base = blockIdx.x * CHK;
#pragma unroll
  for (int i = 0; i < 8; i++) {
    int e = base + i * 256 + threadIdx.x;
    if (e < E) {
      int d = eidx[(size_t)(E + e) * stride];
      atomicAdd(&hist[d >> 8], 1);
    }
  }
  __syncthreads();
  int hv = hist[threadIdx.x];
  if (hv) atomicAdd(&bktCnt[threadIdx.x], hv);
}

// 256-bin exclusive scan -> stable bucket offsets + mutable cursors
__global__ __launch_bounds__(256) void k_bscan(const int* __restrict__ bktCnt,
                                               int* __restrict__ bktOff,
                                               int* __restrict__ bktCur) {
  __shared__ int s[256];
  const int t = threadIdx.x;
  int x = bktCnt[t];
  s[t] = x;
  __syncthreads();
  for (int off = 1; off < 256; off <<= 1) {
    int u = (t >= off) ? s[t - off] : 0;
    __syncthreads();
    s[t] += u;
    __syncthreads();
  }
  int excl = s[t] - x;
  bktOff[t] = excl;
  bktCur[t] = excl;
}

__global__ __launch_bounds__(256) void k_bscatter(const int* __restrict__ eidx, int E,
                                                  const int* __restrict__ flag,
                                                  int* __restrict__ bktCur,
                                                  uint2* __restrict__ eb) {
  __shared__ int hist[256];
  __shared__ int base[256];
  const int t = threadIdx.x;
  hist[t] = 0;
  __syncthreads();
  int stride = *flag;
  int cb = blockIdx.x * CHK;
  int dc[8], sc[8];
#pragma unroll
  for (int i = 0; i < 8; i++) {
    int e = cb + i * 256 + t;
    if (e < E) {
      dc[i] = eidx[(size_t)(E + e) * stride];
      sc[i] = eidx[(size_t)e * stride];
      atomicAdd(&hist[dc[i] >> 8], 1);
    } else dc[i] = -1;
  }
  __syncthreads();
  int h = hist[t];
  if (h) base[t] = atomicAdd(&bktCur[t], h);
  __syncthreads();
  hist[t] = 0;   // reuse as intra-block cursor
  __syncthreads();
#pragma unroll
  for (int i = 0; i < 8; i++) {
    if (dc[i] >= 0) {
      int b = dc[i] >> 8;
      int r = atomicAdd(&hist[b], 1);
      eb[base[b] + r] = make_uint2((unsigned)sc[i], (unsigned)dc[i]);
    }
  }
}

// ---------------- per-bucket CSR build: deg/rowptr/norm/esrc with zero global atomics ----------------
// one block per bucket; bucket b covers nodes [b*256, b*256+256)
__global__ __launch_bounds__(256) void k_bucket_csr(
    const uint2* __restrict__ eb, const int* __restrict__ bktOff,
    int* __restrict__ rowptr, float* __restrict__ norm,
    int* __restrict__ esrc, int N, int E) {
  __shared__ int cnt[256];
  __shared__ int pfx[256];
  __shared__ int cur[256];
  const int b = blockIdx.x, t = threadIdx.x;
  if (b == 0 && t == 0) rowptr[N] = E;
  if (b * 256 >= N) return;
  const int lo = bktOff[b];
  const int hi = (b < 255) ? bktOff[b + 1] : E;
  cnt[t] = 0;
  __syncthreads();
  for (int e = lo + t; e < hi; e += 256)
    atomicAdd(&cnt[eb[e].y & 255u], 1);
  __syncthreads();
  int x = cnt[t];
  pfx[t] = x;
  __syncthreads();
  for (int off = 1; off < 256; off <<= 1) {
    int u = (t >= off) ? pfx[t - off] : 0;
    __syncthreads();
    pfx[t] += u;
    __syncthreads();
  }
  int excl = pfx[t] - x;
  int node = b * 256 + t;
  if (node < N) {
    rowptr[node] = lo + excl;
    norm[node] = x > 0 ? rsqrtf((float)x) : 1.0f;
  }
  cur[t] = excl;
  __syncthreads();
  for (int e = lo + t; e < hi; e += 256) {
    uint2 r = eb[e];
    int d = (int)(r.y & 255u);
    int p = atomicAdd(&cur[d], 1);
    esrc[lo + p] = (int)r.x;
  }
}

// per-row insertion sort in LDS (canonical deterministic order)
__global__ __launch_bounds__(256) void k_sortlds(int* __restrict__ esrc,
                                                 const int* __restrict__ rowptr, int N) {
  __shared__ int buf[64 * 256];
  int n = blockIdx.x * 256 + threadIdx.x;
  if (n >= N) return;
  const int t = threadIdx.x;
  int lo = rowptr[n], hi = rowptr[n + 1], d = hi - lo;
  if (d <= 64) {
    for (int i = 0; i < d; i++) buf[i * 256 + t] = esrc[lo + i];
    for (int i = 1; i < d; i++) {
      int v = buf[i * 256 + t];
      int j = i - 1;
      while (j >= 0 && buf[j * 256 + t] > v) { buf[(j + 1) * 256 + t] = buf[j * 256 + t]; j--; }
      buf[(j + 1) * 256 + t] = v;
    }
    for (int i = 0; i < d; i++) esrc[lo + i] = buf[i * 256 + t];
  } else {
    for (int i = lo + 1; i < hi; i++) {
      int v = esrc[i];
      int j = i - 1;
      while (j >= lo && esrc[j] > v) { esrc[j + 1] = esrc[j]; j--; }
      esrc[j + 1] = v;
    }
  }
}

// ---------------- layer-1 pull: 2 nodes/wave, 32 lanes x float4, 4-edge unroll ----------------
__global__ __launch_bounds__(256) void k_pull1(
    const float* __restrict__ h, const float* __restrict__ norm,
    const int* __restrict__ rowptr, const int* __restrict__ esrc,
    uint32_t* __restrict__ aggP, int N) {
  int node = blockIdx.x * 8 + (threadIdx.x >> 5);
  if (node >= N) return;
  int lane = threadIdx.x & 31;
  int lo = rowptr[node], hi = rowptr[node + 1];
  float4 a0 = {0,0,0,0}, a1 = {0,0,0,0}, a2 = {0,0,0,0}, a3 = {0,0,0,0};
  int e = lo;
  for (; e + 3 < hi; e += 4) {
    int s0 = esrc[e], s1 = esrc[e + 1], s2 = esrc[e + 2], s3 = esrc[e + 3];
    float n0 = norm[s0], n1 = norm[s1], n2 = norm[s2], n3 = norm[s3];
    float4 v0 = *reinterpret_cast<const float4*>(h + (size_t)s0 * N_IN + lane * 4);
    float4 v1 = *reinterpret_cast<const float4*>(h + (size_t)s1 * N_IN + lane * 4);
    float4 v2 = *reinterpret_cast<const float4*>(h + (size_t)s2 * N_IN + lane * 4);
    float4 v3 = *reinterpret_cast<const float4*>(h + (size_t)s3 * N_IN + lane * 4);
    a0.x = fmaf(v0.x, n0, a0.x); a0.y = fmaf(v0.y, n0, a0.y);
    a0.z = fmaf(v0.z, n0, a0.z); a0.w = fmaf(v0.w, n0, a0.w);
    a1.x = fmaf(v1.x, n1, a1.x); a1.y = fmaf(v1.y, n1, a1.y);
    a1.z = fmaf(v1.z, n1, a1.z); a1.w = fmaf(v1.w, n1, a1.w);
    a2.x = fmaf(v2.x, n2, a2.x); a2.y = fmaf(v2.y, n2, a2.y);
    a2.z = fmaf(v2.z, n2, a2.z); a2.w = fmaf(v2.w, n2, a2.w);
    a3.x = fmaf(v3.x, n3, a3.x); a3.y = fmaf(v3.y, n3, a3.y);
    a3.z = fmaf(v3.z, n3, a3.z); a3.w = fmaf(v3.w, n3, a3.w);
  }
  for (; e < hi; e++) {
    int s0 = esrc[e];
    float n0 = norm[s0];
    float4 v0 = *reinterpret_cast<const float4*>(h + (size_t)s0 * N_IN + lane * 4);
    a0.x = fmaf(v0.x, n0, a0.x); a0.y = fmaf(v0.y, n0, a0.y);
    a0.z = fmaf(v0.z, n0, a0.z); a0.w = fmaf(v0.w, n0, a0.w);
  }
  float4 r;
  r.x = (a0.x + a1.x) + (a2.x + a3.x);
  r.y = (a0.y + a1.y) + (a2.y + a3.y);
  r.z = (a0.z + a1.z) + (a2.z + a3.z);
  r.w = (a0.w + a1.w) + (a2.w + a3.w);
  uint4 p = make_uint4(pack_hilo(r.x), pack_hilo(r.y), pack_hilo(r.z), pack_hilo(r.w));
  *reinterpret_cast<uint4*>(aggP + (size_t)node * N_IN + lane * 4) = p;
}

// ---------------- W pack: fragment-order (hi,lo) bf16 planes ----------------
__global__ void k_packW(const float* __restrict__ W, uint4* __restrict__ WH,
                        uint4* __restrict__ WL, int Ncols, int nct, int nks) {
  int g = blockIdx.x * 256 + threadIdx.x;
  if (g >= nct * nks * 64) return;
  int lane = g & 63;
  int grp = g >> 6;
  int ks = grp % nks, ct = grp / nks;
  int k0 = ks * 32 + (lane >> 4) * 8;
  int col = ct * 16 + (lane & 15);
  uint32_t hb[8], lb[8];
#pragma unroll
  for (int j = 0; j < 8; j++) {
    float w = W[(size_t)(k0 + j) * Ncols + col];
    uint32_t bits = __builtin_bit_cast(uint32_t, w);
    uint32_t hi = bits & 0xffff0000u;
    float lo = w - __builtin_bit_cast(float, hi);
    hb[j] = hi >> 16;
    lb[j] = __builtin_bit_cast(uint32_t, lo) >> 16;
  }
  WH[g] = make_uint4(hb[0] | (hb[1] << 16), hb[2] | (hb[3] << 16),
                     hb[4] | (hb[5] << 16), hb[6] | (hb[7] << 16));
  WL[g] = make_uint4(lb[0] | (lb[1] << 16), lb[2] | (lb[3] << 16),
                     lb[4] | (lb[5] << 16), lb[6] | (lb[7] << 16));
}

// ---------------- GEMM1 (split-bf16 MFMA, no LDS, col-split by blockIdx.y) ----------------
__global__ __launch_bounds__(256) void k_gemm1_mfma(
    const uint32_t* __restrict__ aggP, const uint4* __restrict__ WH,
    const uint4* __restrict__ WL, const float* __restrict__ b1,
    const float* __restrict__ norm, const uint16_t* __restrict__ mask,
    uint32_t* __restrict__ h1sP, int Nn) {
  const int tid = threadIdx.x;
  const int wave = tid >> 6, lane = tid & 63;
  const int row0 = blockIdx.x * 64 + wave * 16;
  const int cy = blockIdx.y;
  const int lrow = lane & 15, lk = lane >> 4;
  int arow = row0 + lrow; if (arow >= Nn) arow = Nn - 1;

  f32x4 acc[8];
#pragma unroll
  for (int c = 0; c < 8; c++) acc[c] = f32x4{0.f, 0.f, 0.f, 0.f};

#pragma unroll
  for (int ks = 0; ks < 4; ks++) {
    const uint4* ap = reinterpret_cast<const uint4*>(aggP + (size_t)arow * N_IN + ks * 32 + lk * 8);
    uint4 p0 = ap[0], p1 = ap[1];
    uint32_t pw[8] = {p0.x, p0.y, p0.z, p0.w, p1.x, p1.y, p1.z, p1.w};
    union { ushort u[8]; bf16x8 v; } ah, al;
#pragma unroll
    for (int j = 0; j < 8; j++) { ah.u[j] = (ushort)(pw[j] >> 16); al.u[j] = (ushort)(pw[j] & 0xffffu); }
#pragma unroll
    for (int c = 0; c < 8; c++) {
      int ct = cy * 8 + c;
      union { uint4 q; bf16x8 v; } bh, bl;
      bh.q = WH[(ct * 4 + ks) * 64 + lane];
      bl.q = WL[(ct * 4 + ks) * 64 + lane];
      acc[c] = __builtin_amdgcn_mfma_f32_16x16x32_bf16(ah.v, bh.v, acc[c], 0, 0, 0);
      acc[c] = __builtin_amdgcn_mfma_f32_16x16x32_bf16(ah.v, bl.v, acc[c], 0, 0, 0);
      acc[c] = __builtin_amdgcn_mfma_f32_16x16x32_bf16(al.v, bh.v, acc[c], 0, 0, 0);
    }
  }

  const int colb = lane & 15, rgrp = lane >> 4;
#pragma unroll
  for (int r = 0; r < 4; r++) {
    int row = row0 + rgrp * 4 + r;
    if (row >= Nn) continue;
    float nr = norm[row];
    uint32_t m = mask[row * 16 + colb];
#pragma unroll
    for (int c = 0; c < 8; c++) {
      int ct = cy * 8 + c;
      int col = ct * 16 + colb;
      float v = fmaf(acc[c][r], nr, b1[col]);
      v = fmaxf(v, 0.f);
      v = ((m >> ct) & 1u) ? v * (2.0f * nr) : 0.f;   // dropout + pre-apply src norm
      h1sP[(size_t)row * N_H + col] = pack_hilo(v);
    }
  }
}

// ---------------- GEMM2 (split-bf16 MFMA): z = h1s @ W2 ----------------
__global__ __launch_bounds__(256) void k_gemm2_mfma(
    const uint32_t* __restrict__ h1sP, const uint4* __restrict__ WH,
    const uint4* __restrict__ WL, float* __restrict__ z, int Nn) {
  const int tid = threadIdx.x;
  const int wave = tid >> 6, lane = tid & 63;
  const int row0 = blockIdx.x * 64 + wave * 16;
  const int lrow = lane & 15, lk = lane >> 4;
  int arow = row0 + lrow; if (arow >= Nn) arow = Nn - 1;

  f32x4 acc[4];
#pragma unroll
  for (int ct = 0; ct < 4; ct++) acc[ct] = f32x4{0.f, 0.f, 0.f, 0.f};

#pragma unroll
  for (int ks = 0; ks < 8; ks++) {
    const uint4* ap = reinterpret_cast<const uint4*>(h1sP + (size_t)arow * N_H + ks * 32 + lk * 8);
    uint4 p0 = ap[0], p1 = ap[1];
    uint32_t pw[8] = {p0.x, p0.y, p0.z, p0.w, p1.x, p1.y, p1.z, p1.w};
    union { ushort u[8]; bf16x8 v; } ah, al;
#pragma unroll
    for (int j = 0; j < 8; j++) { ah.u[j] = (ushort)(pw[j] >> 16); al.u[j] = (ushort)(pw[j] & 0xffffu); }
#pragma unroll
    for (int ct = 0; ct < 4; ct++) {
      union { uint4 q; bf16x8 v; } bh, bl;
      bh.q = WH[(ct * 8 + ks) * 64 + lane];
      bl.q = WL[(ct * 8 + ks) * 64 + lane];
      acc[ct] = __builtin_amdgcn_mfma_f32_16x16x32_bf16(ah.v, bh.v, acc[ct], 0, 0, 0);
      acc[ct] = __builtin_amdgcn_mfma_f32_16x16x32_bf16(ah.v, bl.v, acc[ct], 0, 0, 0);
      acc[ct] = __builtin_amdgcn_mfma_f32_16x16x32_bf16(al.v, bh.v, acc[ct], 0, 0, 0);
    }
  }

  const int colb = lane & 15, rgrp = lane >> 4;
#pragma unroll
  for (int r = 0; r < 4; r++) {
    int row = row0 + rgrp * 4 + r;
    if (row >= Nn) continue;
#pragma unroll
    for (int ct = 0; ct < 4; ct++)
      z[(size_t)row * N_OUT + ct * 16 + colb] = acc[ct][r];
  }
}

// ---------------- layer-2 pull fused epilogue: 2 nodes/wave, 32 lanes x float2 ----------------
__global__ __launch_bounds__(256) void k_pull2(
    const float* __restrict__ z, const float* __restrict__ norm,
    const float* __restrict__ b2, const int* __restrict__ rowptr,
    const int* __restrict__ esrc, float* __restrict__ out, int N) {
  int node = blockIdx.x * 8 + (threadIdx.x >> 5);
  if (node >= N) return;
  int lane = threadIdx.x & 31;
  int lo = rowptr[node], hi = rowptr[node + 1];
  float2 a0 = {0,0}, a1 = {0,0}, a2 = {0,0}, a3 = {0,0};
  int e = lo;
  for (; e + 3 < hi; e += 4) {
    int s0 = esrc[e], s1 = esrc[e + 1], s2 = esrc[e + 2], s3 = esrc[e + 3];
    float2 v0 = *reinterpret_cast<const float2*>(z + (size_t)s0 * N_OUT + lane * 2);
    float2 v1 = *reinterpret_cast<const float2*>(z + (size_t)s1 * N_OUT + lane * 2);
    float2 v2 = *reinterpret_cast<const float2*>(z + (size_t)s2 * N_OUT + lane * 2);
    float2 v3 = *reinterpret_cast<const float2*>(z + (size_t)s3 * N_OUT + lane * 2);
    a0.x += v0.x; a0.y += v0.y;
    a1.x += v1.x; a1.y += v1.y;
    a2.x += v2.x; a2.y += v2.y;
    a3.x += v3.x; a3.y += v3.y;
  }
  for (; e < hi; e++) {
    float2 v0 = *reinterpret_cast<const float2*>(z + (size_t)esrc[e] * N_OUT + lane * 2);
    a0.x += v0.x; a0.y += v0.y;
  }
  float nn = norm[node];
  float2 bb = *reinterpret_cast<const float2*>(b2 + lane * 2);
  float2 r;
  r.x = ((a0.x + a1.x) + (a2.x + a3.x)) * nn + bb.x;
  r.y = ((a0.y + a1.y) + (a2.y + a3.y)) * nn + bb.y;
  *reinterpret_cast<float2*>(out + (size_t)node * N_OUT + lane * 2) = r;
}

extern "C" void kernel_launch(void* const* d_in, const int* in_sizes, int n_in,
                              void* d_out, int out_size, void* d_ws, size_t ws_size,
                              hipStream_t stream) {
  const float* h  = (const float*)d_in[0];
  const float* W1 = (const float*)d_in[1];
  const float* b1 = (const float*)d_in[2];
  const float* W2 = (const float*)d_in[3];
  const float* b2 = (const float*)d_in[4];
  const int* eidx = (const int*)d_in[5];
  const int N = in_sizes[0] / N_IN;
  const int E = in_sizes[5] / 2;
  const int NBE = (E + CHK - 1) / CHK;     // bucketing blocks

  char* ws = (char*)d_ws;
  size_t off = 0;
  auto alloc = [&](size_t bytes) { void* p = ws + off; off += (bytes + 511) & ~(size_t)511; return p; };
  int*      eflag  = (int*)alloc(sizeof(int));
  int*      rowptr = (int*)alloc((size_t)(N + 1) * 4);
  float*    norm   = (float*)alloc((size_t)N * 4);
  int*      esrc   = (int*)alloc((size_t)E * 4);
  int*      bktCnt = (int*)alloc((size_t)256 * 4);
  int*      bktOff = (int*)alloc((size_t)256 * 4);
  int*      bktCur = (int*)alloc((size_t)256 * 4);
  uint16_t* mask   = (uint16_t*)alloc((size_t)N * 16 * 2);
  uint4*    W1H    = (uint4*)alloc((size_t)16 * 4 * 64 * 16);
  uint4*    W1L    = (uint4*)alloc((size_t)16 * 4 * 64 * 16);
  uint4*    W2H    = (uint4*)alloc((size_t)4 * 8 * 64 * 16);
  uint4*    W2L    = (uint4*)alloc((size_t)4 * 8 * 64 * 16);
  uint32_t* aggP   = (uint32_t*)alloc((size_t)N * N_IN * 4);
  uint32_t* h1sP   = (uint32_t*)alloc((size_t)N * N_H * 4);
  uint2*    eb     = (uint2*)aggP;   // 6.4 MB <= 25.6 MB; dead before pull1 writes aggP
  float*    z      = (float*)aggP;   // aggP dead after gemm1
  float*    out    = (float*)d_out;

  hipMemsetAsync(bktCnt, 0, 256 * 4, stream);

  // graph-independent prep
  k_packW<<<(16 * 4 * 64 + 255) / 256, 256, 0, stream>>>(W1, W1H, W1L, N_H, 16, 4);
  k_packW<<<(4 * 8 * 64 + 255) / 256, 256, 0, stream>>>(W2, W2H, W2L, N_OUT, 4, 8);
  k_mask<<<(N * 16 + 255) / 256, 256, 0, stream>>>(mask, N);

  k_detect<<<1, 256, 0, stream>>>(eidx, E, eflag);

  // bucketed edge pipeline -> CSR (no global atomics after bscatter)
  k_bhist<<<NBE, 256, 0, stream>>>(eidx, E, eflag, bktCnt);
  k_bscan<<<1, 256, 0, stream>>>(bktCnt, bktOff, bktCur);
  k_bscatter<<<NBE, 256, 0, stream>>>(eidx, E, eflag, bktCur, eb);
  k_bucket_csr<<<256, 256, 0, stream>>>(eb, bktOff, rowptr, norm, esrc, N, E);
  k_sortlds<<<(N + 255) / 256, 256, 0, stream>>>(esrc, rowptr, N);

  k_pull1<<<(N + 7) / 8, 256, 0, stream>>>(h, norm, rowptr, esrc, aggP, N);

  dim3 g1((N + 63) / 64, 2);
  k_gemm1_mfma<<<g1, 256, 0, stream>>>(aggP, W1H, W1L, b1, norm, mask, h1sP, N);
  k_gemm2_mfma<<<(N + 63) / 64, 256, 0, stream>>>(h1sP, W2H, W2L, z, N);

  k_pull2<<<(N + 3) / 8 + 1, 256, 0, stream>>>(z, norm, b2, rowptr, esrc, out, N);
}

// Round 8
// 236.442 us; speedup vs baseline: 1.3885x; 1.0931x over previous
//
#include <hip/hip_runtime.h>
#include <stdint.h>

#define N_IN  128
#define N_H   256
#define N_OUT 64
#define CHK   2048   // edges per bucketing block

typedef __attribute__((ext_vector_type(8))) __bf16 bf16x8;
typedef __attribute__((ext_vector_type(4))) float f32x4;

// ---------------- Threefry-2x32 (JAX-compatible) ----------------
__device__ __forceinline__ void tf4(uint32_t& x0, uint32_t& x1,
                                    const int r0, const int r1, const int r2, const int r3) {
  x0 += x1; x1 = (x1 << r0) | (x1 >> (32 - r0)); x1 ^= x0;
  x0 += x1; x1 = (x1 << r1) | (x1 >> (32 - r1)); x1 ^= x0;
  x0 += x1; x1 = (x1 << r2) | (x1 >> (32 - r2)); x1 ^= x0;
  x0 += x1; x1 = (x1 << r3) | (x1 >> (32 - r3)); x1 ^= x0;
}

__device__ __forceinline__ uint2 threefry2x32(uint32_t k0, uint32_t k1, uint32_t x0, uint32_t x1) {
  const uint32_t k2 = k0 ^ k1 ^ 0x1BD11BDAu;
  x0 += k0; x1 += k1;
  tf4(x0, x1, 13, 15, 26, 6);   x0 += k1; x1 += k2 + 1u;
  tf4(x0, x1, 17, 29, 16, 24);  x0 += k2; x1 += k0 + 2u;
  tf4(x0, x1, 13, 15, 26, 6);   x0 += k0; x1 += k1 + 3u;
  tf4(x0, x1, 17, 29, 16, 24);  x0 += k1; x1 += k2 + 4u;
  tf4(x0, x1, 13, 15, 26, 6);   x0 += k2; x1 += k0 + 5u;
  return make_uint2(x0, x1);
}

// ---------------- dropout mask precompute ----------------
__global__ __launch_bounds__(256) void k_mask(uint16_t* __restrict__ mask, int N) {
  int g = blockIdx.x * 256 + threadIdx.x;
  if (g >= N * 16) return;
  uint32_t row = (uint32_t)(g >> 4), colb = (uint32_t)(g & 15);
  uint32_t base = row * 256u + colb;
  uint32_t m = 0;
#pragma unroll
  for (int ct = 0; ct < 16; ct++) {
    uint2 o = threefry2x32(0u, 42u, 0u, base + (uint32_t)ct * 16u);
    uint32_t bits = o.x ^ o.y;
    m |= ((~bits) >> 31) << ct;   // keep <=> top bit clear
  }
  mask[g] = (uint16_t)m;
}

// split f32 -> (hi,lo) bf16 bit patterns packed in one u32: (hi<<16)|lo
__device__ __forceinline__ uint32_t pack_hilo(float v) {
  uint32_t bits = __builtin_bit_cast(uint32_t, v);
  uint32_t hi = bits & 0xffff0000u;
  float lo = v - __builtin_bit_cast(float, hi);
  uint32_t lob = __builtin_bit_cast(uint32_t, lo) >> 16;
  return hi | lob;
}

// f32 -> bf16 round-to-nearest-even
__device__ __forceinline__ uint16_t f2bf_rne(float v) {
  uint32_t b = __builtin_bit_cast(uint32_t, v);
  b += 0x7fffu + ((b >> 16) & 1u);
  return (uint16_t)(b >> 16);
}
// unpack low/high bf16 of a u32 word
__device__ __forceinline__ float bflo(uint32_t w) { return __builtin_bit_cast(float, w << 16); }
__device__ __forceinline__ float bfhi(uint32_t w) { return __builtin_bit_cast(float, w & 0xffff0000u); }

// ---------------- edge-index layout detection (int64 vs int32) ----------------
__global__ void k_detect(const int* __restrict__ e, int E, int* __restrict__ flag) {
  __shared__ int s_nz;
  if (threadIdx.x == 0) s_nz = 0;
  __syncthreads();
  int n = E < 2048 ? E : 2048;
  for (int i = threadIdx.x; i < n; i += 256)
    if (e[2 * i + 1] != 0) atomicAdd(&s_nz, 1);
  __syncthreads();
  if (threadIdx.x == 0) *flag = (s_nz == 0) ? 2 : 1;
}

// ---------------- edge bucketing (by dst>>8; valid for N <= 65536) ----------------
__global__ __launch_bounds__(256) void k_bhist(const int* __restrict__ eidx, int E,
                                               const int* __restrict__ flag,
                                               int* __restrict__ bktCnt) {
  __shared__ int hist[256];
  hist[threadIdx.x] = 0;
  __syncthreads();
  int stride = *flag;
  int base = blockIdx.x * CHK;
#pragma unroll
  for (int i = 0; i < 8; i++) {
    int e = base + i * 256 + threadIdx.x;
    if (e < E) {
      int d = eidx[(size_t)(E + e) * stride];
      atomicAdd(&hist[d >> 8], 1);
    }
  }
  __syncthreads();
  int hv = hist[threadIdx.x];
  if (hv) atomicAdd(&bktCnt[threadIdx.x], hv);
}

// 256-bin exclusive scan -> stable bucket offsets + mutable cursors
__global__ __launch_bounds__(256) void k_bscan(const int* __restrict__ bktCnt,
                                               int* __restrict__ bktOff,
                                               int* __restrict__ bktCur) {
  __shared__ int s[256];
  const int t = threadIdx.x;
  int x = bktCnt[t];
  s[t] = x;
  __syncthreads();
  for (int off = 1; off < 256; off <<= 1) {
    int u = (t >= off) ? s[t - off] : 0;
    __syncthreads();
    s[t] += u;
    __syncthreads();
  }
  int excl = s[t] - x;
  bktOff[t] = excl;
  bktCur[t] = excl;
}

__global__ __launch_bounds__(256) void k_bscatter(const int* __restrict__ eidx, int E,
                                                  const int* __restrict__ flag,
                                                  int* __restrict__ bktCur,
                                                  uint2* __restrict__ eb) {
  __shared__ int hist[256];
  __shared__ int base[256];
  const int t = threadIdx.x;
  hist[t] = 0;
  __syncthreads();
  int stride = *flag;
  int cb = blockIdx.x * CHK;
  int dc[8], sc[8];
#pragma unroll
  for (int i = 0; i < 8; i++) {
    int e = cb + i * 256 + t;
    if (e < E) {
      dc[i] = eidx[(size_t)(E + e) * stride];
      sc[i] = eidx[(size_t)e * stride];
      atomicAdd(&hist[dc[i] >> 8], 1);
    } else dc[i] = -1;
  }
  __syncthreads();
  int h = hist[t];
  if (h) base[t] = atomicAdd(&bktCur[t], h);
  __syncthreads();
  hist[t] = 0;   // reuse as intra-block cursor
  __syncthreads();
#pragma unroll
  for (int i = 0; i < 8; i++) {
    if (dc[i] >= 0) {
      int b = dc[i] >> 8;
      int r = atomicAdd(&hist[b], 1);
      eb[base[b] + r] = make_uint2((unsigned)sc[i], (unsigned)dc[i]);
    }
  }
}

// ---------------- per-bucket CSR build: deg/rowptr/norm/esrc, zero global atomics ----------------
__global__ __launch_bounds__(256) void k_bucket_csr(
    const uint2* __restrict__ eb, const int* __restrict__ bktOff,
    int* __restrict__ rowptr, float* __restrict__ norm,
    int* __restrict__ esrc, int N, int E) {
  __shared__ int cnt[256];
  __shared__ int pfx[256];
  __shared__ int cur[256];
  const int b = blockIdx.x, t = threadIdx.x;
  if (b == 0 && t == 0) rowptr[N] = E;
  if (b * 256 >= N) return;
  const int lo = bktOff[b];
  const int hi = (b < 255) ? bktOff[b + 1] : E;
  cnt[t] = 0;
  __syncthreads();
  for (int e = lo + t; e < hi; e += 256)
    atomicAdd(&cnt[eb[e].y & 255u], 1);
  __syncthreads();
  int x = cnt[t];
  pfx[t] = x;
  __syncthreads();
  for (int off = 1; off < 256; off <<= 1) {
    int u = (t >= off) ? pfx[t - off] : 0;
    __syncthreads();
    pfx[t] += u;
    __syncthreads();
  }
  int excl = pfx[t] - x;
  int node = b * 256 + t;
  if (node < N) {
    rowptr[node] = lo + excl;
    norm[node] = x > 0 ? rsqrtf((float)x) : 1.0f;
  }
  cur[t] = excl;
  __syncthreads();
  for (int e = lo + t; e < hi; e += 256) {
    uint2 r = eb[e];
    int d = (int)(r.y & 255u);
    int p = atomicAdd(&cur[d], 1);
    esrc[lo + p] = (int)r.x;
  }
}

// per-row insertion sort in LDS (canonical deterministic order)
__global__ __launch_bounds__(256) void k_sortlds(int* __restrict__ esrc,
                                                 const int* __restrict__ rowptr, int N) {
  __shared__ int buf[64 * 256];
  int n = blockIdx.x * 256 + threadIdx.x;
  if (n >= N) return;
  const int t = threadIdx.x;
  int lo = rowptr[n], hi = rowptr[n + 1], d = hi - lo;
  if (d <= 64) {
    for (int i = 0; i < d; i++) buf[i * 256 + t] = esrc[lo + i];
    for (int i = 1; i < d; i++) {
      int v = buf[i * 256 + t];
      int j = i - 1;
      while (j >= 0 && buf[j * 256 + t] > v) { buf[(j + 1) * 256 + t] = buf[j * 256 + t]; j--; }
      buf[(j + 1) * 256 + t] = v;
    }
    for (int i = 0; i < d; i++) esrc[lo + i] = buf[i * 256 + t];
  } else {
    for (int i = lo + 1; i < hi; i++) {
      int v = esrc[i];
      int j = i - 1;
      while (j >= lo && esrc[j] > v) { esrc[j + 1] = esrc[j]; j--; }
      esrc[j + 1] = v;
    }
  }
}

// ---------------- hn = bf16(h * norm[row]) plane (12.8 MB) ----------------
__global__ __launch_bounds__(256) void k_h2bf(const float* __restrict__ h,
                                              const float* __restrict__ norm,
                                              uint16_t* __restrict__ hn, int total4) {
  int g = blockIdx.x * 256 + threadIdx.x;   // one thread per 4 elems
  if (g >= total4) return;
  float nr = norm[g >> 5];                  // 32 threads per 128-elem row
  float4 v = *reinterpret_cast<const float4*>(h + (size_t)g * 4);
  ushort4 r;
  r.x = f2bf_rne(v.x * nr);
  r.y = f2bf_rne(v.y * nr);
  r.z = f2bf_rne(v.z * nr);
  r.w = f2bf_rne(v.w * nr);
  *reinterpret_cast<ushort4*>(hn + (size_t)g * 4) = r;
}

// ---------------- layer-1 pull (bf16 gather): agg[n] = sum hn[s] ----------------
// 2 nodes/wave, 32 lanes x 4 bf16 (8 B/lane), 4-edge unroll
__global__ __launch_bounds__(256) void k_pull1(
    const uint16_t* __restrict__ hn, const int* __restrict__ rowptr,
    const int* __restrict__ esrc, uint32_t* __restrict__ aggP, int N) {
  int node = blockIdx.x * 8 + (threadIdx.x >> 5);
  if (node >= N) return;
  int lane = threadIdx.x & 31;
  int lo = rowptr[node], hi = rowptr[node + 1];
  float4 a0 = {0,0,0,0}, a1 = {0,0,0,0}, a2 = {0,0,0,0}, a3 = {0,0,0,0};
  int e = lo;
  for (; e + 3 < hi; e += 4) {
    int s0 = esrc[e], s1 = esrc[e + 1], s2 = esrc[e + 2], s3 = esrc[e + 3];
    uint2 v0 = *reinterpret_cast<const uint2*>(hn + (size_t)s0 * N_IN + lane * 4);
    uint2 v1 = *reinterpret_cast<const uint2*>(hn + (size_t)s1 * N_IN + lane * 4);
    uint2 v2 = *reinterpret_cast<const uint2*>(hn + (size_t)s2 * N_IN + lane * 4);
    uint2 v3 = *reinterpret_cast<const uint2*>(hn + (size_t)s3 * N_IN + lane * 4);
    a0.x += bflo(v0.x); a0.y += bfhi(v0.x); a0.z += bflo(v0.y); a0.w += bfhi(v0.y);
    a1.x += bflo(v1.x); a1.y += bfhi(v1.x); a1.z += bflo(v1.y); a1.w += bfhi(v1.y);
    a2.x += bflo(v2.x); a2.y += bfhi(v2.x); a2.z += bflo(v2.y); a2.w += bfhi(v2.y);
    a3.x += bflo(v3.x); a3.y += bfhi(v3.x); a3.z += bflo(v3.y); a3.w += bfhi(v3.y);
  }
  for (; e < hi; e++) {
    uint2 v0 = *reinterpret_cast<const uint2*>(hn + (size_t)esrc[e] * N_IN + lane * 4);
    a0.x += bflo(v0.x); a0.y += bfhi(v0.x); a0.z += bflo(v0.y); a0.w += bfhi(v0.y);
  }
  float4 r;
  r.x = (a0.x + a1.x) + (a2.x + a3.x);
  r.y = (a0.y + a1.y) + (a2.y + a3.y);
  r.z = (a0.z + a1.z) + (a2.z + a3.z);
  r.w = (a0.w + a1.w) + (a2.w + a3.w);
  uint4 p = make_uint4(pack_hilo(r.x), pack_hilo(r.y), pack_hilo(r.z), pack_hilo(r.w));
  *reinterpret_cast<uint4*>(aggP + (size_t)node * N_IN + lane * 4) = p;
}

// ---------------- W pack: fragment-order (hi,lo) bf16 planes ----------------
__global__ void k_packW(const float* __restrict__ W, uint4* __restrict__ WH,
                        uint4* __restrict__ WL, int Ncols, int nct, int nks) {
  int g = blockIdx.x * 256 + threadIdx.x;
  if (g >= nct * nks * 64) return;
  int lane = g & 63;
  int grp = g >> 6;
  int ks = grp % nks, ct = grp / nks;
  int k0 = ks * 32 + (lane >> 4) * 8;
  int col = ct * 16 + (lane & 15);
  uint32_t hb[8], lb[8];
#pragma unroll
  for (int j = 0; j < 8; j++) {
    float w = W[(size_t)(k0 + j) * Ncols + col];
    uint32_t bits = __builtin_bit_cast(uint32_t, w);
    uint32_t hi = bits & 0xffff0000u;
    float lo = w - __builtin_bit_cast(float, hi);
    hb[j] = hi >> 16;
    lb[j] = __builtin_bit_cast(uint32_t, lo) >> 16;
  }
  WH[g] = make_uint4(hb[0] | (hb[1] << 16), hb[2] | (hb[3] << 16),
                     hb[4] | (hb[5] << 16), hb[6] | (hb[7] << 16));
  WL[g] = make_uint4(lb[0] | (lb[1] << 16), lb[2] | (lb[3] << 16),
                     lb[4] | (lb[5] << 16), lb[6] | (lb[7] << 16));
}

// ---------------- GEMM1 (split-bf16 MFMA, no LDS, col-split by blockIdx.y) ----------------
__global__ __launch_bounds__(256) void k_gemm1_mfma(
    const uint32_t* __restrict__ aggP, const uint4* __restrict__ WH,
    const uint4* __restrict__ WL, const float* __restrict__ b1,
    const float* __restrict__ norm, const uint16_t* __restrict__ mask,
    uint32_t* __restrict__ h1sP, int Nn) {
  const int tid = threadIdx.x;
  const int wave = tid >> 6, lane = tid & 63;
  const int row0 = blockIdx.x * 64 + wave * 16;
  const int cy = blockIdx.y;
  const int lrow = lane & 15, lk = lane >> 4;
  int arow = row0 + lrow; if (arow >= Nn) arow = Nn - 1;

  f32x4 acc[8];
#pragma unroll
  for (int c = 0; c < 8; c++) acc[c] = f32x4{0.f, 0.f, 0.f, 0.f};

#pragma unroll
  for (int ks = 0; ks < 4; ks++) {
    const uint4* ap = reinterpret_cast<const uint4*>(aggP + (size_t)arow * N_IN + ks * 32 + lk * 8);
    uint4 p0 = ap[0], p1 = ap[1];
    uint32_t pw[8] = {p0.x, p0.y, p0.z, p0.w, p1.x, p1.y, p1.z, p1.w};
    union { ushort u[8]; bf16x8 v; } ah, al;
#pragma unroll
    for (int j = 0; j < 8; j++) { ah.u[j] = (ushort)(pw[j] >> 16); al.u[j] = (ushort)(pw[j] & 0xffffu); }
#pragma unroll
    for (int c = 0; c < 8; c++) {
      int ct = cy * 8 + c;
      union { uint4 q; bf16x8 v; } bh, bl;
      bh.q = WH[(ct * 4 + ks) * 64 + lane];
      bl.q = WL[(ct * 4 + ks) * 64 + lane];
      acc[c] = __builtin_amdgcn_mfma_f32_16x16x32_bf16(ah.v, bh.v, acc[c], 0, 0, 0);
      acc[c] = __builtin_amdgcn_mfma_f32_16x16x32_bf16(ah.v, bl.v, acc[c], 0, 0, 0);
      acc[c] = __builtin_amdgcn_mfma_f32_16x16x32_bf16(al.v, bh.v, acc[c], 0, 0, 0);
    }
  }

  const int colb = lane & 15, rgrp = lane >> 4;
#pragma unroll
  for (int r = 0; r < 4; r++) {
    int row = row0 + rgrp * 4 + r;
    if (row >= Nn) continue;
    float nr = norm[row];
    uint32_t m = mask[row * 16 + colb];
#pragma unroll
    for (int c = 0; c < 8; c++) {
      int ct = cy * 8 + c;
      int col = ct * 16 + colb;
      float v = fmaf(acc[c][r], nr, b1[col]);
      v = fmaxf(v, 0.f);
      v = ((m >> ct) & 1u) ? v * (2.0f * nr) : 0.f;   // dropout + pre-apply src norm
      h1sP[(size_t)row * N_H + col] = pack_hilo(v);
    }
  }
}

// ---------------- GEMM2 (split-bf16 MFMA): zbf = bf16(h1s @ W2) ----------------
__global__ __launch_bounds__(256) void k_gemm2_mfma(
    const uint32_t* __restrict__ h1sP, const uint4* __restrict__ WH,
    const uint4* __restrict__ WL, uint16_t* __restrict__ zbf, int Nn) {
  const int tid = threadIdx.x;
  const int wave = tid >> 6, lane = tid & 63;
  const int row0 = blockIdx.x * 64 + wave * 16;
  const int lrow = lane & 15, lk = lane >> 4;
  int arow = row0 + lrow; if (arow >= Nn) arow = Nn - 1;

  f32x4 acc[4];
#pragma unroll
  for (int ct = 0; ct < 4; ct++) acc[ct] = f32x4{0.f, 0.f, 0.f, 0.f};

#pragma unroll
  for (int ks = 0; ks < 8; ks++) {
    const uint4* ap = reinterpret_cast<const uint4*>(h1sP + (size_t)arow * N_H + ks * 32 + lk * 8);
    uint4 p0 = ap[0], p1 = ap[1];
    uint32_t pw[8] = {p0.x, p0.y, p0.z, p0.w, p1.x, p1.y, p1.z, p1.w};
    union { ushort u[8]; bf16x8 v; } ah, al;
#pragma unroll
    for (int j = 0; j < 8; j++) { ah.u[j] = (ushort)(pw[j] >> 16); al.u[j] = (ushort)(pw[j] & 0xffffu); }
#pragma unroll
    for (int ct = 0; ct < 4; ct++) {
      union { uint4 q; bf16x8 v; } bh, bl;
      bh.q = WH[(ct * 8 + ks) * 64 + lane];
      bl.q = WL[(ct * 8 + ks) * 64 + lane];
      acc[ct] = __builtin_amdgcn_mfma_f32_16x16x32_bf16(ah.v, bh.v, acc[ct], 0, 0, 0);
      acc[ct] = __builtin_amdgcn_mfma_f32_16x16x32_bf16(ah.v, bl.v, acc[ct], 0, 0, 0);
      acc[ct] = __builtin_amdgcn_mfma_f32_16x16x32_bf16(al.v, bh.v, acc[ct], 0, 0, 0);
    }
  }

  const int colb = lane & 15, rgrp = lane >> 4;
#pragma unroll
  for (int r = 0; r < 4; r++) {
    int row = row0 + rgrp * 4 + r;
    if (row >= Nn) continue;
#pragma unroll
    for (int ct = 0; ct < 4; ct++)
      zbf[(size_t)row * N_OUT + ct * 16 + colb] = f2bf_rne(acc[ct][r]);
  }
}

// ---------------- layer-2 pull (bf16 gather) fused epilogue ----------------
// 2 nodes/wave, 32 lanes x 2 bf16 (4 B/lane), 4-edge unroll
__global__ __launch_bounds__(256) void k_pull2(
    const uint16_t* __restrict__ zbf, const float* __restrict__ norm,
    const float* __restrict__ b2, const int* __restrict__ rowptr,
    const int* __restrict__ esrc, float* __restrict__ out, int N) {
  int node = blockIdx.x * 8 + (threadIdx.x >> 5);
  if (node >= N) return;
  int lane = threadIdx.x & 31;
  int lo = rowptr[node], hi = rowptr[node + 1];
  float2 a0 = {0,0}, a1 = {0,0}, a2 = {0,0}, a3 = {0,0};
  int e = lo;
  for (; e + 3 < hi; e += 4) {
    int s0 = esrc[e], s1 = esrc[e + 1], s2 = esrc[e + 2], s3 = esrc[e + 3];
    uint32_t v0 = *reinterpret_cast<const uint32_t*>(zbf + (size_t)s0 * N_OUT + lane * 2);
    uint32_t v1 = *reinterpret_cast<const uint32_t*>(zbf + (size_t)s1 * N_OUT + lane * 2);
    uint32_t v2 = *reinterpret_cast<const uint32_t*>(zbf + (size_t)s2 * N_OUT + lane * 2);
    uint32_t v3 = *reinterpret_cast<const uint32_t*>(zbf + (size_t)s3 * N_OUT + lane * 2);
    a0.x += bflo(v0); a0.y += bfhi(v0);
    a1.x += bflo(v1); a1.y += bfhi(v1);
    a2.x += bflo(v2); a2.y += bfhi(v2);
    a3.x += bflo(v3); a3.y += bfhi(v3);
  }
  for (; e < hi; e++) {
    uint32_t v0 = *reinterpret_cast<const uint32_t*>(zbf + (size_t)esrc[e] * N_OUT + lane * 2);
    a0.x += bflo(v0); a0.y += bfhi(v0);
  }
  float nn = norm[node];
  float2 bb = *reinterpret_cast<const float2*>(b2 + lane * 2);
  float2 r;
  r.x = ((a0.x + a1.x) + (a2.x + a3.x)) * nn + bb.x;
  r.y = ((a0.y + a1.y) + (a2.y + a3.y)) * nn + bb.y;
  *reinterpret_cast<float2*>(out + (size_t)node * N_OUT + lane * 2) = r;
}

extern "C" void kernel_launch(void* const* d_in, const int* in_sizes, int n_in,
                              void* d_out, int out_size, void* d_ws, size_t ws_size,
                              hipStream_t stream) {
  const float* h  = (const float*)d_in[0];
  const float* W1 = (const float*)d_in[1];
  const float* b1 = (const float*)d_in[2];
  const float* W2 = (const float*)d_in[3];
  const float* b2 = (const float*)d_in[4];
  const int* eidx = (const int*)d_in[5];
  const int N = in_sizes[0] / N_IN;
  const int E = in_sizes[5] / 2;
  const int NBE = (E + CHK - 1) / CHK;     // bucketing blocks

  char* ws = (char*)d_ws;
  size_t off = 0;
  auto alloc = [&](size_t bytes) { void* p = ws + off; off += (bytes + 511) & ~(size_t)511; return p; };
  int*      eflag  = (int*)alloc(sizeof(int));
  int*      rowptr = (int*)alloc((size_t)(N + 1) * 4);
  float*    norm   = (float*)alloc((size_t)N * 4);
  int*      esrc   = (int*)alloc((size_t)E * 4);
  int*      bktCnt = (int*)alloc((size_t)256 * 4);
  int*      bktOff = (int*)alloc((size_t)256 * 4);
  int*      bktCur = (int*)alloc((size_t)256 * 4);
  uint16_t* mask   = (uint16_t*)alloc((size_t)N * 16 * 2);
  uint4*    W1H    = (uint4*)alloc((size_t)16 * 4 * 64 * 16);
  uint4*    W1L    = (uint4*)alloc((size_t)16 * 4 * 64 * 16);
  uint4*    W2H    = (uint4*)alloc((size_t)4 * 8 * 64 * 16);
  uint4*    W2L    = (uint4*)alloc((size_t)4 * 8 * 64 * 16);
  uint32_t* aggP   = (uint32_t*)alloc((size_t)N * N_IN * 4);
  uint32_t* h1sP   = (uint32_t*)alloc((size_t)N * N_H * 4);
  uint2*    eb     = (uint2*)aggP;      // 6.4 MB; dead before pull1 writes aggP
  uint16_t* hn     = (uint16_t*)h1sP;   // 12.8 MB; dead before gemm1 writes h1sP
  uint16_t* zbf    = (uint16_t*)aggP;   // 6.4 MB; aggP dead after gemm1
  float*    out    = (float*)d_out;

  hipMemsetAsync(bktCnt, 0, 256 * 4, stream);

  // graph-independent prep
  k_packW<<<(16 * 4 * 64 + 255) / 256, 256, 0, stream>>>(W1, W1H, W1L, N_H, 16, 4);
  k_packW<<<(4 * 8 * 64 + 255) / 256, 256, 0, stream>>>(W2, W2H, W2L, N_OUT, 4, 8);
  k_mask<<<(N * 16 + 255) / 256, 256, 0, stream>>>(mask, N);

  k_detect<<<1, 256, 0, stream>>>(eidx, E, eflag);

  // bucketed edge pipeline -> CSR (no global atomics after bscatter)
  k_bhist<<<NBE, 256, 0, stream>>>(eidx, E, eflag, bktCnt);
  k_bscan<<<1, 256, 0, stream>>>(bktCnt, bktOff, bktCur);
  k_bscatter<<<NBE, 256, 0, stream>>>(eidx, E, eflag, bktCur, eb);
  k_bucket_csr<<<256, 256, 0, stream>>>(eb, bktOff, rowptr, norm, esrc, N, E);
  k_sortlds<<<(N + 255) / 256, 256, 0, stream>>>(esrc, rowptr, N);

  // bf16 gather plane: hn = bf16(h * norm[row])
  k_h2bf<<<(N * 32 + 255) / 256, 256, 0, stream>>>(h, norm, hn, N * 32);

  k_pull1<<<(N + 7) / 8, 256, 0, stream>>>(hn, rowptr, esrc, aggP, N);

  dim3 g1((N + 63) / 64, 2);
  k_gemm1_mfma<<<g1, 256, 0, stream>>>(aggP, W1H, W1L, b1, norm, mask, h1sP, N);
  k_gemm2_mfma<<<(N + 63) / 64, 256, 0, stream>>>(h1sP, W2H, W2L, zbf, N);

  k_pull2<<<(N + 7) / 8, 256, 0, stream>>>(zbf, norm, b2, rowptr, esrc, out, N);
}

// Round 9
// 208.153 us; speedup vs baseline: 1.5772x; 1.1359x over previous
//
#include <hip/hip_runtime.h>
#include <stdint.h>

#define N_IN  128
#define N_H   256
#define N_OUT 64
#define CHK   2048   // edges per bucketing block

typedef __attribute__((ext_vector_type(8))) __bf16 bf16x8;
typedef __attribute__((ext_vector_type(4))) float f32x4;

// ---------------- Threefry-2x32 (JAX-compatible) ----------------
__device__ __forceinline__ void tf4(uint32_t& x0, uint32_t& x1,
                                    const int r0, const int r1, const int r2, const int r3) {
  x0 += x1; x1 = (x1 << r0) | (x1 >> (32 - r0)); x1 ^= x0;
  x0 += x1; x1 = (x1 << r1) | (x1 >> (32 - r1)); x1 ^= x0;
  x0 += x1; x1 = (x1 << r2) | (x1 >> (32 - r2)); x1 ^= x0;
  x0 += x1; x1 = (x1 << r3) | (x1 >> (32 - r3)); x1 ^= x0;
}

__device__ __forceinline__ uint2 threefry2x32(uint32_t k0, uint32_t k1, uint32_t x0, uint32_t x1) {
  const uint32_t k2 = k0 ^ k1 ^ 0x1BD11BDAu;
  x0 += k0; x1 += k1;
  tf4(x0, x1, 13, 15, 26, 6);   x0 += k1; x1 += k2 + 1u;
  tf4(x0, x1, 17, 29, 16, 24);  x0 += k2; x1 += k0 + 2u;
  tf4(x0, x1, 13, 15, 26, 6);   x0 += k0; x1 += k1 + 3u;
  tf4(x0, x1, 17, 29, 16, 24);  x0 += k1; x1 += k2 + 4u;
  tf4(x0, x1, 13, 15, 26, 6);   x0 += k2; x1 += k0 + 5u;
  return make_uint2(x0, x1);
}

// ---------------- dropout mask precompute ----------------
__global__ __launch_bounds__(256) void k_mask(uint16_t* __restrict__ mask, int N) {
  int g = blockIdx.x * 256 + threadIdx.x;
  if (g >= N * 16) return;
  uint32_t row = (uint32_t)(g >> 4), colb = (uint32_t)(g & 15);
  uint32_t base = row * 256u + colb;
  uint32_t m = 0;
#pragma unroll
  for (int ct = 0; ct < 16; ct++) {
    uint2 o = threefry2x32(0u, 42u, 0u, base + (uint32_t)ct * 16u);
    uint32_t bits = o.x ^ o.y;
    m |= ((~bits) >> 31) << ct;   // keep <=> top bit clear
  }
  mask[g] = (uint16_t)m;
}

// split f32 -> (hi,lo) bf16 bit patterns packed in one u32: (hi<<16)|lo
__device__ __forceinline__ uint32_t pack_hilo(float v) {
  uint32_t bits = __builtin_bit_cast(uint32_t, v);
  uint32_t hi = bits & 0xffff0000u;
  float lo = v - __builtin_bit_cast(float, hi);
  uint32_t lob = __builtin_bit_cast(uint32_t, lo) >> 16;
  return hi | lob;
}

// f32 -> bf16 round-to-nearest-even
__device__ __forceinline__ uint16_t f2bf_rne(float v) {
  uint32_t b = __builtin_bit_cast(uint32_t, v);
  b += 0x7fffu + ((b >> 16) & 1u);
  return (uint16_t)(b >> 16);
}
// unpack low/high bf16 of a u32 word
__device__ __forceinline__ float bflo(uint32_t w) { return __builtin_bit_cast(float, w << 16); }
__device__ __forceinline__ float bfhi(uint32_t w) { return __builtin_bit_cast(float, w & 0xffff0000u); }

// ---------------- edge-index layout detection (int64 vs int32) ----------------
__global__ void k_detect(const int* __restrict__ e, int E, int* __restrict__ flag) {
  __shared__ int s_nz;
  if (threadIdx.x == 0) s_nz = 0;
  __syncthreads();
  int n = E < 2048 ? E : 2048;
  for (int i = threadIdx.x; i < n; i += 256)
    if (e[2 * i + 1] != 0) atomicAdd(&s_nz, 1);
  __syncthreads();
  if (threadIdx.x == 0) *flag = (s_nz == 0) ? 2 : 1;
}

// ---------------- edge bucketing (by dst>>8; valid for N <= 65536) ----------------
__global__ __launch_bounds__(256) void k_bhist(const int* __restrict__ eidx, int E,
                                               const int* __restrict__ flag,
                                               int* __restrict__ bktCnt) {
  __shared__ int hist[256];
  hist[threadIdx.x] = 0;
  __syncthreads();
  int stride = *flag;
  int base = blockIdx.x * CHK;
#pragma unroll
  for (int i = 0; i < 8; i++) {
    int e = base + i * 256 + threadIdx.x;
    if (e < E) {
      int d = eidx[(size_t)(E + e) * stride];
      atomicAdd(&hist[d >> 8], 1);
    }
  }
  __syncthreads();
  int hv = hist[threadIdx.x];
  if (hv) atomicAdd(&bktCnt[threadIdx.x], hv);
}

// 256-bin exclusive scan -> stable bucket offsets + mutable cursors
__global__ __launch_bounds__(256) void k_bscan(const int* __restrict__ bktCnt,
                                               int* __restrict__ bktOff,
                                               int* __restrict__ bktCur) {
  __shared__ int s[256];
  const int t = threadIdx.x;
  int x = bktCnt[t];
  s[t] = x;
  __syncthreads();
  for (int off = 1; off < 256; off <<= 1) {
    int u = (t >= off) ? s[t - off] : 0;
    __syncthreads();
    s[t] += u;
    __syncthreads();
  }
  int excl = s[t] - x;
  bktOff[t] = excl;
  bktCur[t] = excl;
}

__global__ __launch_bounds__(256) void k_bscatter(const int* __restrict__ eidx, int E,
                                                  const int* __restrict__ flag,
                                                  int* __restrict__ bktCur,
                                                  uint2* __restrict__ eb) {
  __shared__ int hist[256];
  __shared__ int base[256];
  const int t = threadIdx.x;
  hist[t] = 0;
  __syncthreads();
  int stride = *flag;
  int cb = blockIdx.x * CHK;
  int dc[8], sc[8];
#pragma unroll
  for (int i = 0; i < 8; i++) {
    int e = cb + i * 256 + t;
    if (e < E) {
      dc[i] = eidx[(size_t)(E + e) * stride];
      sc[i] = eidx[(size_t)e * stride];
      atomicAdd(&hist[dc[i] >> 8], 1);
    } else dc[i] = -1;
  }
  __syncthreads();
  int h = hist[t];
  if (h) base[t] = atomicAdd(&bktCur[t], h);
  __syncthreads();
  hist[t] = 0;   // reuse as intra-block cursor
  __syncthreads();
#pragma unroll
  for (int i = 0; i < 8; i++) {
    if (dc[i] >= 0) {
      int b = dc[i] >> 8;
      int r = atomicAdd(&hist[b], 1);
      eb[base[b] + r] = make_uint2((unsigned)sc[i], (unsigned)dc[i]);
    }
  }
}

// ---------------- per-bucket CSR build: deg/rowptr/norm/esrc, zero global atomics ----------------
__global__ __launch_bounds__(256) void k_bucket_csr(
    const uint2* __restrict__ eb, const int* __restrict__ bktOff,
    int* __restrict__ rowptr, float* __restrict__ norm,
    int* __restrict__ esrc, int N, int E) {
  __shared__ int cnt[256];
  __shared__ int pfx[256];
  __shared__ int cur[256];
  const int b = blockIdx.x, t = threadIdx.x;
  if (b == 0 && t == 0) rowptr[N] = E;
  if (b * 256 >= N) return;
  const int lo = bktOff[b];
  const int hi = (b < 255) ? bktOff[b + 1] : E;
  cnt[t] = 0;
  __syncthreads();
  for (int e = lo + t; e < hi; e += 256)
    atomicAdd(&cnt[eb[e].y & 255u], 1);
  __syncthreads();
  int x = cnt[t];
  pfx[t] = x;
  __syncthreads();
  for (int off = 1; off < 256; off <<= 1) {
    int u = (t >= off) ? pfx[t - off] : 0;
    __syncthreads();
    pfx[t] += u;
    __syncthreads();
  }
  int excl = pfx[t] - x;
  int node = b * 256 + t;
  if (node < N) {
    rowptr[node] = lo + excl;
    norm[node] = x > 0 ? rsqrtf((float)x) : 1.0f;
  }
  cur[t] = excl;
  __syncthreads();
  for (int e = lo + t; e < hi; e += 256) {
    uint2 r = eb[e];
    int d = (int)(r.y & 255u);
    int p = atomicAdd(&cur[d], 1);
    esrc[lo + p] = (int)r.x;
  }
}

// ---------------- wave-parallel bitonic row sort (canonical deterministic order) ----------------
// one wave (64 lanes) per node; d <= 64 sorted in registers via shfl_xor; rare d > 64 -> serial
__global__ __launch_bounds__(256) void k_sortwave(int* __restrict__ esrc,
                                                  const int* __restrict__ rowptr, int N) {
  int node = blockIdx.x * 4 + (threadIdx.x >> 6);
  if (node >= N) return;
  const int lane = threadIdx.x & 63;
  int lo = rowptr[node], hi = rowptr[node + 1], d = hi - lo;
  if (d <= 1) return;
  if (d <= 64) {
    int v = (lane < d) ? esrc[lo + lane] : 0x7fffffff;
#pragma unroll
    for (int k = 2; k <= 64; k <<= 1) {
#pragma unroll
      for (int j = k >> 1; j > 0; j >>= 1) {
        int other = __shfl_xor(v, j);
        bool up = ((lane & k) == 0);         // ascending block
        bool lower = ((lane & j) == 0);      // lower partner
        int mn = min(v, other), mx = max(v, other);
        v = (up == lower) ? mn : mx;
      }
    }
    if (lane < d) esrc[lo + lane] = v;
  } else if (lane == 0) {
    for (int i = lo + 1; i < hi; i++) {
      int v = esrc[i];
      int j = i - 1;
      while (j >= lo && esrc[j] > v) { esrc[j + 1] = esrc[j]; j--; }
      esrc[j + 1] = v;
    }
  }
}

// ---------------- hn = bf16(h * norm[row]) plane (12.8 MB) ----------------
__global__ __launch_bounds__(256) void k_h2bf(const float* __restrict__ h,
                                              const float* __restrict__ norm,
                                              uint16_t* __restrict__ hn, int total4) {
  int g = blockIdx.x * 256 + threadIdx.x;   // one thread per 4 elems
  if (g >= total4) return;
  float nr = norm[g >> 5];                  // 32 threads per 128-elem row
  float4 v = *reinterpret_cast<const float4*>(h + (size_t)g * 4);
  ushort4 r;
  r.x = f2bf_rne(v.x * nr);
  r.y = f2bf_rne(v.y * nr);
  r.z = f2bf_rne(v.z * nr);
  r.w = f2bf_rne(v.w * nr);
  *reinterpret_cast<ushort4*>(hn + (size_t)g * 4) = r;
}

// ---------------- layer-1 pull (bf16 gather): agg[n] = sum hn[s] ----------------
// 2 nodes/wave, 32 lanes x 4 bf16 (8 B/lane), 4-edge unroll
__global__ __launch_bounds__(256) void k_pull1(
    const uint16_t* __restrict__ hn, const int* __restrict__ rowptr,
    const int* __restrict__ esrc, uint32_t* __restrict__ aggP, int N) {
  int node = blockIdx.x * 8 + (threadIdx.x >> 5);
  if (node >= N) return;
  int lane = threadIdx.x & 31;
  int lo = rowptr[node], hi = rowptr[node + 1];
  float4 a0 = {0,0,0,0}, a1 = {0,0,0,0}, a2 = {0,0,0,0}, a3 = {0,0,0,0};
  int e = lo;
  for (; e + 3 < hi; e += 4) {
    int s0 = esrc[e], s1 = esrc[e + 1], s2 = esrc[e + 2], s3 = esrc[e + 3];
    uint2 v0 = *reinterpret_cast<const uint2*>(hn + (size_t)s0 * N_IN + lane * 4);
    uint2 v1 = *reinterpret_cast<const uint2*>(hn + (size_t)s1 * N_IN + lane * 4);
    uint2 v2 = *reinterpret_cast<const uint2*>(hn + (size_t)s2 * N_IN + lane * 4);
    uint2 v3 = *reinterpret_cast<const uint2*>(hn + (size_t)s3 * N_IN + lane * 4);
    a0.x += bflo(v0.x); a0.y += bfhi(v0.x); a0.z += bflo(v0.y); a0.w += bfhi(v0.y);
    a1.x += bflo(v1.x); a1.y += bfhi(v1.x); a1.z += bflo(v1.y); a1.w += bfhi(v1.y);
    a2.x += bflo(v2.x); a2.y += bfhi(v2.x); a2.z += bflo(v2.y); a2.w += bfhi(v2.y);
    a3.x += bflo(v3.x); a3.y += bfhi(v3.x); a3.z += bflo(v3.y); a3.w += bfhi(v3.y);
  }
  for (; e < hi; e++) {
    uint2 v0 = *reinterpret_cast<const uint2*>(hn + (size_t)esrc[e] * N_IN + lane * 4);
    a0.x += bflo(v0.x); a0.y += bfhi(v0.x); a0.z += bflo(v0.y); a0.w += bfhi(v0.y);
  }
  float4 r;
  r.x = (a0.x + a1.x) + (a2.x + a3.x);
  r.y = (a0.y + a1.y) + (a2.y + a3.y);
  r.z = (a0.z + a1.z) + (a2.z + a3.z);
  r.w = (a0.w + a1.w) + (a2.w + a3.w);
  uint4 p = make_uint4(pack_hilo(r.x), pack_hilo(r.y), pack_hilo(r.z), pack_hilo(r.w));
  *reinterpret_cast<uint4*>(aggP + (size_t)node * N_IN + lane * 4) = p;
}

// ---------------- W pack: fragment-order (hi,lo) bf16 planes ----------------
__global__ void k_packW(const float* __restrict__ W, uint4* __restrict__ WH,
                        uint4* __restrict__ WL, int Ncols, int nct, int nks) {
  int g = blockIdx.x * 256 + threadIdx.x;
  if (g >= nct * nks * 64) return;
  int lane = g & 63;
  int grp = g >> 6;
  int ks = grp % nks, ct = grp / nks;
  int k0 = ks * 32 + (lane >> 4) * 8;
  int col = ct * 16 + (lane & 15);
  uint32_t hb[8], lb[8];
#pragma unroll
  for (int j = 0; j < 8; j++) {
    float w = W[(size_t)(k0 + j) * Ncols + col];
    uint32_t bits = __builtin_bit_cast(uint32_t, w);
    uint32_t hi = bits & 0xffff0000u;
    float lo = w - __builtin_bit_cast(float, hi);
    hb[j] = hi >> 16;
    lb[j] = __builtin_bit_cast(uint32_t, lo) >> 16;
  }
  WH[g] = make_uint4(hb[0] | (hb[1] << 16), hb[2] | (hb[3] << 16),
                     hb[4] | (hb[5] << 16), hb[6] | (hb[7] << 16));
  WL[g] = make_uint4(lb[0] | (lb[1] << 16), lb[2] | (lb[3] << 16),
                     lb[4] | (lb[5] << 16), lb[6] | (lb[7] << 16));
}

// ---------------- GEMM1 (split-bf16 MFMA, no LDS, col-split by blockIdx.y) ----------------
__global__ __launch_bounds__(256) void k_gemm1_mfma(
    const uint32_t* __restrict__ aggP, const uint4* __restrict__ WH,
    const uint4* __restrict__ WL, const float* __restrict__ b1,
    const float* __restrict__ norm, const uint16_t* __restrict__ mask,
    uint32_t* __restrict__ h1sP, int Nn) {
  const int tid = threadIdx.x;
  const int wave = tid >> 6, lane = tid & 63;
  const int row0 = blockIdx.x * 64 + wave * 16;
  const int cy = blockIdx.y;
  const int lrow = lane & 15, lk = lane >> 4;
  int arow = row0 + lrow; if (arow >= Nn) arow = Nn - 1;

  f32x4 acc[8];
#pragma unroll
  for (int c = 0; c < 8; c++) acc[c] = f32x4{0.f, 0.f, 0.f, 0.f};

#pragma unroll
  for (int ks = 0; ks < 4; ks++) {
    const uint4* ap = reinterpret_cast<const uint4*>(aggP + (size_t)arow * N_IN + ks * 32 + lk * 8);
    uint4 p0 = ap[0], p1 = ap[1];
    uint32_t pw[8] = {p0.x, p0.y, p0.z, p0.w, p1.x, p1.y, p1.z, p1.w};
    union { ushort u[8]; bf16x8 v; } ah, al;
#pragma unroll
    for (int j = 0; j < 8; j++) { ah.u[j] = (ushort)(pw[j] >> 16); al.u[j] = (ushort)(pw[j] & 0xffffu); }
#pragma unroll
    for (int c = 0; c < 8; c++) {
      int ct = cy * 8 + c;
      union { uint4 q; bf16x8 v; } bh, bl;
      bh.q = WH[(ct * 4 + ks) * 64 + lane];
      bl.q = WL[(ct * 4 + ks) * 64 + lane];
      acc[c] = __builtin_amdgcn_mfma_f32_16x16x32_bf16(ah.v, bh.v, acc[c], 0, 0, 0);
      acc[c] = __builtin_amdgcn_mfma_f32_16x16x32_bf16(ah.v, bl.v, acc[c], 0, 0, 0);
      acc[c] = __builtin_amdgcn_mfma_f32_16x16x32_bf16(al.v, bh.v, acc[c], 0, 0, 0);
    }
  }

  const int colb = lane & 15, rgrp = lane >> 4;
#pragma unroll
  for (int r = 0; r < 4; r++) {
    int row = row0 + rgrp * 4 + r;
    if (row >= Nn) continue;
    float nr = norm[row];
    uint32_t m = mask[row * 16 + colb];
#pragma unroll
    for (int c = 0; c < 8; c++) {
      int ct = cy * 8 + c;
      int col = ct * 16 + colb;
      float v = fmaf(acc[c][r], nr, b1[col]);
      v = fmaxf(v, 0.f);
      v = ((m >> ct) & 1u) ? v * (2.0f * nr) : 0.f;   // dropout + pre-apply src norm
      h1sP[(size_t)row * N_H + col] = pack_hilo(v);
    }
  }
}

// ---------------- GEMM2 (split-bf16 MFMA): zbf = bf16(h1s @ W2) ----------------
__global__ __launch_bounds__(256) void k_gemm2_mfma(
    const uint32_t* __restrict__ h1sP, const uint4* __restrict__ WH,
    const uint4* __restrict__ WL, uint16_t* __restrict__ zbf, int Nn) {
  const int tid = threadIdx.x;
  const int wave = tid >> 6, lane = tid & 63;
  const int row0 = blockIdx.x * 64 + wave * 16;
  const int lrow = lane & 15, lk = lane >> 4;
  int arow = row0 + lrow; if (arow >= Nn) arow = Nn - 1;

  f32x4 acc[4];
#pragma unroll
  for (int ct = 0; ct < 4; ct++) acc[ct] = f32x4{0.f, 0.f, 0.f, 0.f};

#pragma unroll
  for (int ks = 0; ks < 8; ks++) {
    const uint4* ap = reinterpret_cast<const uint4*>(h1sP + (size_t)arow * N_H + ks * 32 + lk * 8);
    uint4 p0 = ap[0], p1 = ap[1];
    uint32_t pw[8] = {p0.x, p0.y, p0.z, p0.w, p1.x, p1.y, p1.z, p1.w};
    union { ushort u[8]; bf16x8 v; } ah, al;
#pragma unroll
    for (int j = 0; j < 8; j++) { ah.u[j] = (ushort)(pw[j] >> 16); al.u[j] = (ushort)(pw[j] & 0xffffu); }
#pragma unroll
    for (int ct = 0; ct < 4; ct++) {
      union { uint4 q; bf16x8 v; } bh, bl;
      bh.q = WH[(ct * 8 + ks) * 64 + lane];
      bl.q = WL[(ct * 8 + ks) * 64 + lane];
      acc[ct] = __builtin_amdgcn_mfma_f32_16x16x32_bf16(ah.v, bh.v, acc[ct], 0, 0, 0);
      acc[ct] = __builtin_amdgcn_mfma_f32_16x16x32_bf16(ah.v, bl.v, acc[ct], 0, 0, 0);
      acc[ct] = __builtin_amdgcn_mfma_f32_16x16x32_bf16(al.v, bh.v, acc[ct], 0, 0, 0);
    }
  }

  const int colb = lane & 15, rgrp = lane >> 4;
#pragma unroll
  for (int r = 0; r < 4; r++) {
    int row = row0 + rgrp * 4 + r;
    if (row >= Nn) continue;
#pragma unroll
    for (int ct = 0; ct < 4; ct++)
      zbf[(size_t)row * N_OUT + ct * 16 + colb] = f2bf_rne(acc[ct][r]);
  }
}

// ---------------- layer-2 pull (bf16 gather) fused epilogue ----------------
// 2 nodes/wave, 32 lanes x 2 bf16 (4 B/lane), 4-edge unroll
__global__ __launch_bounds__(256) void k_pull2(
    const uint16_t* __restrict__ zbf, const float* __restrict__ norm,
    const float* __restrict__ b2, const int* __restrict__ rowptr,
    const int* __restrict__ esrc, float* __restrict__ out, int N) {
  int node = blockIdx.x * 8 + (threadIdx.x >> 5);
  if (node >= N) return;
  int lane = threadIdx.x & 31;
  int lo = rowptr[node], hi = rowptr[node + 1];
  float2 a0 = {0,0}, a1 = {0,0}, a2 = {0,0}, a3 = {0,0};
  int e = lo;
  for (; e + 3 < hi; e += 4) {
    int s0 = esrc[e], s1 = esrc[e + 1], s2 = esrc[e + 2], s3 = esrc[e + 3];
    uint32_t v0 = *reinterpret_cast<const uint32_t*>(zbf + (size_t)s0 * N_OUT + lane * 2);
    uint32_t v1 = *reinterpret_cast<const uint32_t*>(zbf + (size_t)s1 * N_OUT + lane * 2);
    uint32_t v2 = *reinterpret_cast<const uint32_t*>(zbf + (size_t)s2 * N_OUT + lane * 2);
    uint32_t v3 = *reinterpret_cast<const uint32_t*>(zbf + (size_t)s3 * N_OUT + lane * 2);
    a0.x += bflo(v0); a0.y += bfhi(v0);
    a1.x += bflo(v1); a1.y += bfhi(v1);
    a2.x += bflo(v2); a2.y += bfhi(v2);
    a3.x += bflo(v3); a3.y += bfhi(v3);
  }
  for (; e < hi; e++) {
    uint32_t v0 = *reinterpret_cast<const uint32_t*>(zbf + (size_t)esrc[e] * N_OUT + lane * 2);
    a0.x += bflo(v0); a0.y += bfhi(v0);
  }
  float nn = norm[node];
  float2 bb = *reinterpret_cast<const float2*>(b2 + lane * 2);
  float2 r;
  r.x = ((a0.x + a1.x) + (a2.x + a3.x)) * nn + bb.x;
  r.y = ((a0.y + a1.y) + (a2.y + a3.y)) * nn + bb.y;
  *reinterpret_cast<float2*>(out + (size_t)node * N_OUT + lane * 2) = r;
}

extern "C" void kernel_launch(void* const* d_in, const int* in_sizes, int n_in,
                              void* d_out, int out_size, void* d_ws, size_t ws_size,
                              hipStream_t stream) {
  const float* h  = (const float*)d_in[0];
  const float* W1 = (const float*)d_in[1];
  const float* b1 = (const float*)d_in[2];
  const float* W2 = (const float*)d_in[3];
  const float* b2 = (const float*)d_in[4];
  const int* eidx = (const int*)d_in[5];
  const int N = in_sizes[0] / N_IN;
  const int E = in_sizes[5] / 2;
  const int NBE = (E + CHK - 1) / CHK;     // bucketing blocks

  char* ws = (char*)d_ws;
  size_t off = 0;
  auto alloc = [&](size_t bytes) { void* p = ws + off; off += (bytes + 511) & ~(size_t)511; return p; };
  int*      eflag  = (int*)alloc(sizeof(int));
  int*      rowptr = (int*)alloc((size_t)(N + 1) * 4);
  float*    norm   = (float*)alloc((size_t)N * 4);
  int*      esrc   = (int*)alloc((size_t)E * 4);
  int*      bktCnt = (int*)alloc((size_t)256 * 4);
  int*      bktOff = (int*)alloc((size_t)256 * 4);
  int*      bktCur = (int*)alloc((size_t)256 * 4);
  uint16_t* mask   = (uint16_t*)alloc((size_t)N * 16 * 2);
  uint4*    W1H    = (uint4*)alloc((size_t)16 * 4 * 64 * 16);
  uint4*    W1L    = (uint4*)alloc((size_t)16 * 4 * 64 * 16);
  uint4*    W2H    = (uint4*)alloc((size_t)4 * 8 * 64 * 16);
  uint4*    W2L    = (uint4*)alloc((size_t)4 * 8 * 64 * 16);
  uint32_t* aggP   = (uint32_t*)alloc((size_t)N * N_IN * 4);
  uint32_t* h1sP   = (uint32_t*)alloc((size_t)N * N_H * 4);
  uint2*    eb     = (uint2*)aggP;      // 6.4 MB; dead before pull1 writes aggP
  uint16_t* hn     = (uint16_t*)h1sP;   // 12.8 MB; dead before gemm1 writes h1sP
  uint16_t* zbf    = (uint16_t*)aggP;   // 6.4 MB; aggP dead after gemm1
  float*    out    = (float*)d_out;

  hipMemsetAsync(bktCnt, 0, 256 * 4, stream);

  // graph-independent prep
  k_packW<<<(16 * 4 * 64 + 255) / 256, 256, 0, stream>>>(W1, W1H, W1L, N_H, 16, 4);
  k_packW<<<(4 * 8 * 64 + 255) / 256, 256, 0, stream>>>(W2, W2H, W2L, N_OUT, 4, 8);
  k_mask<<<(N * 16 + 255) / 256, 256, 0, stream>>>(mask, N);

  k_detect<<<1, 256, 0, stream>>>(eidx, E, eflag);

  // bucketed edge pipeline -> CSR (no global atomics after bscatter)
  k_bhist<<<NBE, 256, 0, stream>>>(eidx, E, eflag, bktCnt);
  k_bscan<<<1, 256, 0, stream>>>(bktCnt, bktOff, bktCur);
  k_bscatter<<<NBE, 256, 0, stream>>>(eidx, E, eflag, bktCur, eb);
  k_bucket_csr<<<256, 256, 0, stream>>>(eb, bktOff, rowptr, norm, esrc, N, E);
  k_sortwave<<<(N + 3) / 4, 256, 0, stream>>>(esrc, rowptr, N);

  // bf16 gather plane: hn = bf16(h * norm[row])
  k_h2bf<<<(N * 32 + 255) / 256, 256, 0, stream>>>(h, norm, hn, N * 32);

  k_pull1<<<(N + 7) / 8, 256, 0, stream>>>(hn, rowptr, esrc, aggP, N);

  dim3 g1((N + 63) / 64, 2);
  k_gemm1_mfma<<<g1, 256, 0, stream>>>(aggP, W1H, W1L, b1, norm, mask, h1sP, N);
  k_gemm2_mfma<<<(N + 63) / 64, 256, 0, stream>>>(h1sP, W2H, W2L, zbf, N);

  k_pull2<<<(N + 7) / 8, 256, 0, stream>>>(zbf, norm, b2, rowptr, esrc, out, N);
}

// Round 10
// 196.278 us; speedup vs baseline: 1.6726x; 1.0605x over previous
//
#include <hip/hip_runtime.h>
#include <stdint.h>

#define N_IN  128
#define N_H   256
#define N_OUT 64
#define CHK   2048   // edges per bucketing block

typedef __attribute__((ext_vector_type(8))) __bf16 bf16x8;
typedef __attribute__((ext_vector_type(4))) float f32x4;

// ---------------- Threefry-2x32 (JAX-compatible) ----------------
__device__ __forceinline__ void tf4(uint32_t& x0, uint32_t& x1,
                                    const int r0, const int r1, const int r2, const int r3) {
  x0 += x1; x1 = (x1 << r0) | (x1 >> (32 - r0)); x1 ^= x0;
  x0 += x1; x1 = (x1 << r1) | (x1 >> (32 - r1)); x1 ^= x0;
  x0 += x1; x1 = (x1 << r2) | (x1 >> (32 - r2)); x1 ^= x0;
  x0 += x1; x1 = (x1 << r3) | (x1 >> (32 - r3)); x1 ^= x0;
}

__device__ __forceinline__ uint2 threefry2x32(uint32_t k0, uint32_t k1, uint32_t x0, uint32_t x1) {
  const uint32_t k2 = k0 ^ k1 ^ 0x1BD11BDAu;
  x0 += k0; x1 += k1;
  tf4(x0, x1, 13, 15, 26, 6);   x0 += k1; x1 += k2 + 1u;
  tf4(x0, x1, 17, 29, 16, 24);  x0 += k2; x1 += k0 + 2u;
  tf4(x0, x1, 13, 15, 26, 6);   x0 += k0; x1 += k1 + 3u;
  tf4(x0, x1, 17, 29, 16, 24);  x0 += k1; x1 += k2 + 4u;
  tf4(x0, x1, 13, 15, 26, 6);   x0 += k2; x1 += k0 + 5u;
  return make_uint2(x0, x1);
}

// split f32 -> (hi,lo) bf16 bit patterns packed in one u32: (hi<<16)|lo
__device__ __forceinline__ uint32_t pack_hilo(float v) {
  uint32_t bits = __builtin_bit_cast(uint32_t, v);
  uint32_t hi = bits & 0xffff0000u;
  float lo = v - __builtin_bit_cast(float, hi);
  uint32_t lob = __builtin_bit_cast(uint32_t, lo) >> 16;
  return hi | lob;
}

// f32 -> bf16 round-to-nearest-even
__device__ __forceinline__ uint16_t f2bf_rne(float v) {
  uint32_t b = __builtin_bit_cast(uint32_t, v);
  b += 0x7fffu + ((b >> 16) & 1u);
  return (uint16_t)(b >> 16);
}
// unpack low/high bf16 of a u32 word
__device__ __forceinline__ float bflo(uint32_t w) { return __builtin_bit_cast(float, w << 16); }
__device__ __forceinline__ float bfhi(uint32_t w) { return __builtin_bit_cast(float, w & 0xffff0000u); }

// ---------------- detect int64-vs-int32 layout + zero bucket counters ----------------
__global__ void k_detect(const int* __restrict__ e, int E, int* __restrict__ flag,
                         int* __restrict__ bktCnt, int* __restrict__ bktCur) {
  __shared__ int s_nz;
  if (threadIdx.x == 0) s_nz = 0;
  __syncthreads();
  bktCnt[threadIdx.x] = 0;
  bktCur[threadIdx.x] = 0;
  int n = E < 2048 ? E : 2048;
  for (int i = threadIdx.x; i < n; i += 256)
    if (e[2 * i + 1] != 0) atomicAdd(&s_nz, 1);
  __syncthreads();
  if (threadIdx.x == 0) *flag = (s_nz == 0) ? 2 : 1;
}

// ---------------- fused prep: dropout mask + W1/W2 fragment packing ----------------
__device__ __forceinline__ void packW_body(const float* __restrict__ W,
                                           uint4* __restrict__ WH, uint4* __restrict__ WL,
                                           int Ncols, int nct, int nks, int g) {
  if (g >= nct * nks * 64) return;
  int lane = g & 63;
  int grp = g >> 6;
  int ks = grp % nks, ct = grp / nks;
  int k0 = ks * 32 + (lane >> 4) * 8;
  int col = ct * 16 + (lane & 15);
  uint32_t hb[8], lb[8];
#pragma unroll
  for (int j = 0; j < 8; j++) {
    float w = W[(size_t)(k0 + j) * Ncols + col];
    uint32_t bits = __builtin_bit_cast(uint32_t, w);
    uint32_t hi = bits & 0xffff0000u;
    float lo = w - __builtin_bit_cast(float, hi);
    hb[j] = hi >> 16;
    lb[j] = __builtin_bit_cast(uint32_t, lo) >> 16;
  }
  WH[g] = make_uint4(hb[0] | (hb[1] << 16), hb[2] | (hb[3] << 16),
                     hb[4] | (hb[5] << 16), hb[6] | (hb[7] << 16));
  WL[g] = make_uint4(lb[0] | (lb[1] << 16), lb[2] | (lb[3] << 16),
                     lb[4] | (lb[5] << 16), lb[6] | (lb[7] << 16));
}

__global__ __launch_bounds__(256) void k_prep(
    uint16_t* __restrict__ mask, int N,
    const float* __restrict__ W1, uint4* __restrict__ W1H, uint4* __restrict__ W1L,
    const float* __restrict__ W2, uint4* __restrict__ W2H, uint4* __restrict__ W2L) {
  const int NBM = (N * 16 + 255) >> 8;
  const int b = blockIdx.x, t = threadIdx.x;
  if (b < NBM) {
    int g = b * 256 + t;
    if (g >= N * 16) return;
    uint32_t row = (uint32_t)(g >> 4), colb = (uint32_t)(g & 15);
    uint32_t base = row * 256u + colb;
    uint32_t m = 0;
#pragma unroll
    for (int ct = 0; ct < 16; ct++) {
      uint2 o = threefry2x32(0u, 42u, 0u, base + (uint32_t)ct * 16u);
      uint32_t bits = o.x ^ o.y;
      m |= ((~bits) >> 31) << ct;   // keep <=> top bit clear
    }
    mask[g] = (uint16_t)m;
  } else if (b < NBM + 16) {
    packW_body(W1, W1H, W1L, N_H, 16, 4, (b - NBM) * 256 + t);
  } else {
    packW_body(W2, W2H, W2L, N_OUT, 4, 8, (b - NBM - 16) * 256 + t);
  }
}

// ---------------- edge bucketing (by dst>>8; valid for N <= 65536) ----------------
__global__ __launch_bounds__(256) void k_bhist(const int* __restrict__ eidx, int E,
                                               const int* __restrict__ flag,
                                               int* __restrict__ bktCnt) {
  __shared__ int hist[256];
  hist[threadIdx.x] = 0;
  __syncthreads();
  int stride = *flag;
  int base = blockIdx.x * CHK;
#pragma unroll
  for (int i = 0; i < 8; i++) {
    int e = base + i * 256 + threadIdx.x;
    if (e < E) {
      int d = eidx[(size_t)(E + e) * stride];
      atomicAdd(&hist[d >> 8], 1);
    }
  }
  __syncthreads();
  int hv = hist[threadIdx.x];
  if (hv) atomicAdd(&bktCnt[threadIdx.x], hv);
}

// bucket scatter; bucket offsets computed locally from bktCnt (no separate scan kernel)
__global__ __launch_bounds__(256) void k_bscatter(const int* __restrict__ eidx, int E,
                                                  const int* __restrict__ flag,
                                                  const int* __restrict__ bktCnt,
                                                  int* __restrict__ bktCur,
                                                  uint2* __restrict__ eb) {
  __shared__ int s[256];
  __shared__ int hist[256];
  __shared__ int base[256];
  const int t = threadIdx.x;
  // local inclusive scan of bucket counts -> exclusive offset
  int xc = bktCnt[t];
  s[t] = xc;
  __syncthreads();
  for (int off = 1; off < 256; off <<= 1) {
    int u = (t >= off) ? s[t - off] : 0;
    __syncthreads();
    s[t] += u;
    __syncthreads();
  }
  int myOff = s[t] - xc;
  hist[t] = 0;
  __syncthreads();

  int stride = *flag;
  int cb = blockIdx.x * CHK;
  int dc[8], sc[8];
#pragma unroll
  for (int i = 0; i < 8; i++) {
    int e = cb + i * 256 + t;
    if (e < E) {
      dc[i] = eidx[(size_t)(E + e) * stride];
      sc[i] = eidx[(size_t)e * stride];
      atomicAdd(&hist[dc[i] >> 8], 1);
    } else dc[i] = -1;
  }
  __syncthreads();
  int h = hist[t];
  if (h) base[t] = myOff + atomicAdd(&bktCur[t], h);
  __syncthreads();
  hist[t] = 0;   // reuse as intra-block cursor
  __syncthreads();
#pragma unroll
  for (int i = 0; i < 8; i++) {
    if (dc[i] >= 0) {
      int b = dc[i] >> 8;
      int r = atomicAdd(&hist[b], 1);
      eb[base[b] + r] = make_uint2((unsigned)sc[i], (unsigned)dc[i]);
    }
  }
}

// ---------------- per-bucket CSR build (bucket bounds from local scan) ----------------
__global__ __launch_bounds__(256) void k_bucket_csr(
    const uint2* __restrict__ eb, const int* __restrict__ bktCnt,
    int* __restrict__ rowptr, float* __restrict__ norm,
    int* __restrict__ esrc, int N, int E) {
  __shared__ int s[256];
  __shared__ int cnt[256];
  __shared__ int pfx[256];
  __shared__ int cur[256];
  const int b = blockIdx.x, t = threadIdx.x;
  if (b == 0 && t == 0) rowptr[N] = E;
  if (b * 256 >= N) return;
  // bucket bounds
  int xc = bktCnt[t];
  s[t] = xc;
  __syncthreads();
  for (int off = 1; off < 256; off <<= 1) {
    int u = (t >= off) ? s[t - off] : 0;
    __syncthreads();
    s[t] += u;
    __syncthreads();
  }
  const int lo = (b > 0) ? s[b - 1] : 0;
  const int hi = s[b];
  cnt[t] = 0;
  __syncthreads();
  for (int e = lo + t; e < hi; e += 256)
    atomicAdd(&cnt[eb[e].y & 255u], 1);
  __syncthreads();
  int x = cnt[t];
  pfx[t] = x;
  __syncthreads();
  for (int off = 1; off < 256; off <<= 1) {
    int u = (t >= off) ? pfx[t - off] : 0;
    __syncthreads();
    pfx[t] += u;
    __syncthreads();
  }
  int excl = pfx[t] - x;
  int node = b * 256 + t;
  if (node < N) {
    rowptr[node] = lo + excl;
    norm[node] = x > 0 ? rsqrtf((float)x) : 1.0f;
  }
  cur[t] = excl;
  __syncthreads();
  for (int e = lo + t; e < hi; e += 256) {
    uint2 r = eb[e];
    int d = (int)(r.y & 255u);
    int p = atomicAdd(&cur[d], 1);
    esrc[lo + p] = (int)r.x;
  }
}

// ---------------- wave-parallel bitonic row sort (canonical deterministic order) ----------------
__global__ __launch_bounds__(256) void k_sortwave(int* __restrict__ esrc,
                                                  const int* __restrict__ rowptr, int N) {
  int node = blockIdx.x * 4 + (threadIdx.x >> 6);
  if (node >= N) return;
  const int lane = threadIdx.x & 63;
  int lo = rowptr[node], hi = rowptr[node + 1], d = hi - lo;
  if (d <= 1) return;
  if (d <= 64) {
    int v = (lane < d) ? esrc[lo + lane] : 0x7fffffff;
#pragma unroll
    for (int k = 2; k <= 64; k <<= 1) {
#pragma unroll
      for (int j = k >> 1; j > 0; j >>= 1) {
        int other = __shfl_xor(v, j);
        bool up = ((lane & k) == 0);
        bool lower = ((lane & j) == 0);
        int mn = min(v, other), mx = max(v, other);
        v = (up == lower) ? mn : mx;
      }
    }
    if (lane < d) esrc[lo + lane] = v;
  } else if (lane == 0) {
    for (int i = lo + 1; i < hi; i++) {
      int v = esrc[i];
      int j = i - 1;
      while (j >= lo && esrc[j] > v) { esrc[j + 1] = esrc[j]; j--; }
      esrc[j + 1] = v;
    }
  }
}

// ---------------- hn = bf16(h * norm[row]) plane (12.8 MB) ----------------
__global__ __launch_bounds__(256) void k_h2bf(const float* __restrict__ h,
                                              const float* __restrict__ norm,
                                              uint16_t* __restrict__ hn, int total4) {
  int g = blockIdx.x * 256 + threadIdx.x;   // one thread per 4 elems
  if (g >= total4) return;
  float nr = norm[g >> 5];                  // 32 threads per 128-elem row
  float4 v = *reinterpret_cast<const float4*>(h + (size_t)g * 4);
  ushort4 r;
  r.x = f2bf_rne(v.x * nr);
  r.y = f2bf_rne(v.y * nr);
  r.z = f2bf_rne(v.z * nr);
  r.w = f2bf_rne(v.w * nr);
  *reinterpret_cast<ushort4*>(hn + (size_t)g * 4) = r;
}

// ---------------- layer-1 pull (bf16 gather): agg[n] = sum hn[s] ----------------
// 2 nodes/wave, 32 lanes x 4 bf16 (8 B/lane), 8-edge unroll
__global__ __launch_bounds__(256) void k_pull1(
    const uint16_t* __restrict__ hn, const int* __restrict__ rowptr,
    const int* __restrict__ esrc, uint32_t* __restrict__ aggP, int N) {
  int node = blockIdx.x * 8 + (threadIdx.x >> 5);
  if (node >= N) return;
  int lane = threadIdx.x & 31;
  int lo = rowptr[node], hi = rowptr[node + 1];
  float4 a0 = {0,0,0,0}, a1 = {0,0,0,0}, a2 = {0,0,0,0}, a3 = {0,0,0,0};
  int e = lo;
  for (; e + 7 < hi; e += 8) {
    int s0 = esrc[e],     s1 = esrc[e + 1], s2 = esrc[e + 2], s3 = esrc[e + 3];
    int s4 = esrc[e + 4], s5 = esrc[e + 5], s6 = esrc[e + 6], s7 = esrc[e + 7];
    uint2 v0 = *reinterpret_cast<const uint2*>(hn + (size_t)s0 * N_IN + lane * 4);
    uint2 v1 = *reinterpret_cast<const uint2*>(hn + (size_t)s1 * N_IN + lane * 4);
    uint2 v2 = *reinterpret_cast<const uint2*>(hn + (size_t)s2 * N_IN + lane * 4);
    uint2 v3 = *reinterpret_cast<const uint2*>(hn + (size_t)s3 * N_IN + lane * 4);
    uint2 v4 = *reinterpret_cast<const uint2*>(hn + (size_t)s4 * N_IN + lane * 4);
    uint2 v5 = *reinterpret_cast<const uint2*>(hn + (size_t)s5 * N_IN + lane * 4);
    uint2 v6 = *reinterpret_cast<const uint2*>(hn + (size_t)s6 * N_IN + lane * 4);
    uint2 v7 = *reinterpret_cast<const uint2*>(hn + (size_t)s7 * N_IN + lane * 4);
    a0.x += bflo(v0.x); a0.y += bfhi(v0.x); a0.z += bflo(v0.y); a0.w += bfhi(v0.y);
    a1.x += bflo(v1.x); a1.y += bfhi(v1.x); a1.z += bflo(v1.y); a1.w += bfhi(v1.y);
    a2.x += bflo(v2.x); a2.y += bfhi(v2.x); a2.z += bflo(v2.y); a2.w += bfhi(v2.y);
    a3.x += bflo(v3.x); a3.y += bfhi(v3.x); a3.z += bflo(v3.y); a3.w += bfhi(v3.y);
    a0.x += bflo(v4.x); a0.y += bfhi(v4.x); a0.z += bflo(v4.y); a0.w += bfhi(v4.y);
    a1.x += bflo(v5.x); a1.y += bfhi(v5.x); a1.z += bflo(v5.y); a1.w += bfhi(v5.y);
    a2.x += bflo(v6.x); a2.y += bfhi(v6.x); a2.z += bflo(v6.y); a2.w += bfhi(v6.y);
    a3.x += bflo(v7.x); a3.y += bfhi(v7.x); a3.z += bflo(v7.y); a3.w += bfhi(v7.y);
  }
  for (; e < hi; e++) {
    uint2 v0 = *reinterpret_cast<const uint2*>(hn + (size_t)esrc[e] * N_IN + lane * 4);
    a0.x += bflo(v0.x); a0.y += bfhi(v0.x); a0.z += bflo(v0.y); a0.w += bfhi(v0.y);
  }
  float4 r;
  r.x = (a0.x + a1.x) + (a2.x + a3.x);
  r.y = (a0.y + a1.y) + (a2.y + a3.y);
  r.z = (a0.z + a1.z) + (a2.z + a3.z);
  r.w = (a0.w + a1.w) + (a2.w + a3.w);
  uint4 p = make_uint4(pack_hilo(r.x), pack_hilo(r.y), pack_hilo(r.z), pack_hilo(r.w));
  *reinterpret_cast<uint4*>(aggP + (size_t)node * N_IN + lane * 4) = p;
}

// ---------------- GEMM1 (split-bf16 MFMA, no LDS, col-split by blockIdx.y) ----------------
// output h1sB is plain bf16 (u16)
__global__ __launch_bounds__(256) void k_gemm1_mfma(
    const uint32_t* __restrict__ aggP, const uint4* __restrict__ WH,
    const uint4* __restrict__ WL, const float* __restrict__ b1,
    const float* __restrict__ norm, const uint16_t* __restrict__ mask,
    uint16_t* __restrict__ h1sB, int Nn) {
  const int tid = threadIdx.x;
  const int wave = tid >> 6, lane = tid & 63;
  const int row0 = blockIdx.x * 64 + wave * 16;
  const int cy = blockIdx.y;
  const int lrow = lane & 15, lk = lane >> 4;
  int arow = row0 + lrow; if (arow >= Nn) arow = Nn - 1;

  f32x4 acc[8];
#pragma unroll
  for (int c = 0; c < 8; c++) acc[c] = f32x4{0.f, 0.f, 0.f, 0.f};

#pragma unroll
  for (int ks = 0; ks < 4; ks++) {
    const uint4* ap = reinterpret_cast<const uint4*>(aggP + (size_t)arow * N_IN + ks * 32 + lk * 8);
    uint4 p0 = ap[0], p1 = ap[1];
    uint32_t pw[8] = {p0.x, p0.y, p0.z, p0.w, p1.x, p1.y, p1.z, p1.w};
    union { ushort u[8]; bf16x8 v; } ah, al;
#pragma unroll
    for (int j = 0; j < 8; j++) { ah.u[j] = (ushort)(pw[j] >> 16); al.u[j] = (ushort)(pw[j] & 0xffffu); }
#pragma unroll
    for (int c = 0; c < 8; c++) {
      int ct = cy * 8 + c;
      union { uint4 q; bf16x8 v; } bh, bl;
      bh.q = WH[(ct * 4 + ks) * 64 + lane];
      bl.q = WL[(ct * 4 + ks) * 64 + lane];
      acc[c] = __builtin_amdgcn_mfma_f32_16x16x32_bf16(ah.v, bh.v, acc[c], 0, 0, 0);
      acc[c] = __builtin_amdgcn_mfma_f32_16x16x32_bf16(ah.v, bl.v, acc[c], 0, 0, 0);
      acc[c] = __builtin_amdgcn_mfma_f32_16x16x32_bf16(al.v, bh.v, acc[c], 0, 0, 0);
    }
  }

  const int colb = lane & 15, rgrp = lane >> 4;
#pragma unroll
  for (int r = 0; r < 4; r++) {
    int row = row0 + rgrp * 4 + r;
    if (row >= Nn) continue;
    float nr = norm[row];
    uint32_t m = mask[row * 16 + colb];
#pragma unroll
    for (int c = 0; c < 8; c++) {
      int ct = cy * 8 + c;
      int col = ct * 16 + colb;
      float v = fmaf(acc[c][r], nr, b1[col]);
      v = fmaxf(v, 0.f);
      v = ((m >> ct) & 1u) ? v * (2.0f * nr) : 0.f;   // dropout + pre-apply src norm
      h1sB[(size_t)row * N_H + col] = f2bf_rne(v);
    }
  }
}

// ---------------- GEMM2 (A=bf16, B split hi/lo): zbf = bf16(h1s @ W2) ----------------
__global__ __launch_bounds__(256) void k_gemm2_mfma(
    const uint16_t* __restrict__ h1sB, const uint4* __restrict__ WH,
    const uint4* __restrict__ WL, uint16_t* __restrict__ zbf, int Nn) {
  const int tid = threadIdx.x;
  const int wave = tid >> 6, lane = tid & 63;
  const int row0 = blockIdx.x * 64 + wave * 16;
  const int lrow = lane & 15, lk = lane >> 4;
  int arow = row0 + lrow; if (arow >= Nn) arow = Nn - 1;

  f32x4 acc[4];
#pragma unroll
  for (int ct = 0; ct < 4; ct++) acc[ct] = f32x4{0.f, 0.f, 0.f, 0.f};

#pragma unroll
  for (int ks = 0; ks < 8; ks++) {
    union { uint4 q; bf16x8 v; } ah;
    ah.q = *reinterpret_cast<const uint4*>(h1sB + (size_t)arow * N_H + ks * 32 + lk * 8);
#pragma unroll
    for (int ct = 0; ct < 4; ct++) {
      union { uint4 q; bf16x8 v; } bh, bl;
      bh.q = WH[(ct * 8 + ks) * 64 + lane];
      bl.q = WL[(ct * 8 + ks) * 64 + lane];
      acc[ct] = __builtin_amdgcn_mfma_f32_16x16x32_bf16(ah.v, bh.v, acc[ct], 0, 0, 0);
      acc[ct] = __builtin_amdgcn_mfma_f32_16x16x32_bf16(ah.v, bl.v, acc[ct], 0, 0, 0);
    }
  }

  const int colb = lane & 15, rgrp = lane >> 4;
#pragma unroll
  for (int r = 0; r < 4; r++) {
    int row = row0 + rgrp * 4 + r;
    if (row >= Nn) continue;
#pragma unroll
    for (int ct = 0; ct < 4; ct++)
      zbf[(size_t)row * N_OUT + ct * 16 + colb] = f2bf_rne(acc[ct][r]);
  }
}

// ---------------- layer-2 pull (bf16 gather) fused epilogue ----------------
// 2 nodes/wave, 32 lanes x 2 bf16 (4 B/lane), 8-edge unroll
__global__ __launch_bounds__(256) void k_pull2(
    const uint16_t* __restrict__ zbf, const float* __restrict__ norm,
    const float* __restrict__ b2, const int* __restrict__ rowptr,
    const int* __restrict__ esrc, float* __restrict__ out, int N) {
  int node = blockIdx.x * 8 + (threadIdx.x >> 5);
  if (node >= N) return;
  int lane = threadIdx.x & 31;
  int lo = rowptr[node], hi = rowptr[node + 1];
  float2 a0 = {0,0}, a1 = {0,0}, a2 = {0,0}, a3 = {0,0};
  int e = lo;
  for (; e + 7 < hi; e += 8) {
    int s0 = esrc[e],     s1 = esrc[e + 1], s2 = esrc[e + 2], s3 = esrc[e + 3];
    int s4 = esrc[e + 4], s5 = esrc[e + 5], s6 = esrc[e + 6], s7 = esrc[e + 7];
    uint32_t v0 = *reinterpret_cast<const uint32_t*>(zbf + (size_t)s0 * N_OUT + lane * 2);
    uint32_t v1 = *reinterpret_cast<const uint32_t*>(zbf + (size_t)s1 * N_OUT + lane * 2);
    uint32_t v2 = *reinterpret_cast<const uint32_t*>(zbf + (size_t)s2 * N_OUT + lane * 2);
    uint32_t v3 = *reinterpret_cast<const uint32_t*>(zbf + (size_t)s3 * N_OUT + lane * 2);
    uint32_t v4 = *reinterpret_cast<const uint32_t*>(zbf + (size_t)s4 * N_OUT + lane * 2);
    uint32_t v5 = *reinterpret_cast<const uint32_t*>(zbf + (size_t)s5 * N_OUT + lane * 2);
    uint32_t v6 = *reinterpret_cast<const uint32_t*>(zbf + (size_t)s6 * N_OUT + lane * 2);
    uint32_t v7 = *reinterpret_cast<const uint32_t*>(zbf + (size_t)s7 * N_OUT + lane * 2);
    a0.x += bflo(v0); a0.y += bfhi(v0);
    a1.x += bflo(v1); a1.y += bfhi(v1);
    a2.x += bflo(v2); a2.y += bfhi(v2);
    a3.x += bflo(v3); a3.y += bfhi(v3);
    a0.x += bflo(v4); a0.y += bfhi(v4);
    a1.x += bflo(v5); a1.y += bfhi(v5);
    a2.x += bflo(v6); a2.y += bfhi(v6);
    a3.x += bflo(v7); a3.y += bfhi(v7);
  }
  for (; e < hi; e++) {
    uint32_t v0 = *reinterpret_cast<const uint32_t*>(zbf + (size_t)esrc[e] * N_OUT + lane * 2);
    a0.x += bflo(v0); a0.y += bfhi(v0);
  }
  float nn = norm[node];
  float2 bb = *reinterpret_cast<const float2*>(b2 + lane * 2);
  float2 r;
  r.x = ((a0.x + a1.x) + (a2.x + a3.x)) * nn + bb.x;
  r.y = ((a0.y + a1.y) + (a2.y + a3.y)) * nn + bb.y;
  *reinterpret_cast<float2*>(out + (size_t)node * N_OUT + lane * 2) = r;
}

extern "C" void kernel_launch(void* const* d_in, const int* in_sizes, int n_in,
                              void* d_out, int out_size, void* d_ws, size_t ws_size,
                              hipStream_t stream) {
  const float* h  = (const float*)d_in[0];
  const float* W1 = (const float*)d_in[1];
  const float* b1 = (const float*)d_in[2];
  const float* W2 = (const float*)d_in[3];
  const float* b2 = (const float*)d_in[4];
  const int* eidx = (const int*)d_in[5];
  const int N = in_sizes[0] / N_IN;
  const int E = in_sizes[5] / 2;
  const int NBE = (E + CHK - 1) / CHK;     // bucketing blocks

  char* ws = (char*)d_ws;
  size_t off = 0;
  auto alloc = [&](size_t bytes) { void* p = ws + off; off += (bytes + 511) & ~(size_t)511; return p; };
  int*      eflag  = (int*)alloc(sizeof(int));
  int*      rowptr = (int*)alloc((size_t)(N + 1) * 4);
  float*    norm   = (float*)alloc((size_t)N * 4);
  int*      esrc   = (int*)alloc((size_t)E * 4);
  int*      bktCnt = (int*)alloc((size_t)256 * 4);
  int*      bktCur = (int*)alloc((size_t)256 * 4);
  uint16_t* mask   = (uint16_t*)alloc((size_t)N * 16 * 2);
  uint4*    W1H    = (uint4*)alloc((size_t)16 * 4 * 64 * 16);
  uint4*    W1L    = (uint4*)alloc((size_t)16 * 4 * 64 * 16);
  uint4*    W2H    = (uint4*)alloc((size_t)4 * 8 * 64 * 16);
  uint4*    W2L    = (uint4*)alloc((size_t)4 * 8 * 64 * 16);
  uint32_t* aggP   = (uint32_t*)alloc((size_t)N * N_IN * 4);
  uint16_t* h1sB   = (uint16_t*)alloc((size_t)N * N_H * 2);
  uint2*    eb     = (uint2*)aggP;      // 6.4 MB; dead before pull1 writes aggP
  uint16_t* hn     = (uint16_t*)h1sB;   // 12.8 MB; dead before gemm1 writes h1sB (25.6 MB)
  uint16_t* zbf    = (uint16_t*)aggP;   // 6.4 MB; aggP dead after gemm1
  float*    out    = (float*)d_out;

  // 1. detect layout + zero bucket counters
  k_detect<<<1, 256, 0, stream>>>(eidx, E, eflag, bktCnt, bktCur);

  // 2. fused graph-independent prep (dropout mask + W packs)
  {
    int NBM = (N * 16 + 255) / 256;
    k_prep<<<NBM + 16 + 8, 256, 0, stream>>>(mask, N, W1, W1H, W1L, W2, W2H, W2L);
  }

  // 3-5. bucketed edge pipeline -> CSR
  k_bhist<<<NBE, 256, 0, stream>>>(eidx, E, eflag, bktCnt);
  k_bscatter<<<NBE, 256, 0, stream>>>(eidx, E, eflag, bktCnt, bktCur, eb);
  k_bucket_csr<<<256, 256, 0, stream>>>(eb, bktCnt, rowptr, norm, esrc, N, E);

  // 6. canonical row order
  k_sortwave<<<(N + 3) / 4, 256, 0, stream>>>(esrc, rowptr, N);

  // 7. bf16 gather plane: hn = bf16(h * norm[row])
  k_h2bf<<<(N * 32 + 255) / 256, 256, 0, stream>>>(h, norm, hn, N * 32);

  // 8. layer-1 aggregation
  k_pull1<<<(N + 7) / 8, 256, 0, stream>>>(hn, rowptr, esrc, aggP, N);

  // 9-10. GEMMs
  dim3 g1((N + 63) / 64, 2);
  k_gemm1_mfma<<<g1, 256, 0, stream>>>(aggP, W1H, W1L, b1, norm, mask, h1sB, N);
  k_gemm2_mfma<<<(N + 63) / 64, 256, 0, stream>>>(h1sB, W2H, W2L, zbf, N);

  // 11. layer-2 aggregation + epilogue
  k_pull2<<<(N + 7) / 8, 256, 0, stream>>>(zbf, norm, b2, rowptr, esrc, out, N);
}

// Round 11
// 192.196 us; speedup vs baseline: 1.7081x; 1.0212x over previous
//
#include <hip/hip_runtime.h>
#include <stdint.h>

#define N_IN  128
#define N_H   256
#define N_OUT 64
#define CHK   2048   // edges per bucketing block

typedef __attribute__((ext_vector_type(8))) __bf16 bf16x8;
typedef __attribute__((ext_vector_type(4))) float f32x4;

// ---------------- Threefry-2x32 (JAX-compatible) ----------------
__device__ __forceinline__ void tf4(uint32_t& x0, uint32_t& x1,
                                    const int r0, const int r1, const int r2, const int r3) {
  x0 += x1; x1 = (x1 << r0) | (x1 >> (32 - r0)); x1 ^= x0;
  x0 += x1; x1 = (x1 << r1) | (x1 >> (32 - r1)); x1 ^= x0;
  x0 += x1; x1 = (x1 << r2) | (x1 >> (32 - r2)); x1 ^= x0;
  x0 += x1; x1 = (x1 << r3) | (x1 >> (32 - r3)); x1 ^= x0;
}

__device__ __forceinline__ uint2 threefry2x32(uint32_t k0, uint32_t k1, uint32_t x0, uint32_t x1) {
  const uint32_t k2 = k0 ^ k1 ^ 0x1BD11BDAu;
  x0 += k0; x1 += k1;
  tf4(x0, x1, 13, 15, 26, 6);   x0 += k1; x1 += k2 + 1u;
  tf4(x0, x1, 17, 29, 16, 24);  x0 += k2; x1 += k0 + 2u;
  tf4(x0, x1, 13, 15, 26, 6);   x0 += k0; x1 += k1 + 3u;
  tf4(x0, x1, 17, 29, 16, 24);  x0 += k1; x1 += k2 + 4u;
  tf4(x0, x1, 13, 15, 26, 6);   x0 += k2; x1 += k0 + 5u;
  return make_uint2(x0, x1);
}

// f32 -> bf16 round-to-nearest-even
__device__ __forceinline__ uint16_t f2bf_rne(float v) {
  uint32_t b = __builtin_bit_cast(uint32_t, v);
  b += 0x7fffu + ((b >> 16) & 1u);
  return (uint16_t)(b >> 16);
}
// unpack low/high bf16 of a u32 word
__device__ __forceinline__ float bflo(uint32_t w) { return __builtin_bit_cast(float, w << 16); }
__device__ __forceinline__ float bfhi(uint32_t w) { return __builtin_bit_cast(float, w & 0xffff0000u); }

// ---------------- detect int64-vs-int32 layout + zero bucket counters ----------------
__global__ void k_detect(const int* __restrict__ e, int E, int* __restrict__ flag,
                         int* __restrict__ bktCnt, int* __restrict__ bktCur) {
  __shared__ int s_nz;
  if (threadIdx.x == 0) s_nz = 0;
  __syncthreads();
  bktCnt[threadIdx.x] = 0;
  bktCur[threadIdx.x] = 0;
  int n = E < 2048 ? E : 2048;
  for (int i = threadIdx.x; i < n; i += 256)
    if (e[2 * i + 1] != 0) atomicAdd(&s_nz, 1);
  __syncthreads();
  if (threadIdx.x == 0) *flag = (s_nz == 0) ? 2 : 1;
}

// ---------------- fused prep: dropout mask + W1/W2 fragment packing ----------------
__device__ __forceinline__ void packW_body(const float* __restrict__ W,
                                           uint4* __restrict__ WH, uint4* __restrict__ WL,
                                           int Ncols, int nct, int nks, int g) {
  if (g >= nct * nks * 64) return;
  int lane = g & 63;
  int grp = g >> 6;
  int ks = grp % nks, ct = grp / nks;
  int k0 = ks * 32 + (lane >> 4) * 8;
  int col = ct * 16 + (lane & 15);
  uint32_t hb[8], lb[8];
#pragma unroll
  for (int j = 0; j < 8; j++) {
    float w = W[(size_t)(k0 + j) * Ncols + col];
    uint32_t bits = __builtin_bit_cast(uint32_t, w);
    uint32_t hi = bits & 0xffff0000u;
    float lo = w - __builtin_bit_cast(float, hi);
    hb[j] = hi >> 16;
    lb[j] = __builtin_bit_cast(uint32_t, lo) >> 16;
  }
  WH[g] = make_uint4(hb[0] | (hb[1] << 16), hb[2] | (hb[3] << 16),
                     hb[4] | (hb[5] << 16), hb[6] | (hb[7] << 16));
  WL[g] = make_uint4(lb[0] | (lb[1] << 16), lb[2] | (lb[3] << 16),
                     lb[4] | (lb[5] << 16), lb[6] | (lb[7] << 16));
}

__global__ __launch_bounds__(256) void k_prep(
    uint16_t* __restrict__ mask, int N,
    const float* __restrict__ W1, uint4* __restrict__ W1H, uint4* __restrict__ W1L,
    const float* __restrict__ W2, uint4* __restrict__ W2H, uint4* __restrict__ W2L) {
  const int NBM = (N * 16 + 255) >> 8;
  const int b = blockIdx.x, t = threadIdx.x;
  if (b < NBM) {
    int g = b * 256 + t;
    if (g >= N * 16) return;
    uint32_t row = (uint32_t)(g >> 4), colb = (uint32_t)(g & 15);
    uint32_t base = row * 256u + colb;
    uint32_t m = 0;
#pragma unroll
    for (int ct = 0; ct < 16; ct++) {
      uint2 o = threefry2x32(0u, 42u, 0u, base + (uint32_t)ct * 16u);
      uint32_t bits = o.x ^ o.y;
      m |= ((~bits) >> 31) << ct;   // keep <=> top bit clear
    }
    mask[g] = (uint16_t)m;
  } else if (b < NBM + 16) {
    packW_body(W1, W1H, W1L, N_H, 16, 4, (b - NBM) * 256 + t);
  } else {
    packW_body(W2, W2H, W2L, N_OUT, 4, 8, (b - NBM - 16) * 256 + t);
  }
}

// ---------------- edge bucketing (by dst>>8; valid for N <= 65536) ----------------
__global__ __launch_bounds__(256) void k_bhist(const int* __restrict__ eidx, int E,
                                               const int* __restrict__ flag,
                                               int* __restrict__ bktCnt) {
  __shared__ int hist[256];
  hist[threadIdx.x] = 0;
  __syncthreads();
  int stride = *flag;
  int base = blockIdx.x * CHK;
#pragma unroll
  for (int i = 0; i < 8; i++) {
    int e = base + i * 256 + threadIdx.x;
    if (e < E) {
      int d = eidx[(size_t)(E + e) * stride];
      atomicAdd(&hist[d >> 8], 1);
    }
  }
  __syncthreads();
  int hv = hist[threadIdx.x];
  if (hv) atomicAdd(&bktCnt[threadIdx.x], hv);
}

// bucket scatter; bucket offsets computed locally from bktCnt (no separate scan kernel)
__global__ __launch_bounds__(256) void k_bscatter(const int* __restrict__ eidx, int E,
                                                  const int* __restrict__ flag,
                                                  const int* __restrict__ bktCnt,
                                                  int* __restrict__ bktCur,
                                                  uint2* __restrict__ eb) {
  __shared__ int s[256];
  __shared__ int hist[256];
  __shared__ int base[256];
  const int t = threadIdx.x;
  int xc = bktCnt[t];
  s[t] = xc;
  __syncthreads();
  for (int off = 1; off < 256; off <<= 1) {
    int u = (t >= off) ? s[t - off] : 0;
    __syncthreads();
    s[t] += u;
    __syncthreads();
  }
  int myOff = s[t] - xc;
  hist[t] = 0;
  __syncthreads();

  int stride = *flag;
  int cb = blockIdx.x * CHK;
  int dc[8], sc[8];
#pragma unroll
  for (int i = 0; i < 8; i++) {
    int e = cb + i * 256 + t;
    if (e < E) {
      dc[i] = eidx[(size_t)(E + e) * stride];
      sc[i] = eidx[(size_t)e * stride];
      atomicAdd(&hist[dc[i] >> 8], 1);
    } else dc[i] = -1;
  }
  __syncthreads();
  int h = hist[t];
  if (h) base[t] = myOff + atomicAdd(&bktCur[t], h);
  __syncthreads();
  hist[t] = 0;   // reuse as intra-block cursor
  __syncthreads();
#pragma unroll
  for (int i = 0; i < 8; i++) {
    if (dc[i] >= 0) {
      int b = dc[i] >> 8;
      int r = atomicAdd(&hist[b], 1);
      eb[base[b] + r] = make_uint2((unsigned)sc[i], (unsigned)dc[i]);
    }
  }
}

// ---------------- per-bucket CSR build (bucket bounds from local scan) ----------------
__global__ __launch_bounds__(256) void k_bucket_csr(
    const uint2* __restrict__ eb, const int* __restrict__ bktCnt,
    int* __restrict__ rowptr, float* __restrict__ norm,
    int* __restrict__ esrc, int N, int E) {
  __shared__ int s[256];
  __shared__ int cnt[256];
  __shared__ int pfx[256];
  __shared__ int cur[256];
  const int b = blockIdx.x, t = threadIdx.x;
  if (b == 0 && t == 0) rowptr[N] = E;
  if (b * 256 >= N) return;
  int xc = bktCnt[t];
  s[t] = xc;
  __syncthreads();
  for (int off = 1; off < 256; off <<= 1) {
    int u = (t >= off) ? s[t - off] : 0;
    __syncthreads();
    s[t] += u;
    __syncthreads();
  }
  const int lo = (b > 0) ? s[b - 1] : 0;
  const int hi = s[b];
  cnt[t] = 0;
  __syncthreads();
  for (int e = lo + t; e < hi; e += 256)
    atomicAdd(&cnt[eb[e].y & 255u], 1);
  __syncthreads();
  int x = cnt[t];
  pfx[t] = x;
  __syncthreads();
  for (int off = 1; off < 256; off <<= 1) {
    int u = (t >= off) ? pfx[t - off] : 0;
    __syncthreads();
    pfx[t] += u;
    __syncthreads();
  }
  int excl = pfx[t] - x;
  int node = b * 256 + t;
  if (node < N) {
    rowptr[node] = lo + excl;
    norm[node] = x > 0 ? rsqrtf((float)x) : 1.0f;
  }
  cur[t] = excl;
  __syncthreads();
  for (int e = lo + t; e < hi; e += 256) {
    uint2 r = eb[e];
    int d = (int)(r.y & 255u);
    int p = atomicAdd(&cur[d], 1);
    esrc[lo + p] = (int)r.x;
  }
}

// ---------------- wave-parallel bitonic row sort (canonical deterministic order) ----------------
__global__ __launch_bounds__(256) void k_sortwave(int* __restrict__ esrc,
                                                  const int* __restrict__ rowptr, int N) {
  int node = blockIdx.x * 4 + (threadIdx.x >> 6);
  if (node >= N) return;
  const int lane = threadIdx.x & 63;
  int lo = rowptr[node], hi = rowptr[node + 1], d = hi - lo;
  if (d <= 1) return;
  if (d <= 64) {
    int v = (lane < d) ? esrc[lo + lane] : 0x7fffffff;
#pragma unroll
    for (int k = 2; k <= 64; k <<= 1) {
#pragma unroll
      for (int j = k >> 1; j > 0; j >>= 1) {
        int other = __shfl_xor(v, j);
        bool up = ((lane & k) == 0);
        bool lower = ((lane & j) == 0);
        int mn = min(v, other), mx = max(v, other);
        v = (up == lower) ? mn : mx;
      }
    }
    if (lane < d) esrc[lo + lane] = v;
  } else if (lane == 0) {
    for (int i = lo + 1; i < hi; i++) {
      int v = esrc[i];
      int j = i - 1;
      while (j >= lo && esrc[j] > v) { esrc[j + 1] = esrc[j]; j--; }
      esrc[j + 1] = v;
    }
  }
}

// ---------------- hn = bf16(h * norm[row]) plane (12.8 MB) ----------------
__global__ __launch_bounds__(256) void k_h2bf(const float* __restrict__ h,
                                              const float* __restrict__ norm,
                                              uint16_t* __restrict__ hn, int total4) {
  int g = blockIdx.x * 256 + threadIdx.x;   // one thread per 4 elems
  if (g >= total4) return;
  float nr = norm[g >> 5];                  // 32 threads per 128-elem row
  float4 v = *reinterpret_cast<const float4*>(h + (size_t)g * 4);
  ushort4 r;
  r.x = f2bf_rne(v.x * nr);
  r.y = f2bf_rne(v.y * nr);
  r.z = f2bf_rne(v.z * nr);
  r.w = f2bf_rne(v.w * nr);
  *reinterpret_cast<ushort4*>(hn + (size_t)g * 4) = r;
}

// ---------------- layer-1 pull (bf16 gather): aggB[n] = bf16(sum hn[s]) ----------------
// 2 nodes/wave, 32 lanes x 4 bf16 (8 B/lane), 8-edge unroll; plain-bf16 output
__global__ __launch_bounds__(256) void k_pull1(
    const uint16_t* __restrict__ hn, const int* __restrict__ rowptr,
    const int* __restrict__ esrc, uint16_t* __restrict__ aggB, int N) {
  int node = blockIdx.x * 8 + (threadIdx.x >> 5);
  if (node >= N) return;
  int lane = threadIdx.x & 31;
  int lo = rowptr[node], hi = rowptr[node + 1];
  float4 a0 = {0,0,0,0}, a1 = {0,0,0,0}, a2 = {0,0,0,0}, a3 = {0,0,0,0};
  int e = lo;
  for (; e + 7 < hi; e += 8) {
    int s0 = esrc[e],     s1 = esrc[e + 1], s2 = esrc[e + 2], s3 = esrc[e + 3];
    int s4 = esrc[e + 4], s5 = esrc[e + 5], s6 = esrc[e + 6], s7 = esrc[e + 7];
    uint2 v0 = *reinterpret_cast<const uint2*>(hn + (size_t)s0 * N_IN + lane * 4);
    uint2 v1 = *reinterpret_cast<const uint2*>(hn + (size_t)s1 * N_IN + lane * 4);
    uint2 v2 = *reinterpret_cast<const uint2*>(hn + (size_t)s2 * N_IN + lane * 4);
    uint2 v3 = *reinterpret_cast<const uint2*>(hn + (size_t)s3 * N_IN + lane * 4);
    uint2 v4 = *reinterpret_cast<const uint2*>(hn + (size_t)s4 * N_IN + lane * 4);
    uint2 v5 = *reinterpret_cast<const uint2*>(hn + (size_t)s5 * N_IN + lane * 4);
    uint2 v6 = *reinterpret_cast<const uint2*>(hn + (size_t)s6 * N_IN + lane * 4);
    uint2 v7 = *reinterpret_cast<const uint2*>(hn + (size_t)s7 * N_IN + lane * 4);
    a0.x += bflo(v0.x); a0.y += bfhi(v0.x); a0.z += bflo(v0.y); a0.w += bfhi(v0.y);
    a1.x += bflo(v1.x); a1.y += bfhi(v1.x); a1.z += bflo(v1.y); a1.w += bfhi(v1.y);
    a2.x += bflo(v2.x); a2.y += bfhi(v2.x); a2.z += bflo(v2.y); a2.w += bfhi(v2.y);
    a3.x += bflo(v3.x); a3.y += bfhi(v3.x); a3.z += bflo(v3.y); a3.w += bfhi(v3.y);
    a0.x += bflo(v4.x); a0.y += bfhi(v4.x); a0.z += bflo(v4.y); a0.w += bfhi(v4.y);
    a1.x += bflo(v5.x); a1.y += bfhi(v5.x); a1.z += bflo(v5.y); a1.w += bfhi(v5.y);
    a2.x += bflo(v6.x); a2.y += bfhi(v6.x); a2.z += bflo(v6.y); a2.w += bfhi(v6.y);
    a3.x += bflo(v7.x); a3.y += bfhi(v7.x); a3.z += bflo(v7.y); a3.w += bfhi(v7.y);
  }
  for (; e < hi; e++) {
    uint2 v0 = *reinterpret_cast<const uint2*>(hn + (size_t)esrc[e] * N_IN + lane * 4);
    a0.x += bflo(v0.x); a0.y += bfhi(v0.x); a0.z += bflo(v0.y); a0.w += bfhi(v0.y);
  }
  float4 r;
  r.x = (a0.x + a1.x) + (a2.x + a3.x);
  r.y = (a0.y + a1.y) + (a2.y + a3.y);
  r.z = (a0.z + a1.z) + (a2.z + a3.z);
  r.w = (a0.w + a1.w) + (a2.w + a3.w);
  ushort4 p = make_ushort4(f2bf_rne(r.x), f2bf_rne(r.y), f2bf_rne(r.z), f2bf_rne(r.w));
  *reinterpret_cast<ushort4*>(aggB + (size_t)node * N_IN + lane * 4) = p;
}

// ---------------- GEMM1 (A plain bf16, B split hi/lo; col-split by blockIdx.y) ----------------
// output h1sB is plain bf16 (u16)
__global__ __launch_bounds__(256) void k_gemm1_mfma(
    const uint16_t* __restrict__ aggB, const uint4* __restrict__ WH,
    const uint4* __restrict__ WL, const float* __restrict__ b1,
    const float* __restrict__ norm, const uint16_t* __restrict__ mask,
    uint16_t* __restrict__ h1sB, int Nn) {
  const int tid = threadIdx.x;
  const int wave = tid >> 6, lane = tid & 63;
  const int row0 = blockIdx.x * 64 + wave * 16;
  const int cy = blockIdx.y;
  const int lrow = lane & 15, lk = lane >> 4;
  int arow = row0 + lrow; if (arow >= Nn) arow = Nn - 1;

  f32x4 acc[8];
#pragma unroll
  for (int c = 0; c < 8; c++) acc[c] = f32x4{0.f, 0.f, 0.f, 0.f};

#pragma unroll
  for (int ks = 0; ks < 4; ks++) {
    union { uint4 q; bf16x8 v; } ah;
    ah.q = *reinterpret_cast<const uint4*>(aggB + (size_t)arow * N_IN + ks * 32 + lk * 8);
#pragma unroll
    for (int c = 0; c < 8; c++) {
      int ct = cy * 8 + c;
      union { uint4 q; bf16x8 v; } bh, bl;
      bh.q = WH[(ct * 4 + ks) * 64 + lane];
      bl.q = WL[(ct * 4 + ks) * 64 + lane];
      acc[c] = __builtin_amdgcn_mfma_f32_16x16x32_bf16(ah.v, bh.v, acc[c], 0, 0, 0);
      acc[c] = __builtin_amdgcn_mfma_f32_16x16x32_bf16(ah.v, bl.v, acc[c], 0, 0, 0);
    }
  }

  const int colb = lane & 15, rgrp = lane >> 4;
#pragma unroll
  for (int r = 0; r < 4; r++) {
    int row = row0 + rgrp * 4 + r;
    if (row >= Nn) continue;
    float nr = norm[row];
    uint32_t m = mask[row * 16 + colb];
#pragma unroll
    for (int c = 0; c < 8; c++) {
      int ct = cy * 8 + c;
      int col = ct * 16 + colb;
      float v = fmaf(acc[c][r], nr, b1[col]);
      v = fmaxf(v, 0.f);
      v = ((m >> ct) & 1u) ? v * (2.0f * nr) : 0.f;   // dropout + pre-apply src norm
      h1sB[(size_t)row * N_H + col] = f2bf_rne(v);
    }
  }
}

// ---------------- GEMM2 (A=bf16, B split hi/lo): zbf = bf16(h1s @ W2) ----------------
__global__ __launch_bounds__(256) void k_gemm2_mfma(
    const uint16_t* __restrict__ h1sB, const uint4* __restrict__ WH,
    const uint4* __restrict__ WL, uint16_t* __restrict__ zbf, int Nn) {
  const int tid = threadIdx.x;
  const int wave = tid >> 6, lane = tid & 63;
  const int row0 = blockIdx.x * 64 + wave * 16;
  const int lrow = lane & 15, lk = lane >> 4;
  int arow = row0 + lrow; if (arow >= Nn) arow = Nn - 1;

  f32x4 acc[4];
#pragma unroll
  for (int ct = 0; ct < 4; ct++) acc[ct] = f32x4{0.f, 0.f, 0.f, 0.f};

#pragma unroll
  for (int ks = 0; ks < 8; ks++) {
    union { uint4 q; bf16x8 v; } ah;
    ah.q = *reinterpret_cast<const uint4*>(h1sB + (size_t)arow * N_H + ks * 32 + lk * 8);
#pragma unroll
    for (int ct = 0; ct < 4; ct++) {
      union { uint4 q; bf16x8 v; } bh, bl;
      bh.q = WH[(ct * 8 + ks) * 64 + lane];
      bl.q = WL[(ct * 8 + ks) * 64 + lane];
      acc[ct] = __builtin_amdgcn_mfma_f32_16x16x32_bf16(ah.v, bh.v, acc[ct], 0, 0, 0);
      acc[ct] = __builtin_amdgcn_mfma_f32_16x16x32_bf16(ah.v, bl.v, acc[ct], 0, 0, 0);
    }
  }

  const int colb = lane & 15, rgrp = lane >> 4;
#pragma unroll
  for (int r = 0; r < 4; r++) {
    int row = row0 + rgrp * 4 + r;
    if (row >= Nn) continue;
#pragma unroll
    for (int ct = 0; ct < 4; ct++)
      zbf[(size_t)row * N_OUT + ct * 16 + colb] = f2bf_rne(acc[ct][r]);
  }
}

// ---------------- layer-2 pull (bf16 gather) fused epilogue ----------------
// 4 nodes/wave, 16 lanes x 4 bf16 (8 B/lane), 8-edge unroll
__global__ __launch_bounds__(256) void k_pull2(
    const uint16_t* __restrict__ zbf, const float* __restrict__ norm,
    const float* __restrict__ b2, const int* __restrict__ rowptr,
    const int* __restrict__ esrc, float* __restrict__ out, int N) {
  int node = blockIdx.x * 16 + (threadIdx.x >> 4);
  if (node >= N) return;
  int lane = threadIdx.x & 15;
  int lo = rowptr[node], hi = rowptr[node + 1];
  float4 a0 = {0,0,0,0}, a1 = {0,0,0,0}, a2 = {0,0,0,0}, a3 = {0,0,0,0};
  int e = lo;
  for (; e + 7 < hi; e += 8) {
    int s0 = esrc[e],     s1 = esrc[e + 1], s2 = esrc[e + 2], s3 = esrc[e + 3];
    int s4 = esrc[e + 4], s5 = esrc[e + 5], s6 = esrc[e + 6], s7 = esrc[e + 7];
    uint2 v0 = *reinterpret_cast<const uint2*>(zbf + (size_t)s0 * N_OUT + lane * 4);
    uint2 v1 = *reinterpret_cast<const uint2*>(zbf + (size_t)s1 * N_OUT + lane * 4);
    uint2 v2 = *reinterpret_cast<const uint2*>(zbf + (size_t)s2 * N_OUT + lane * 4);
    uint2 v3 = *reinterpret_cast<const uint2*>(zbf + (size_t)s3 * N_OUT + lane * 4);
    uint2 v4 = *reinterpret_cast<const uint2*>(zbf + (size_t)s4 * N_OUT + lane * 4);
    uint2 v5 = *reinterpret_cast<const uint2*>(zbf + (size_t)s5 * N_OUT + lane * 4);
    uint2 v6 = *reinterpret_cast<const uint2*>(zbf + (size_t)s6 * N_OUT + lane * 4);
    uint2 v7 = *reinterpret_cast<const uint2*>(zbf + (size_t)s7 * N_OUT + lane * 4);
    a0.x += bflo(v0.x); a0.y += bfhi(v0.x); a0.z += bflo(v0.y); a0.w += bfhi(v0.y);
    a1.x += bflo(v1.x); a1.y += bfhi(v1.x); a1.z += bflo(v1.y); a1.w += bfhi(v1.y);
    a2.x += bflo(v2.x); a2.y += bfhi(v2.x); a2.z += bflo(v2.y); a2.w += bfhi(v2.y);
    a3.x += bflo(v3.x); a3.y += bfhi(v3.x); a3.z += bflo(v3.y); a3.w += bfhi(v3.y);
    a0.x += bflo(v4.x); a0.y += bfhi(v4.x); a0.z += bflo(v4.y); a0.w += bfhi(v4.y);
    a1.x += bflo(v5.x); a1.y += bfhi(v5.x); a1.z += bflo(v5.y); a1.w += bfhi(v5.y);
    a2.x += bflo(v6.x); a2.y += bfhi(v6.x); a2.z += bflo(v6.y); a2.w += bfhi(v6.y);
    a3.x += bflo(v7.x); a3.y += bfhi(v7.x); a3.z += bflo(v7.y); a3.w += bfhi(v7.y);
  }
  for (; e < hi; e++) {
    uint2 v0 = *reinterpret_cast<const uint2*>(zbf + (size_t)esrc[e] * N_OUT + lane * 4);
    a0.x += bflo(v0.x); a0.y += bfhi(v0.x); a0.z += bflo(v0.y); a0.w += bfhi(v0.y);
  }
  float nn = norm[node];
  float4 bb = *reinterpret_cast<const float4*>(b2 + lane * 4);
  float4 r;
  r.x = ((a0.x + a1.x) + (a2.x + a3.x)) * nn + bb.x;
  r.y = ((a0.y + a1.y) + (a2.y + a3.y)) * nn + bb.y;
  r.z = ((a0.z + a1.z) + (a2.z + a3.z)) * nn + bb.z;
  r.w = ((a0.w + a1.w) + (a2.w + a3.w)) * nn + bb.w;
  *reinterpret_cast<float4*>(out + (size_t)node * N_OUT + lane * 4) = r;
}

extern "C" void kernel_launch(void* const* d_in, const int* in_sizes, int n_in,
                              void* d_out, int out_size, void* d_ws, size_t ws_size,
                              hipStream_t stream) {
  const float* h  = (const float*)d_in[0];
  const float* W1 = (const float*)d_in[1];
  const float* b1 = (const float*)d_in[2];
  const float* W2 = (const float*)d_in[3];
  const float* b2 = (const float*)d_in[4];
  const int* eidx = (const int*)d_in[5];
  const int N = in_sizes[0] / N_IN;
  const int E = in_sizes[5] / 2;
  const int NBE = (E + CHK - 1) / CHK;     // bucketing blocks

  char* ws = (char*)d_ws;
  size_t off = 0;
  auto alloc = [&](size_t bytes) { void* p = ws + off; off += (bytes + 511) & ~(size_t)511; return p; };
  int*      eflag  = (int*)alloc(sizeof(int));
  int*      rowptr = (int*)alloc((size_t)(N + 1) * 4);
  float*    norm   = (float*)alloc((size_t)N * 4);
  int*      esrc   = (int*)alloc((size_t)E * 4);
  int*      bktCnt = (int*)alloc((size_t)256 * 4);
  int*      bktCur = (int*)alloc((size_t)256 * 4);
  uint16_t* mask   = (uint16_t*)alloc((size_t)N * 16 * 2);
  uint4*    W1H    = (uint4*)alloc((size_t)16 * 4 * 64 * 16);
  uint4*    W1L    = (uint4*)alloc((size_t)16 * 4 * 64 * 16);
  uint4*    W2H    = (uint4*)alloc((size_t)4 * 8 * 64 * 16);
  uint4*    W2L    = (uint4*)alloc((size_t)4 * 8 * 64 * 16);
  uint16_t* aggB   = (uint16_t*)alloc((size_t)N * N_IN * 2);   // 12.8 MB plain bf16
  uint16_t* h1sB   = (uint16_t*)alloc((size_t)N * N_H * 2);    // 25.6 MB
  uint2*    eb     = (uint2*)aggB;      // 6.4 MB <= 12.8 MB; dead before pull1 writes aggB
  uint16_t* hn     = (uint16_t*)h1sB;   // 12.8 MB; dead before gemm1 writes h1sB
  uint16_t* zbf    = (uint16_t*)aggB;   // 6.4 MB; aggB dead after gemm1
  float*    out    = (float*)d_out;

  // 1. detect layout + zero bucket counters
  k_detect<<<1, 256, 0, stream>>>(eidx, E, eflag, bktCnt, bktCur);

  // 2. fused graph-independent prep (dropout mask + W packs)
  {
    int NBM = (N * 16 + 255) / 256;
    k_prep<<<NBM + 16 + 8, 256, 0, stream>>>(mask, N, W1, W1H, W1L, W2, W2H, W2L);
  }

  // 3-5. bucketed edge pipeline -> CSR
  k_bhist<<<NBE, 256, 0, stream>>>(eidx, E, eflag, bktCnt);
  k_bscatter<<<NBE, 256, 0, stream>>>(eidx, E, eflag, bktCnt, bktCur, eb);
  k_bucket_csr<<<256, 256, 0, stream>>>(eb, bktCnt, rowptr, norm, esrc, N, E);

  // 6. canonical row order
  k_sortwave<<<(N + 3) / 4, 256, 0, stream>>>(esrc, rowptr, N);

  // 7. bf16 gather plane: hn = bf16(h * norm[row])
  k_h2bf<<<(N * 32 + 255) / 256, 256, 0, stream>>>(h, norm, hn, N * 32);

  // 8. layer-1 aggregation (plain-bf16 output)
  k_pull1<<<(N + 7) / 8, 256, 0, stream>>>(hn, rowptr, esrc, aggB, N);

  // 9-10. GEMMs
  dim3 g1((N + 63) / 64, 2);
  k_gemm1_mfma<<<g1, 256, 0, stream>>>(aggB, W1H, W1L, b1, norm, mask, h1sB, N);
  k_gemm2_mfma<<<(N + 63) / 64, 256, 0, stream>>>(h1sB, W2H, W2L, zbf, N);

  // 11. layer-2 aggregation + epilogue
  k_pull2<<<(N + 15) / 16, 256, 0, stream>>>(zbf, norm, b2, rowptr, esrc, out, N);
}

// Round 12
// 163.533 us; speedup vs baseline: 2.0075x; 1.1753x over previous
//
#include <hip/hip_runtime.h>
#include <stdint.h>

#define N_IN  128
#define N_H   256
#define N_OUT 64
#define CHK   2048   // edges per scatter block
#define CAP   6144   // fixed bucket capacity (mean 4096, sigma ~64 -> 32-sigma margin)

typedef __attribute__((ext_vector_type(8))) __bf16 bf16x8;
typedef __attribute__((ext_vector_type(4))) float f32x4;

// ---------------- Threefry-2x32 (JAX-compatible) ----------------
__device__ __forceinline__ void tf4(uint32_t& x0, uint32_t& x1,
                                    const int r0, const int r1, const int r2, const int r3) {
  x0 += x1; x1 = (x1 << r0) | (x1 >> (32 - r0)); x1 ^= x0;
  x0 += x1; x1 = (x1 << r1) | (x1 >> (32 - r1)); x1 ^= x0;
  x0 += x1; x1 = (x1 << r2) | (x1 >> (32 - r2)); x1 ^= x0;
  x0 += x1; x1 = (x1 << r3) | (x1 >> (32 - r3)); x1 ^= x0;
}

__device__ __forceinline__ uint2 threefry2x32(uint32_t k0, uint32_t k1, uint32_t x0, uint32_t x1) {
  const uint32_t k2 = k0 ^ k1 ^ 0x1BD11BDAu;
  x0 += k0; x1 += k1;
  tf4(x0, x1, 13, 15, 26, 6);   x0 += k1; x1 += k2 + 1u;
  tf4(x0, x1, 17, 29, 16, 24);  x0 += k2; x1 += k0 + 2u;
  tf4(x0, x1, 13, 15, 26, 6);   x0 += k0; x1 += k1 + 3u;
  tf4(x0, x1, 17, 29, 16, 24);  x0 += k1; x1 += k2 + 4u;
  tf4(x0, x1, 13, 15, 26, 6);   x0 += k2; x1 += k0 + 5u;
  return make_uint2(x0, x1);
}

// f32 -> bf16 round-to-nearest-even
__device__ __forceinline__ uint16_t f2bf_rne(float v) {
  uint32_t b = __builtin_bit_cast(uint32_t, v);
  b += 0x7fffu + ((b >> 16) & 1u);
  return (uint16_t)(b >> 16);
}
__device__ __forceinline__ float bflo(uint32_t w) { return __builtin_bit_cast(float, w << 16); }
__device__ __forceinline__ float bfhi(uint32_t w) { return __builtin_bit_cast(float, w & 0xffff0000u); }

// ---------------- W fragment packing body ----------------
__device__ __forceinline__ void packW_body(const float* __restrict__ W,
                                           uint4* __restrict__ WH, uint4* __restrict__ WL,
                                           int Ncols, int nct, int nks, int g) {
  if (g >= nct * nks * 64) return;
  int lane = g & 63;
  int grp = g >> 6;
  int ks = grp % nks, ct = grp / nks;
  int k0 = ks * 32 + (lane >> 4) * 8;
  int col = ct * 16 + (lane & 15);
  uint32_t hb[8], lb[8];
#pragma unroll
  for (int j = 0; j < 8; j++) {
    float w = W[(size_t)(k0 + j) * Ncols + col];
    uint32_t bits = __builtin_bit_cast(uint32_t, w);
    uint32_t hi = bits & 0xffff0000u;
    float lo = w - __builtin_bit_cast(float, hi);
    hb[j] = hi >> 16;
    lb[j] = __builtin_bit_cast(uint32_t, lo) >> 16;
  }
  WH[g] = make_uint4(hb[0] | (hb[1] << 16), hb[2] | (hb[3] << 16),
                     hb[4] | (hb[5] << 16), hb[6] | (hb[7] << 16));
  WL[g] = make_uint4(lb[0] | (lb[1] << 16), lb[2] | (lb[3] << 16),
                     lb[4] | (lb[5] << 16), lb[6] | (lb[7] << 16));
}

// ---------------- k_front: fused [edge scatter | dropout mask | W packs] ----------------
// blocks [0, NBE): single-pass edge scatter into fixed-capacity buckets (dst>>8)
// blocks [NBE, NBE+NBM): dropout mask; next 16: packW1; next 8: packW2
__global__ __launch_bounds__(256) void k_front(
    const int* __restrict__ eidx, int E, int* __restrict__ bktCur, uint2* __restrict__ eb,
    uint16_t* __restrict__ mask, int N,
    const float* __restrict__ W1, uint4* __restrict__ W1H, uint4* __restrict__ W1L,
    const float* __restrict__ W2, uint4* __restrict__ W2H, uint4* __restrict__ W2L,
    int NBE) {
  const int b = blockIdx.x, t = threadIdx.x;
  if (b < NBE) {
    __shared__ int s_nz;
    __shared__ int hist[256];
    __shared__ int base[256];
    if (t == 0) s_nz = 0;
    hist[t] = 0;
    __syncthreads();
    // per-block layout detection (first 2048 edges, L2-hot)
    int n = E < 2048 ? E : 2048;
    int nz = 0;
    for (int i = t; i < n; i += 256) nz |= (eidx[2 * i + 1] != 0) ? 1 : 0;
    if (nz) atomicAdd(&s_nz, 1);
    __syncthreads();
    int stride = (s_nz == 0) ? 2 : 1;

    int cb = b * CHK;
    int dc[8], sc[8];
#pragma unroll
    for (int i = 0; i < 8; i++) {
      int e = cb + i * 256 + t;
      if (e < E) {
        dc[i] = eidx[(size_t)(E + e) * stride];
        sc[i] = eidx[(size_t)e * stride];
        atomicAdd(&hist[dc[i] >> 8], 1);
      } else dc[i] = -1;
    }
    __syncthreads();
    int hcnt = hist[t];
    if (hcnt) base[t] = atomicAdd(&bktCur[t], hcnt);
    __syncthreads();
    hist[t] = 0;   // reuse as intra-block cursor
    __syncthreads();
#pragma unroll
    for (int i = 0; i < 8; i++) {
      if (dc[i] >= 0) {
        int bk = dc[i] >> 8;
        int r = atomicAdd(&hist[bk], 1);
        eb[(size_t)bk * CAP + base[bk] + r] = make_uint2((unsigned)sc[i], (unsigned)dc[i]);
      }
    }
  } else {
    const int NBM = (N * 16 + 255) >> 8;
    int bb = b - NBE;
    if (bb < NBM) {
      int g = bb * 256 + t;
      if (g >= N * 16) return;
      uint32_t row = (uint32_t)(g >> 4), colb = (uint32_t)(g & 15);
      uint32_t bse = row * 256u + colb;
      uint32_t m = 0;
#pragma unroll
      for (int ct = 0; ct < 16; ct++) {
        uint2 o = threefry2x32(0u, 42u, 0u, bse + (uint32_t)ct * 16u);
        uint32_t bits = o.x ^ o.y;
        m |= ((~bits) >> 31) << ct;   // keep <=> top bit clear
      }
      mask[g] = (uint16_t)m;
    } else if (bb < NBM + 16) {
      packW_body(W1, W1H, W1L, N_H, 16, 4, (bb - NBM) * 256 + t);
    } else {
      packW_body(W2, W2H, W2L, N_OUT, 4, 8, (bb - NBM - 16) * 256 + t);
    }
  }
}

// ---------------- per-bucket CSR build (counts from bktCur, edges at fixed-cap bases) ----------------
__global__ __launch_bounds__(256) void k_bucket_csr(
    const uint2* __restrict__ eb, const int* __restrict__ bktCur,
    int* __restrict__ rowptr, float* __restrict__ norm,
    int* __restrict__ esrc, int N, int E) {
  __shared__ int s[256];
  __shared__ int cnt[256];
  __shared__ int pfx[256];
  __shared__ int cur[256];
  const int b = blockIdx.x, t = threadIdx.x;
  if (b == 0 && t == 0) rowptr[N] = E;
  if (b * 256 >= N) return;
  int xc = bktCur[t];
  s[t] = xc;
  __syncthreads();
  for (int off = 1; off < 256; off <<= 1) {
    int u = (t >= off) ? s[t - off] : 0;
    __syncthreads();
    s[t] += u;
    __syncthreads();
  }
  const int lo = (b > 0) ? s[b - 1] : 0;
  const int ecnt = s[b] - lo;
  const uint2* ebb = eb + (size_t)b * CAP;
  cnt[t] = 0;
  __syncthreads();
  for (int e = t; e < ecnt; e += 256)
    atomicAdd(&cnt[ebb[e].y & 255u], 1);
  __syncthreads();
  int x = cnt[t];
  pfx[t] = x;
  __syncthreads();
  for (int off = 1; off < 256; off <<= 1) {
    int u = (t >= off) ? pfx[t - off] : 0;
    __syncthreads();
    pfx[t] += u;
    __syncthreads();
  }
  int excl = pfx[t] - x;
  int node = b * 256 + t;
  if (node < N) {
    rowptr[node] = lo + excl;
    norm[node] = x > 0 ? rsqrtf((float)x) : 1.0f;
  }
  cur[t] = excl;
  __syncthreads();
  for (int e = t; e < ecnt; e += 256) {
    uint2 r = ebb[e];
    int d = (int)(r.y & 255u);
    int p = atomicAdd(&cur[d], 1);
    esrc[lo + p] = (int)r.x;
  }
}

// ---------------- k_mid: fused [bitonic row sort | hn = bf16(h*norm) plane] ----------------
__global__ __launch_bounds__(256) void k_mid(
    int* __restrict__ esrc, const int* __restrict__ rowptr, int N,
    const float* __restrict__ h, const float* __restrict__ norm,
    uint16_t* __restrict__ hn, int NS) {
  const int b = blockIdx.x, t = threadIdx.x;
  if (b < NS) {
    int node = b * 4 + (t >> 6);
    if (node >= N) return;
    const int lane = t & 63;
    int lo = rowptr[node], hi = rowptr[node + 1], d = hi - lo;
    if (d <= 1) return;
    if (d <= 64) {
      int v = (lane < d) ? esrc[lo + lane] : 0x7fffffff;
#pragma unroll
      for (int k = 2; k <= 64; k <<= 1) {
#pragma unroll
        for (int j = k >> 1; j > 0; j >>= 1) {
          int other = __shfl_xor(v, j);
          bool up = ((lane & k) == 0);
          bool lower = ((lane & j) == 0);
          int mn = min(v, other), mx = max(v, other);
          v = (up == lower) ? mn : mx;
        }
      }
      if (lane < d) esrc[lo + lane] = v;
    } else if (lane == 0) {
      for (int i = lo + 1; i < hi; i++) {
        int v = esrc[i];
        int j = i - 1;
        while (j >= lo && esrc[j] > v) { esrc[j + 1] = esrc[j]; j--; }
        esrc[j + 1] = v;
      }
    }
  } else {
    int g = (b - NS) * 256 + t;   // one thread per 4 elems
    if (g >= N * 32) return;
    float nr = norm[g >> 5];
    float4 v = *reinterpret_cast<const float4*>(h + (size_t)g * 4);
    ushort4 r;
    r.x = f2bf_rne(v.x * nr);
    r.y = f2bf_rne(v.y * nr);
    r.z = f2bf_rne(v.z * nr);
    r.w = f2bf_rne(v.w * nr);
    *reinterpret_cast<ushort4*>(hn + (size_t)g * 4) = r;
  }
}

// ---------------- layer-1 pull (bf16 gather): aggB[n] = bf16(sum hn[s]) ----------------
__global__ __launch_bounds__(256) void k_pull1(
    const uint16_t* __restrict__ hn, const int* __restrict__ rowptr,
    const int* __restrict__ esrc, uint16_t* __restrict__ aggB, int N) {
  int node = blockIdx.x * 8 + (threadIdx.x >> 5);
  if (node >= N) return;
  int lane = threadIdx.x & 31;
  int lo = rowptr[node], hi = rowptr[node + 1];
  float4 a0 = {0,0,0,0}, a1 = {0,0,0,0}, a2 = {0,0,0,0}, a3 = {0,0,0,0};
  int e = lo;
  for (; e + 7 < hi; e += 8) {
    int s0 = esrc[e],     s1 = esrc[e + 1], s2 = esrc[e + 2], s3 = esrc[e + 3];
    int s4 = esrc[e + 4], s5 = esrc[e + 5], s6 = esrc[e + 6], s7 = esrc[e + 7];
    uint2 v0 = *reinterpret_cast<const uint2*>(hn + (size_t)s0 * N_IN + lane * 4);
    uint2 v1 = *reinterpret_cast<const uint2*>(hn + (size_t)s1 * N_IN + lane * 4);
    uint2 v2 = *reinterpret_cast<const uint2*>(hn + (size_t)s2 * N_IN + lane * 4);
    uint2 v3 = *reinterpret_cast<const uint2*>(hn + (size_t)s3 * N_IN + lane * 4);
    uint2 v4 = *reinterpret_cast<const uint2*>(hn + (size_t)s4 * N_IN + lane * 4);
    uint2 v5 = *reinterpret_cast<const uint2*>(hn + (size_t)s5 * N_IN + lane * 4);
    uint2 v6 = *reinterpret_cast<const uint2*>(hn + (size_t)s6 * N_IN + lane * 4);
    uint2 v7 = *reinterpret_cast<const uint2*>(hn + (size_t)s7 * N_IN + lane * 4);
    a0.x += bflo(v0.x); a0.y += bfhi(v0.x); a0.z += bflo(v0.y); a0.w += bfhi(v0.y);
    a1.x += bflo(v1.x); a1.y += bfhi(v1.x); a1.z += bflo(v1.y); a1.w += bfhi(v1.y);
    a2.x += bflo(v2.x); a2.y += bfhi(v2.x); a2.z += bflo(v2.y); a2.w += bfhi(v2.y);
    a3.x += bflo(v3.x); a3.y += bfhi(v3.x); a3.z += bflo(v3.y); a3.w += bfhi(v3.y);
    a0.x += bflo(v4.x); a0.y += bfhi(v4.x); a0.z += bflo(v4.y); a0.w += bfhi(v4.y);
    a1.x += bflo(v5.x); a1.y += bfhi(v5.x); a1.z += bflo(v5.y); a1.w += bfhi(v5.y);
    a2.x += bflo(v6.x); a2.y += bfhi(v6.x); a2.z += bflo(v6.y); a2.w += bfhi(v6.y);
    a3.x += bflo(v7.x); a3.y += bfhi(v7.x); a3.z += bflo(v7.y); a3.w += bfhi(v7.y);
  }
  for (; e < hi; e++) {
    uint2 v0 = *reinterpret_cast<const uint2*>(hn + (size_t)esrc[e] * N_IN + lane * 4);
    a0.x += bflo(v0.x); a0.y += bfhi(v0.x); a0.z += bflo(v0.y); a0.w += bfhi(v0.y);
  }
  float4 r;
  r.x = (a0.x + a1.x) + (a2.x + a3.x);
  r.y = (a0.y + a1.y) + (a2.y + a3.y);
  r.z = (a0.z + a1.z) + (a2.z + a3.z);
  r.w = (a0.w + a1.w) + (a2.w + a3.w);
  ushort4 p = make_ushort4(f2bf_rne(r.x), f2bf_rne(r.y), f2bf_rne(r.z), f2bf_rne(r.w));
  *reinterpret_cast<ushort4*>(aggB + (size_t)node * N_IN + lane * 4) = p;
}

// ---------------- GEMM1 (A plain bf16, B split hi/lo; col-split by blockIdx.y) ----------------
__global__ __launch_bounds__(256) void k_gemm1_mfma(
    const uint16_t* __restrict__ aggB, const uint4* __restrict__ WH,
    const uint4* __restrict__ WL, const float* __restrict__ b1,
    const float* __restrict__ norm, const uint16_t* __restrict__ mask,
    uint16_t* __restrict__ h1sB, int Nn) {
  const int tid = threadIdx.x;
  const int wave = tid >> 6, lane = tid & 63;
  const int row0 = blockIdx.x * 64 + wave * 16;
  const int cy = blockIdx.y;
  const int lrow = lane & 15, lk = lane >> 4;
  int arow = row0 + lrow; if (arow >= Nn) arow = Nn - 1;

  f32x4 acc[8];
#pragma unroll
  for (int c = 0; c < 8; c++) acc[c] = f32x4{0.f, 0.f, 0.f, 0.f};

#pragma unroll
  for (int ks = 0; ks < 4; ks++) {
    union { uint4 q; bf16x8 v; } ah;
    ah.q = *reinterpret_cast<const uint4*>(aggB + (size_t)arow * N_IN + ks * 32 + lk * 8);
#pragma unroll
    for (int c = 0; c < 8; c++) {
      int ct = cy * 8 + c;
      union { uint4 q; bf16x8 v; } bh, bl;
      bh.q = WH[(ct * 4 + ks) * 64 + lane];
      bl.q = WL[(ct * 4 + ks) * 64 + lane];
      acc[c] = __builtin_amdgcn_mfma_f32_16x16x32_bf16(ah.v, bh.v, acc[c], 0, 0, 0);
      acc[c] = __builtin_amdgcn_mfma_f32_16x16x32_bf16(ah.v, bl.v, acc[c], 0, 0, 0);
    }
  }

  const int colb = lane & 15, rgrp = lane >> 4;
#pragma unroll
  for (int r = 0; r < 4; r++) {
    int row = row0 + rgrp * 4 + r;
    if (row >= Nn) continue;
    float nr = norm[row];
    uint32_t m = mask[row * 16 + colb];
#pragma unroll
    for (int c = 0; c < 8; c++) {
      int ct = cy * 8 + c;
      int col = ct * 16 + colb;
      float v = fmaf(acc[c][r], nr, b1[col]);
      v = fmaxf(v, 0.f);
      v = ((m >> ct) & 1u) ? v * (2.0f * nr) : 0.f;   // dropout + pre-apply src norm
      h1sB[(size_t)row * N_H + col] = f2bf_rne(v);
    }
  }
}

// ---------------- GEMM2 (A=bf16, B split hi/lo): zbf = bf16(h1s @ W2) ----------------
__global__ __launch_bounds__(256) void k_gemm2_mfma(
    const uint16_t* __restrict__ h1sB, const uint4* __restrict__ WH,
    const uint4* __restrict__ WL, uint16_t* __restrict__ zbf, int Nn) {
  const int tid = threadIdx.x;
  const int wave = tid >> 6, lane = tid & 63;
  const int row0 = blockIdx.x * 64 + wave * 16;
  const int lrow = lane & 15, lk = lane >> 4;
  int arow = row0 + lrow; if (arow >= Nn) arow = Nn - 1;

  f32x4 acc[4];
#pragma unroll
  for (int ct = 0; ct < 4; ct++) acc[ct] = f32x4{0.f, 0.f, 0.f, 0.f};

#pragma unroll
  for (int ks = 0; ks < 8; ks++) {
    union { uint4 q; bf16x8 v; } ah;
    ah.q = *reinterpret_cast<const uint4*>(h1sB + (size_t)arow * N_H + ks * 32 + lk * 8);
#pragma unroll
    for (int ct = 0; ct < 4; ct++) {
      union { uint4 q; bf16x8 v; } bh, bl;
      bh.q = WH[(ct * 8 + ks) * 64 + lane];
      bl.q = WL[(ct * 8 + ks) * 64 + lane];
      acc[ct] = __builtin_amdgcn_mfma_f32_16x16x32_bf16(ah.v, bh.v, acc[ct], 0, 0, 0);
      acc[ct] = __builtin_amdgcn_mfma_f32_16x16x32_bf16(ah.v, bl.v, acc[ct], 0, 0, 0);
    }
  }

  const int colb = lane & 15, rgrp = lane >> 4;
#pragma unroll
  for (int r = 0; r < 4; r++) {
    int row = row0 + rgrp * 4 + r;
    if (row >= Nn) continue;
#pragma unroll
    for (int ct = 0; ct < 4; ct++)
      zbf[(size_t)row * N_OUT + ct * 16 + colb] = f2bf_rne(acc[ct][r]);
  }
}

// ---------------- layer-2 pull (bf16 gather) fused epilogue ----------------
// 4 nodes/wave, 16 lanes x 4 bf16 (8 B/lane), 8-edge unroll
__global__ __launch_bounds__(256) void k_pull2(
    const uint16_t* __restrict__ zbf, const float* __restrict__ norm,
    const float* __restrict__ b2, const int* __restrict__ rowptr,
    const int* __restrict__ esrc, float* __restrict__ out, int N) {
  int node = blockIdx.x * 16 + (threadIdx.x >> 4);
  if (node >= N) return;
  int lane = threadIdx.x & 15;
  int lo = rowptr[node], hi = rowptr[node + 1];
  float4 a0 = {0,0,0,0}, a1 = {0,0,0,0}, a2 = {0,0,0,0}, a3 = {0,0,0,0};
  int e = lo;
  for (; e + 7 < hi; e += 8) {
    int s0 = esrc[e],     s1 = esrc[e + 1], s2 = esrc[e + 2], s3 = esrc[e + 3];
    int s4 = esrc[e + 4], s5 = esrc[e + 5], s6 = esrc[e + 6], s7 = esrc[e + 7];
    uint2 v0 = *reinterpret_cast<const uint2*>(zbf + (size_t)s0 * N_OUT + lane * 4);
    uint2 v1 = *reinterpret_cast<const uint2*>(zbf + (size_t)s1 * N_OUT + lane * 4);
    uint2 v2 = *reinterpret_cast<const uint2*>(zbf + (size_t)s2 * N_OUT + lane * 4);
    uint2 v3 = *reinterpret_cast<const uint2*>(zbf + (size_t)s3 * N_OUT + lane * 4);
    uint2 v4 = *reinterpret_cast<const uint2*>(zbf + (size_t)s4 * N_OUT + lane * 4);
    uint2 v5 = *reinterpret_cast<const uint2*>(zbf + (size_t)s5 * N_OUT + lane * 4);
    uint2 v6 = *reinterpret_cast<const uint2*>(zbf + (size_t)s6 * N_OUT + lane * 4);
    uint2 v7 = *reinterpret_cast<const uint2*>(zbf + (size_t)s7 * N_OUT + lane * 4);
    a0.x += bflo(v0.x); a0.y += bfhi(v0.x); a0.z += bflo(v0.y); a0.w += bfhi(v0.y);
    a1.x += bflo(v1.x); a1.y += bfhi(v1.x); a1.z += bflo(v1.y); a1.w += bfhi(v1.y);
    a2.x += bflo(v2.x); a2.y += bfhi(v2.x); a2.z += bflo(v2.y); a2.w += bfhi(v2.y);
    a3.x += bflo(v3.x); a3.y += bfhi(v3.x); a3.z += bflo(v3.y); a3.w += bfhi(v3.y);
    a0.x += bflo(v4.x); a0.y += bfhi(v4.x); a0.z += bflo(v4.y); a0.w += bfhi(v4.y);
    a1.x += bflo(v5.x); a1.y += bfhi(v5.x); a1.z += bflo(v5.y); a1.w += bfhi(v5.y);
    a2.x += bflo(v6.x); a2.y += bfhi(v6.x); a2.z += bflo(v6.y); a2.w += bfhi(v6.y);
    a3.x += bflo(v7.x); a3.y += bfhi(v7.x); a3.z += bflo(v7.y); a3.w += bfhi(v7.y);
  }
  for (; e < hi; e++) {
    uint2 v0 = *reinterpret_cast<const uint2*>(zbf + (size_t)esrc[e] * N_OUT + lane * 4);
    a0.x += bflo(v0.x); a0.y += bfhi(v0.x); a0.z += bflo(v0.y); a0.w += bfhi(v0.y);
  }
  float nn = norm[node];
  float4 bb = *reinterpret_cast<const float4*>(b2 + lane * 4);
  float4 r;
  r.x = ((a0.x + a1.x) + (a2.x + a3.x)) * nn + bb.x;
  r.y = ((a0.y + a1.y) + (a2.y + a3.y)) * nn + bb.y;
  r.z = ((a0.z + a1.z) + (a2.z + a3.z)) * nn + bb.z;
  r.w = ((a0.w + a1.w) + (a2.w + a3.w)) * nn + bb.w;
  *reinterpret_cast<float4*>(out + (size_t)node * N_OUT + lane * 4) = r;
}

extern "C" void kernel_launch(void* const* d_in, const int* in_sizes, int n_in,
                              void* d_out, int out_size, void* d_ws, size_t ws_size,
                              hipStream_t stream) {
  const float* h  = (const float*)d_in[0];
  const float* W1 = (const float*)d_in[1];
  const float* b1 = (const float*)d_in[2];
  const float* W2 = (const float*)d_in[3];
  const float* b2 = (const float*)d_in[4];
  const int* eidx = (const int*)d_in[5];
  const int N = in_sizes[0] / N_IN;
  const int E = in_sizes[5] / 2;
  const int NBE = (E + CHK - 1) / CHK;     // scatter blocks
  const int NBM = (N * 16 + 255) / 256;    // mask blocks
  const int NS  = (N + 3) / 4;             // sort blocks
  const int NH  = (N * 32 + 255) / 256;    // h2bf blocks

  char* ws = (char*)d_ws;
  size_t off = 0;
  auto alloc = [&](size_t bytes) { void* p = ws + off; off += (bytes + 511) & ~(size_t)511; return p; };
  int*      rowptr = (int*)alloc((size_t)(N + 1) * 4);
  float*    norm   = (float*)alloc((size_t)N * 4);
  int*      esrc   = (int*)alloc((size_t)E * 4);
  int*      bktCur = (int*)alloc((size_t)256 * 4);
  uint16_t* mask   = (uint16_t*)alloc((size_t)N * 16 * 2);
  uint4*    W1H    = (uint4*)alloc((size_t)16 * 4 * 64 * 16);
  uint4*    W1L    = (uint4*)alloc((size_t)16 * 4 * 64 * 16);
  uint4*    W2H    = (uint4*)alloc((size_t)4 * 8 * 64 * 16);
  uint4*    W2L    = (uint4*)alloc((size_t)4 * 8 * 64 * 16);
  uint2*    eb     = (uint2*)alloc((size_t)256 * CAP * 8);     // 12.6 MB fixed-cap buckets
  uint16_t* aggB   = (uint16_t*)alloc((size_t)N * N_IN * 2);   // 12.8 MB plain bf16
  uint16_t* h1sB   = (uint16_t*)alloc((size_t)N * N_H * 2);    // 25.6 MB
  uint16_t* hn     = (uint16_t*)h1sB;   // 12.8 MB; dead before gemm1 writes h1sB
  uint16_t* zbf    = (uint16_t*)aggB;   // 6.4 MB; aggB dead after gemm1
  float*    out    = (float*)d_out;

  // 1. zero bucket cursors (1 KB DMA)
  hipMemsetAsync(bktCur, 0, 256 * 4, stream);

  // 2. fused front: edge scatter || dropout mask || W packs
  k_front<<<NBE + NBM + 16 + 8, 256, 0, stream>>>(eidx, E, bktCur, eb,
                                                  mask, N, W1, W1H, W1L, W2, W2H, W2L, NBE);

  // 3. per-bucket CSR build
  k_bucket_csr<<<256, 256, 0, stream>>>(eb, bktCur, rowptr, norm, esrc, N, E);

  // 4. fused mid: row sort || bf16 gather plane
  k_mid<<<NS + NH, 256, 0, stream>>>(esrc, rowptr, N, h, norm, hn, NS);

  // 5. layer-1 aggregation
  k_pull1<<<(N + 7) / 8, 256, 0, stream>>>(hn, rowptr, esrc, aggB, N);

  // 6-7. GEMMs
  dim3 g1((N + 63) / 64, 2);
  k_gemm1_mfma<<<g1, 256, 0, stream>>>(aggB, W1H, W1L, b1, norm, mask, h1sB, N);
  k_gemm2_mfma<<<(N + 63) / 64, 256, 0, stream>>>(h1sB, W2H, W2L, zbf, N);

  // 8. layer-2 aggregation + epilogue
  k_pull2<<<(N + 15) / 16, 256, 0, stream>>>(zbf, norm, b2, rowptr, esrc, out, N);
}